// Round 10
// baseline (12057.965 us; speedup 1.0000x reference)
//
#include <hip/hip_runtime.h>
#include <hip/hip_bf16.h>

typedef __hip_bfloat16 bf16;

#define BZc 64
#define NAc 64
#define Dc 128
#define Rc 3
#define Hc 4
#define INc 96
#define NACTc 20

// fixed workspace layout (float element offsets)
#define WM1_OFF    0        // 16384 : W_m1 others-half, float4-permuted by dm
#define WM2_OFF    16384    // 16384 : W_m2 float4-permuted
#define WS1_OFF    32768    // 24576 : W_s1 msg-half, float4-permuted by du
#define WM1ST_OFF  57344    // 16384 : W_m1 self-half, transposed [c][dm]
#define WS1ST_OFF  73728    // 24576 : W_s1 self-half, transposed [r][c][du]
#define WENCT_OFF  98304    // 12288 : W_enc^T [c][128]
#define WIHT_OFF   110592   // 49152 : W_ih^T  [c][384]
#define WHHT_OFF   159744   // 49152 : W_hh^T  [c][384]
#define WOTHT_OFF  208896   // 16384 : W_oth^T [c][128]
#define WQ1T_OFF   225280   // 32768 : W_q1^T  [c][128]
#define WQ2T_OFF   258048   // 2560  : W_q2^T  [c][20]
#define MH_OFF     260608   // 196608: Mhq[r][hh] float4-permuted (Wq_h^T Wk_h)
#define P_OFF      457216   // 196608: Pq[r] float4-permuted (k=hh*128+d major)
#define CHUNK_BASE 655360   // floats; per-chunk region starts here

// ---------------- weight permute / transpose kernel ----------------
__global__ void kW(const float* __restrict__ W_m1, const float* __restrict__ W_m2,
                   const float* __restrict__ W_s1, const float* __restrict__ W_enc,
                   const float* __restrict__ W_ih, const float* __restrict__ W_hh,
                   const float* __restrict__ W_oth, const float* __restrict__ W_q1,
                   const float* __restrict__ W_q2, float* __restrict__ ws) {
  int idx = blockIdx.x * blockDim.x + threadIdx.x;
  if (idx < 16384) {
    int dm = idx & 127, c = idx >> 7;
    ws[WM1_OFF + ((c >> 2) * 128 + dm) * 4 + (c & 3)] = W_m1[dm * 256 + c];
  } else if (idx < 32768) {
    int k = idx - 16384;
    int dm = k & 127, c = k >> 7;
    ws[WM2_OFF + ((c >> 2) * 128 + dm) * 4 + (c & 3)] = W_m2[dm * 128 + c];
  } else if (idx < 57344) {
    int k = idx - 32768;
    int r = k >> 13, rem = k & 8191;
    int du = rem & 63, c = rem >> 6;
    ws[WS1_OFF + r * 8192 + ((c >> 2) * 64 + du) * 4 + (c & 3)] =
        W_s1[(r * 64 + du) * 256 + 128 + c];
  } else if (idx < 73728) {
    int k = idx - 57344;
    int dm = k & 127, c = k >> 7;
    ws[WM1ST_OFF + c * 128 + dm] = W_m1[dm * 256 + 128 + c];
  } else if (idx < 98304) {
    int k = idx - 73728;
    int r = k >> 13, rem = k & 8191;
    int du = rem & 63, c = rem >> 6;
    ws[WS1ST_OFF + r * 8192 + c * 64 + du] = W_s1[(r * 64 + du) * 256 + c];
  } else if (idx < 110592) {
    int k = idx - 98304;              // W_encT [96][128]
    int o = k & 127, c = k >> 7;
    ws[WENCT_OFF + c * 128 + o] = W_enc[o * 96 + c];
  } else if (idx < 159744) {
    int k = idx - 110592;             // W_ihT [128][384]
    int o = k % 384, c = k / 384;
    ws[WIHT_OFF + c * 384 + o] = W_ih[o * 128 + c];
  } else if (idx < 208896) {
    int k = idx - 159744;             // W_hhT [128][384]
    int o = k % 384, c = k / 384;
    ws[WHHT_OFF + c * 384 + o] = W_hh[o * 128 + c];
  } else if (idx < 225280) {
    int k = idx - 208896;             // W_othT [128][128]
    int o = k & 127, c = k >> 7;
    ws[WOTHT_OFF + c * 128 + o] = W_oth[o * 128 + c];
  } else if (idx < 258048) {
    int k = idx - 225280;             // W_q1T [256][128]
    int o = k & 127, c = k >> 7;
    ws[WQ1T_OFF + c * 128 + o] = W_q1[o * 256 + c];
  } else if (idx < 260608) {
    int k = idx - 258048;             // W_q2T [128][20]
    int o = k % 20, c = k / 20;
    ws[WQ2T_OFF + c * 20 + o] = W_q2[o * 128 + c];
  }
}

// ---------------- per-head projection folds, stored float4-permuted ----------------
__global__ __launch_bounds__(256) void kMP(
    const float* __restrict__ Wq, const float* __restrict__ Wk,
    const float* __restrict__ Wv, const float* __restrict__ Wo,
    float* __restrict__ Mhq, float* __restrict__ Pq) {
  const int bid = blockIdx.x;  // 24 = r*8 + hh*2 + which
  const int which = bid & 1, hh = (bid >> 1) & 3, r = bid >> 3;
  const int t = threadIdx.x;
  __shared__ float A[4096];
  __shared__ float B[4224];
  if (which == 0) {
    for (int k = t; k < 4096; k += 256) {
      int e = k >> 7, c = k & 127;
      A[k] = Wq[(r * 128 + hh * 32 + e) * 128 + c];
      B[k] = Wk[(r * 128 + hh * 32 + e) * 128 + c];
    }
    __syncthreads();
    for (int k = 0; k < 64; ++k) {
      int o = k * 256 + t, c = o >> 7, d = o & 127;
      float a = 0.f;
      #pragma unroll 8
      for (int e = 0; e < 32; ++e) a += A[e * 128 + c] * B[e * 128 + d];
      Mhq[(size_t)(r * 4 + hh) * 16384 + ((c >> 2) * 128 + d) * 4 + (c & 3)] = a;
    }
  } else {
    for (int k = t; k < 4096; k += 256) A[k] = Wv[(r * 128 + hh * 32 + (k >> 7)) * 128 + (k & 127)];
    for (int k = t; k < 4096; k += 256) {
      int dp = k >> 5, e = k & 31;
      B[dp * 33 + e] = Wo[(r * 128 + dp) * 128 + hh * 32 + e];
    }
    __syncthreads();
    for (int k = 0; k < 64; ++k) {
      int o = k * 256 + t, d = o >> 7, dp = o & 127;
      float a = 0.f;
      #pragma unroll 8
      for (int e = 0; e < 32; ++e) a += A[e * 128 + d] * B[dp * 33 + e];
      int kk = hh * 128 + d;
      Pq[(size_t)r * 65536 + ((kk >> 2) * 128 + dp) * 4 + (kk & 3)] = a;
    }
  }
}

// ---------------- encoder + GRU + others ----------------
__global__ __launch_bounds__(128) void k_enc(
    const float* __restrict__ obs, const float* __restrict__ hidden,
    const float* __restrict__ WencT, const float* __restrict__ b_enc,
    const float* __restrict__ WihT, const float* __restrict__ WhhT,
    const float* __restrict__ b_ih, const float* __restrict__ b_hh,
    const float* __restrict__ WothT, const float* __restrict__ b_oth,
    float* __restrict__ h_f32, float* __restrict__ oth_f32,
    float* __restrict__ out_h, int b0) {
  const int row_l = blockIdx.x, t = threadIdx.x;
  const int row_g = b0 * 64 + row_l;
  __shared__ float obs_s[96], hid_s[128], x_s[128], h_s[128];
  if (t < 96) obs_s[t] = obs[row_g * 96 + t];
  hid_s[t] = hidden[row_g * 128 + t];
  __syncthreads();
  float x = b_enc[t];
  #pragma unroll 8
  for (int c = 0; c < 96; ++c) x += obs_s[c] * WencT[c * 128 + t];
  x_s[t] = x;
  __syncthreads();
  float gxr = b_ih[t], gxz = b_ih[t + 128], gxn = b_ih[t + 256];
  float ghr = b_hh[t], ghz = b_hh[t + 128], ghn = b_hh[t + 256];
  #pragma unroll 4
  for (int c = 0; c < 128; ++c) {
    float xv = x_s[c], hv = hid_s[c];
    const float* wi = WihT + c * 384 + t;
    const float* wh = WhhT + c * 384 + t;
    gxr += xv * wi[0]; gxz += xv * wi[128]; gxn += xv * wi[256];
    ghr += hv * wh[0]; ghz += hv * wh[128]; ghn += hv * wh[256];
  }
  float rg = 1.f / (1.f + expf(-(gxr + ghr)));
  float zg = 1.f / (1.f + expf(-(gxz + ghz)));
  float ng = tanhf(gxn + rg * ghn);
  float hv = (1.f - zg) * ng + zg * hid_s[t];
  h_s[t] = hv;
  h_f32[row_l * 128 + t] = hv;
  out_h[(size_t)row_g * 128 + t] = hv;
  __syncthreads();
  float o = b_oth[t];
  #pragma unroll 4
  for (int c = 0; c < 128; ++c) o += h_s[c] * WothT[c * 128 + t];
  oth_f32[row_l * 128 + t] = o;
}

// ---------------- message MLP + scheduler MLP (S arithmetic FROZEN; pragmas only) ----
__global__ __launch_bounds__(256, 2) void k_msg(
    const float* __restrict__ h_f32, const float* __restrict__ oth_f32,
    const float* __restrict__ Wm1q, const float* __restrict__ Wm1sT,
    const float* __restrict__ b_m1, const float* __restrict__ Wm2q,
    const float* __restrict__ b_m2, const float* __restrict__ Ws1q,
    const float* __restrict__ Ws1sT, const float* __restrict__ b_s1,
    const float* __restrict__ W_s2, const float* __restrict__ b_s2,
    bf16* __restrict__ msg_g, float* __restrict__ S_g, int nblk) {
  const int blk = blockIdx.x;        // local: b_l*64 + i
  const int b = blk >> 6;
  const int t = threadIdx.x;
  __shared__ float oth_s[64 * 128];  // 32KB: others; becomes msg after layer 2
  __shared__ float tact[64 * 128];   // 32KB
  const int dq = t & 31;             // dm quad: dm = dq + 32*k, k=0..3
  const int jb = (t >> 5) * 8;       // 8 j-groups of 8
  const int l = t & 63, wv = t >> 6; // scheduler mapping (l = du = lane)

  {
    const float* ob = oth_f32 + (size_t)b * 8192;
    for (int k = t; k < 8192; k += 256) oth_s[k] = ob[k];
  }
  float sp0 = b_m1[dq], sp1v = b_m1[dq + 32], sp2 = b_m1[dq + 64], sp3 = b_m1[dq + 96];
  float spS0 = b_s1[l], spS1 = b_s1[64 + l], spS2 = b_s1[128 + l];
  {
    const float* hrow = h_f32 + (size_t)blk * 128;
    #pragma unroll 4
    for (int c = 0; c < 128; ++c) {
      float hv = hrow[c];
      const float* wt = Wm1sT + c * 128;
      sp0  += hv * wt[dq];
      sp1v += hv * wt[dq + 32];
      sp2  += hv * wt[dq + 64];
      sp3  += hv * wt[dq + 96];
      spS0 += hv * Ws1sT[c * 64 + l];
      spS1 += hv * Ws1sT[8192 + c * 64 + l];
      spS2 += hv * Ws1sT[16384 + c * 64 + l];
    }
  }
  __syncthreads();
  // ---- message layer 1 ----
  {
    float a0[8], a1[8], a2[8], a3[8];
    #pragma unroll
    for (int j = 0; j < 8; ++j) { a0[j] = sp0; a1[j] = sp1v; a2[j] = sp2; a3[j] = sp3; }
    const float4* wq = (const float4*)Wm1q;
    #pragma unroll
    for (int c4 = 0; c4 < 32; ++c4) {
      float4 w0 = wq[c4 * 128 + dq];
      float4 w1 = wq[c4 * 128 + dq + 32];
      float4 w2 = wq[c4 * 128 + dq + 64];
      float4 w3 = wq[c4 * 128 + dq + 96];
      #pragma unroll
      for (int j = 0; j < 8; ++j) {
        float4 v = *(const float4*)&oth_s[(jb + j) * 128 + c4 * 4];
        a0[j] += v.x * w0.x; a0[j] += v.y * w0.y; a0[j] += v.z * w0.z; a0[j] += v.w * w0.w;
        a1[j] += v.x * w1.x; a1[j] += v.y * w1.y; a1[j] += v.z * w1.z; a1[j] += v.w * w1.w;
        a2[j] += v.x * w2.x; a2[j] += v.y * w2.y; a2[j] += v.z * w2.z; a2[j] += v.w * w2.w;
        a3[j] += v.x * w3.x; a3[j] += v.y * w3.y; a3[j] += v.z * w3.z; a3[j] += v.w * w3.w;
      }
    }
    #pragma unroll
    for (int j = 0; j < 8; ++j) {
      tact[(jb + j) * 128 + dq]      = fmaxf(a0[j], 0.f);
      tact[(jb + j) * 128 + dq + 32] = fmaxf(a1[j], 0.f);
      tact[(jb + j) * 128 + dq + 64] = fmaxf(a2[j], 0.f);
      tact[(jb + j) * 128 + dq + 96] = fmaxf(a3[j], 0.f);
    }
  }
  __syncthreads();
  // ---- message layer 2 ----
  {
    float a0[8], a1[8], a2[8], a3[8];
    const float s0 = b_m2[dq], s1 = b_m2[dq + 32], s2 = b_m2[dq + 64], s3 = b_m2[dq + 96];
    #pragma unroll
    for (int j = 0; j < 8; ++j) { a0[j] = s0; a1[j] = s1; a2[j] = s2; a3[j] = s3; }
    const float4* wq = (const float4*)Wm2q;
    #pragma unroll
    for (int c4 = 0; c4 < 32; ++c4) {
      float4 w0 = wq[c4 * 128 + dq];
      float4 w1 = wq[c4 * 128 + dq + 32];
      float4 w2 = wq[c4 * 128 + dq + 64];
      float4 w3 = wq[c4 * 128 + dq + 96];
      #pragma unroll
      for (int j = 0; j < 8; ++j) {
        float4 v = *(const float4*)&tact[(jb + j) * 128 + c4 * 4];
        a0[j] += v.x * w0.x; a0[j] += v.y * w0.y; a0[j] += v.z * w0.z; a0[j] += v.w * w0.w;
        a1[j] += v.x * w1.x; a1[j] += v.y * w1.y; a1[j] += v.z * w1.z; a1[j] += v.w * w1.w;
        a2[j] += v.x * w2.x; a2[j] += v.y * w2.y; a2[j] += v.z * w2.z; a2[j] += v.w * w2.w;
        a3[j] += v.x * w3.x; a3[j] += v.y * w3.y; a3[j] += v.z * w3.z; a3[j] += v.w * w3.w;
      }
    }
    #pragma unroll
    for (int j = 0; j < 8; ++j) {
      float m0 = fmaxf(a0[j], 0.f), m1 = fmaxf(a1[j], 0.f);
      float m2 = fmaxf(a2[j], 0.f), m3 = fmaxf(a3[j], 0.f);
      oth_s[(jb + j) * 128 + dq]      = m0;
      oth_s[(jb + j) * 128 + dq + 32] = m1;
      oth_s[(jb + j) * 128 + dq + 64] = m2;
      oth_s[(jb + j) * 128 + dq + 96] = m3;
      bf16* mg = msg_g + ((size_t)blk * 64 + (jb + j)) * 128 + dq;
      mg[0]  = __float2bfloat16(m0);
      mg[32] = __float2bfloat16(m1);
      mg[64] = __float2bfloat16(m2);
      mg[96] = __float2bfloat16(m3);
    }
  }
  __syncthreads();
  // ---- scheduler MLP (chains + butterfly FROZEN) ----
  const float spSr[3] = {spS0, spS1, spS2};
  for (int r = 0; r < 3; ++r) {
    const float4* wq = (const float4*)(Ws1q + r * 8192);
    const float w2a = W_s2[(r * 2 + 0) * 64 + l];
    const float w2b = W_s2[(r * 2 + 1) * 64 + l];
    const float bs2a = b_s2[r * 2 + 0], bs2b = b_s2[r * 2 + 1];
    float ua[16];
    #pragma unroll
    for (int j = 0; j < 16; ++j) ua[j] = spSr[r];
    #pragma unroll
    for (int c4 = 0; c4 < 32; ++c4) {
      float4 w = wq[c4 * 64 + l];
      #pragma unroll
      for (int j = 0; j < 16; ++j) {
        float4 v = *(const float4*)&oth_s[(wv * 16 + j) * 128 + c4 * 4];
        ua[j] += v.x * w.x + v.y * w.y + v.z * w.z + v.w * w.w;
      }
    }
    #pragma unroll
    for (int j = 0; j < 16; ++j) {
      float u = fmaxf(ua[j], 0.f);
      float v0 = u * w2a, v1 = u * w2b;
      #pragma unroll
      for (int s = 1; s < 64; s <<= 1) {
        v0 += __shfl_xor(v0, s, 64);
        v1 += __shfl_xor(v1, s, 64);
      }
      if (l == 0) {
        float* sp = S_g + (((size_t)r * nblk + blk) * 64 + (wv * 16 + j)) * 2;
        sp[0] = v0 + bs2a;
        sp[1] = v1 + bs2b;
      }
    }
  }
}

// ---------------- batched qW = h @ Mh (Mh read once per 64 agents) ----------------
__global__ __launch_bounds__(256) void k_qw(
    const float* __restrict__ h_f32, const float* __restrict__ Mhq,
    float* __restrict__ qW_g, int nblk) {
  const int b = blockIdx.x, r = blockIdx.y, t = threadIdx.x;
  __shared__ float h_s[8192];
  for (int k = t; k < 8192; k += 256) h_s[k] = h_f32[(size_t)b * 8192 + k];
  __syncthreads();
  const int dq = t & 31, ib = (t >> 5) * 8;
  for (int hh = 0; hh < 4; ++hh) {
    float a0[8], a1[8], a2[8], a3[8];
    #pragma unroll
    for (int i = 0; i < 8; ++i) { a0[i] = 0.f; a1[i] = 0.f; a2[i] = 0.f; a3[i] = 0.f; }
    const float4* mq = (const float4*)(Mhq + (size_t)(r * 4 + hh) * 16384);
    #pragma unroll
    for (int c4 = 0; c4 < 32; ++c4) {
      float4 w0 = mq[c4 * 128 + dq];
      float4 w1 = mq[c4 * 128 + dq + 32];
      float4 w2 = mq[c4 * 128 + dq + 64];
      float4 w3 = mq[c4 * 128 + dq + 96];
      #pragma unroll
      for (int i = 0; i < 8; ++i) {
        float4 v = *(const float4*)&h_s[(ib + i) * 128 + c4 * 4];
        a0[i] += v.x * w0.x; a0[i] += v.y * w0.y; a0[i] += v.z * w0.z; a0[i] += v.w * w0.w;
        a1[i] += v.x * w1.x; a1[i] += v.y * w1.y; a1[i] += v.z * w1.z; a1[i] += v.w * w1.w;
        a2[i] += v.x * w2.x; a2[i] += v.y * w2.y; a2[i] += v.z * w2.z; a2[i] += v.w * w2.w;
        a3[i] += v.x * w3.x; a3[i] += v.y * w3.y; a3[i] += v.z * w3.z; a3[i] += v.w * w3.w;
      }
    }
    #pragma unroll
    for (int i = 0; i < 8; ++i) {
      float* qp = qW_g + ((size_t)r * nblk + b * 64 + ib + i) * 512 + hh * 128 + dq;
      qp[0]  = a0[i];
      qp[32] = a1[i];
      qp[64] = a2[i];
      qp[96] = a3[i];
    }
  }
}

// ---------------- adjacency + scores + masked softmax + mw (core) ----------------
__global__ __launch_bounds__(256) void k_attn(
    const bf16* __restrict__ msg_g, const float* __restrict__ S_g,
    const float* __restrict__ gumbel, const float* __restrict__ qW_g,
    float* __restrict__ mw_g, int b0, int nblk) {
  const int blk = blockIdx.x, r = blockIdx.y;
  const int b = blk >> 6, i = blk & 63, t = threadIdx.x;
  __shared__ float msg_s[64][132];
  __shared__ float qW_s[4][132];
  __shared__ float sc_s[320];
  __shared__ float adj_s[64];
  __shared__ float w_s[320];

  {
    const unsigned int* mb = (const unsigned int*)(msg_g + (size_t)blk * 8192);
    for (int k = t; k < 4096; k += 256) {
      unsigned int v = mb[k];
      int j = k >> 6, d2 = (k & 63) * 2;
      msg_s[j][d2]     = __uint_as_float(v << 16);
      msg_s[j][d2 + 1] = __uint_as_float(v & 0xffff0000u);
    }
  }
  for (int o = t; o < 512; o += 256)
    qW_s[o >> 7][o & 127] = qW_g[((size_t)r * nblk + blk) * 512 + o];
  if (t < 64) {
    const int j = t;
    const float* Sij = S_g + (((size_t)r * nblk + blk) * 64 + j) * 2;
    const float* Sji = S_g + (((size_t)r * nblk + b * 64 + j) * 64 + i) * 2;
    const float* g = gumbel + ((((size_t)r * 64 + (b0 + b)) * 64 + i) * 64 + j) * 2;
    float y0 = 0.5f * Sij[0] + 0.5f * Sji[0] + g[0];
    float y1 = 0.5f * Sij[1] + 0.5f * Sji[1] + g[1];
    adj_s[j] = (y1 > y0) ? 1.f : 0.f;
  }
  __syncthreads();
  // scores[j][hh]
  {
    const int j = t >> 2, hh = t & 3;
    float a = 0.f;
    #pragma unroll
    for (int d4 = 0; d4 < 32; ++d4) {
      float4 mv = *(const float4*)&msg_s[j][d4 * 4];
      float4 qv = *(const float4*)&qW_s[hh][d4 * 4];
      a += mv.x * qv.x + mv.y * qv.y + mv.z * qv.z + mv.w * qv.w;
    }
    sc_s[j * 5 + hh] = a * 0.17677669529663687f;  // 1/sqrt(32)
  }
  __syncthreads();
  // masked softmax per head (one wave per head)
  {
    const int hh = t >> 6, jj = t & 63;
    float v = sc_s[jj * 5 + hh];
    float mx = v;
    #pragma unroll
    for (int s = 32; s > 0; s >>= 1) mx = fmaxf(mx, __shfl_xor(mx, s, 64));
    float e = expf(v - mx);
    float ad = adj_s[jj];
    float E = e, Em = ad * e;
    #pragma unroll
    for (int s = 32; s > 0; s >>= 1) {
      E += __shfl_xor(E, s, 64);
      Em += __shfl_xor(Em, s, 64);
    }
    w_s[jj * 5 + hh] = ad * e / (Em + 1e-10f * E);
  }
  __syncthreads();
  // mw[hh][d] = sum_j w[j,hh] * msg[j,d]  -> mw_g
  {
    const int hh0 = t >> 7, d = t & 127;
    float a0 = 0.f, a1 = 0.f;
    for (int j = 0; j < 64; ++j) {
      float m = msg_s[j][d];
      a0 += w_s[j * 5 + hh0] * m;
      a1 += w_s[j * 5 + hh0 + 2] * m;
    }
    float* mp = mw_g + ((size_t)r * nblk + blk) * 512;
    mp[hh0 * 128 + d] = a0;
    mp[(hh0 + 2) * 128 + d] = a1;
  }
}

// ---------------- batched att = elu(mw @ P) (P read once per 64 agents) ----------------
__global__ __launch_bounds__(256) void k_pv(
    const float* __restrict__ mw_g, const float* __restrict__ Pq,
    float* __restrict__ att_r, int nblk) {
  const int b = blockIdx.x, r = blockIdx.y, t = threadIdx.x;
  const int dq = t & 31, ib = (t >> 5) * 8;
  float a0[8], a1[8], a2[8], a3[8];
  #pragma unroll
  for (int i = 0; i < 8; ++i) { a0[i] = 0.f; a1[i] = 0.f; a2[i] = 0.f; a3[i] = 0.f; }
  const float4* pq = (const float4*)(Pq + (size_t)r * 65536);
  const float* mwb = mw_g + ((size_t)r * nblk + b * 64) * 512;
  #pragma unroll 4
  for (int c4 = 0; c4 < 128; ++c4) {
    float4 w0 = pq[c4 * 128 + dq];
    float4 w1 = pq[c4 * 128 + dq + 32];
    float4 w2 = pq[c4 * 128 + dq + 64];
    float4 w3 = pq[c4 * 128 + dq + 96];
    #pragma unroll
    for (int i = 0; i < 8; ++i) {
      float4 v = *(const float4*)&mwb[(size_t)(ib + i) * 512 + c4 * 4];
      a0[i] += v.x * w0.x; a0[i] += v.y * w0.y; a0[i] += v.z * w0.z; a0[i] += v.w * w0.w;
      a1[i] += v.x * w1.x; a1[i] += v.y * w1.y; a1[i] += v.z * w1.z; a1[i] += v.w * w1.w;
      a2[i] += v.x * w2.x; a2[i] += v.y * w2.y; a2[i] += v.z * w2.z; a2[i] += v.w * w2.w;
      a3[i] += v.x * w3.x; a3[i] += v.y * w3.y; a3[i] += v.z * w3.z; a3[i] += v.w * w3.w;
    }
  }
  #pragma unroll
  for (int i = 0; i < 8; ++i) {
    float* ap = att_r + ((size_t)r * nblk + b * 64 + ib + i) * 128 + dq;
    ap[0]  = (a0[i] > 0.f) ? a0[i] : expm1f(a0[i]);
    ap[32] = (a1[i] > 0.f) ? a1[i] : expm1f(a1[i]);
    ap[64] = (a2[i] > 0.f) ? a2[i] : expm1f(a2[i]);
    ap[96] = (a3[i] > 0.f) ? a3[i] : expm1f(a3[i]);
  }
}

// ---------------- mean over rounds + output head ----------------
__global__ __launch_bounds__(128) void k_head(
    const float* __restrict__ h_f32, const float* __restrict__ att_r,
    const float* __restrict__ Wq1T, const float* __restrict__ b_q1,
    const float* __restrict__ Wq2T, const float* __restrict__ b_q2,
    float* __restrict__ out_q, int b0, int nblk) {
  const int blk = blockIdx.x, t = threadIdx.x;
  __shared__ float hi[128], agg[128], u[128];
  hi[t] = h_f32[(size_t)blk * 128 + t];
  agg[t] = (att_r[(size_t)blk * 128 + t] +
            att_r[((size_t)nblk + blk) * 128 + t] +
            att_r[((size_t)2 * nblk + blk) * 128 + t]) * (1.f / 3.f);
  __syncthreads();
  float a = b_q1[t];
  #pragma unroll 4
  for (int c = 0; c < 128; ++c) a += hi[c] * Wq1T[c * 128 + t];
  #pragma unroll 4
  for (int c = 0; c < 128; ++c) a += agg[c] * Wq1T[(128 + c) * 128 + t];
  u[t] = fmaxf(a, 0.f);
  __syncthreads();
  if (t < 20) {
    float a2 = b_q2[t];
    #pragma unroll 4
    for (int c = 0; c < 128; ++c) a2 += u[c] * Wq2T[c * 20 + t];
    out_q[((size_t)b0 * 64 + blk) * 20 + t] = a2;
  }
}

extern "C" void kernel_launch(void* const* d_in, const int* in_sizes, int n_in,
                              void* d_out, int out_size, void* d_ws, size_t ws_size,
                              hipStream_t stream) {
  (void)in_sizes; (void)n_in; (void)out_size;
  const float* obs    = (const float*)d_in[0];
  const float* hidden = (const float*)d_in[1];
  const float* gumb   = (const float*)d_in[2];
  const float* W_enc  = (const float*)d_in[3];
  const float* b_enc  = (const float*)d_in[4];
  const float* W_ih   = (const float*)d_in[5];
  const float* W_hh   = (const float*)d_in[6];
  const float* b_ih   = (const float*)d_in[7];
  const float* b_hh   = (const float*)d_in[8];
  const float* W_oth  = (const float*)d_in[9];
  const float* b_oth  = (const float*)d_in[10];
  const float* W_m1   = (const float*)d_in[11];
  const float* b_m1   = (const float*)d_in[12];
  const float* W_m2   = (const float*)d_in[13];
  const float* b_m2   = (const float*)d_in[14];
  const float* W_s1   = (const float*)d_in[15];
  const float* b_s1   = (const float*)d_in[16];
  const float* W_s2   = (const float*)d_in[17];
  const float* b_s2   = (const float*)d_in[18];
  const float* Wq     = (const float*)d_in[19];
  const float* Wk     = (const float*)d_in[20];
  const float* Wv     = (const float*)d_in[21];
  const float* Wo     = (const float*)d_in[22];
  const float* W_q1   = (const float*)d_in[23];
  const float* b_q1   = (const float*)d_in[24];
  const float* W_q2   = (const float*)d_in[25];
  const float* b_q2   = (const float*)d_in[26];

  float* ws    = (float*)d_ws;
  float* Wm1q  = ws + WM1_OFF;
  float* Wm2q  = ws + WM2_OFF;
  float* Ws1q  = ws + WS1_OFF;
  float* Wm1sT = ws + WM1ST_OFF;
  float* Ws1sT = ws + WS1ST_OFF;
  float* WencT = ws + WENCT_OFF;
  float* WihT  = ws + WIHT_OFF;
  float* WhhT  = ws + WHHT_OFF;
  float* WothT = ws + WOTHT_OFF;
  float* Wq1T  = ws + WQ1T_OFF;
  float* Wq2T  = ws + WQ2T_OFF;
  float* Mhq   = ws + MH_OFF;
  float* Pq    = ws + P_OFF;

  float* out_q = (float*)d_out;  // f32 output: qout then h
  float* out_h = out_q + BZc * NAc * NACTc;

  // per-b chunk: h 32KB + oth 32KB + S 96KB + att 96KB + qW 384KB + mw 384KB + msg 1MB = 2MB
  int BC = 64;
  while (BC > 1) {
    size_t need = 4ull * CHUNK_BASE + (size_t)BC * 2097152ull;
    if (need <= ws_size) break;
    BC >>= 1;
  }
  const int nblk = BC * 64;
  float* h_f32   = ws + CHUNK_BASE;
  float* oth_f32 = h_f32 + (size_t)BC * 8192;
  float* S_g     = oth_f32 + (size_t)BC * 8192;
  float* att_rb  = S_g + (size_t)BC * 24576;
  float* qW_g    = att_rb + (size_t)BC * 24576;
  float* mw_g    = qW_g + (size_t)BC * 98304;
  bf16*  msg_g   = (bf16*)(mw_g + (size_t)BC * 98304);

  kW<<<dim3(1018), dim3(256), 0, stream>>>(W_m1, W_m2, W_s1, W_enc, W_ih, W_hh,
                                           W_oth, W_q1, W_q2, ws);
  kMP<<<dim3(24), dim3(256), 0, stream>>>(Wq, Wk, Wv, Wo, Mhq, Pq);
  for (int b0 = 0; b0 < BZc; b0 += BC) {
    k_enc<<<dim3(nblk), dim3(128), 0, stream>>>(obs, hidden, WencT, b_enc, WihT, WhhT,
                                                b_ih, b_hh, WothT, b_oth,
                                                h_f32, oth_f32, out_h, b0);
    k_msg<<<dim3(nblk), dim3(256), 0, stream>>>(h_f32, oth_f32, Wm1q, Wm1sT, b_m1,
                                                Wm2q, b_m2, Ws1q, Ws1sT, b_s1,
                                                W_s2, b_s2, msg_g, S_g, nblk);
    k_qw<<<dim3(BC, 3), dim3(256), 0, stream>>>(h_f32, Mhq, qW_g, nblk);
    k_attn<<<dim3(nblk, 3), dim3(256), 0, stream>>>(msg_g, S_g, gumb, qW_g,
                                                    mw_g, b0, nblk);
    k_pv<<<dim3(BC, 3), dim3(256), 0, stream>>>(mw_g, Pq, att_rb, nblk);
    k_head<<<dim3(nblk), dim3(128), 0, stream>>>(h_f32, att_rb, Wq1T, b_q1,
                                                 Wq2T, b_q2, out_q, b0, nblk);
  }
}

// Round 11
// 1011.861 us; speedup vs baseline: 11.9166x; 11.9166x over previous
//
#include <hip/hip_runtime.h>
#include <hip/hip_bf16.h>

typedef __hip_bfloat16 bf16;

#define BZc 64
#define NAc 64
#define Dc 128
#define Rc 3
#define Hc 4
#define INc 96
#define NACTc 20

// fixed workspace layout (float element offsets)
#define WM1_OFF    0        // 16384 : W_m1 others-half, float4-permuted by dm
#define WM2_OFF    16384    // 16384 : W_m2 float4-permuted
#define WS1_OFF    32768    // 24576 : W_s1 msg-half, float4-permuted by du
#define WM1ST_OFF  57344    // 16384 : W_m1 self-half, transposed [c][dm]
#define WS1ST_OFF  73728    // 24576 : W_s1 self-half, transposed [r][c][du]
#define WENCT_OFF  98304    // 12288 : W_enc^T [c][128]
#define WIHT_OFF   110592   // 49152 : W_ih^T  [c][384]
#define WHHT_OFF   159744   // 49152 : W_hh^T  [c][384]
#define WOTHT_OFF  208896   // 16384 : W_oth^T [c][128]
#define WQ1T_OFF   225280   // 32768 : W_q1^T  [c][128]
#define WQ2T_OFF   258048   // 2560  : W_q2^T  [c][20]
#define MH_OFF     260608   // 196608: Mhq[r][hh] float4-permuted (Wq_h^T Wk_h)
#define P_OFF      457216   // 196608: Pq[r] float4-permuted (k=hh*128+d major)
#define CHUNK_BASE 655360   // floats; per-chunk region starts here

// ---------------- weight permute / transpose kernel ----------------
__global__ void kW(const float* __restrict__ W_m1, const float* __restrict__ W_m2,
                   const float* __restrict__ W_s1, const float* __restrict__ W_enc,
                   const float* __restrict__ W_ih, const float* __restrict__ W_hh,
                   const float* __restrict__ W_oth, const float* __restrict__ W_q1,
                   const float* __restrict__ W_q2, float* __restrict__ ws) {
  int idx = blockIdx.x * blockDim.x + threadIdx.x;
  if (idx < 16384) {
    int dm = idx & 127, c = idx >> 7;
    ws[WM1_OFF + ((c >> 2) * 128 + dm) * 4 + (c & 3)] = W_m1[dm * 256 + c];
  } else if (idx < 32768) {
    int k = idx - 16384;
    int dm = k & 127, c = k >> 7;
    ws[WM2_OFF + ((c >> 2) * 128 + dm) * 4 + (c & 3)] = W_m2[dm * 128 + c];
  } else if (idx < 57344) {
    int k = idx - 32768;
    int r = k >> 13, rem = k & 8191;
    int du = rem & 63, c = rem >> 6;
    ws[WS1_OFF + r * 8192 + ((c >> 2) * 64 + du) * 4 + (c & 3)] =
        W_s1[(r * 64 + du) * 256 + 128 + c];
  } else if (idx < 73728) {
    int k = idx - 57344;
    int dm = k & 127, c = k >> 7;
    ws[WM1ST_OFF + c * 128 + dm] = W_m1[dm * 256 + 128 + c];
  } else if (idx < 98304) {
    int k = idx - 73728;
    int r = k >> 13, rem = k & 8191;
    int du = rem & 63, c = rem >> 6;
    ws[WS1ST_OFF + r * 8192 + c * 64 + du] = W_s1[(r * 64 + du) * 256 + c];
  } else if (idx < 110592) {
    int k = idx - 98304;              // W_encT [96][128]
    int o = k & 127, c = k >> 7;
    ws[WENCT_OFF + c * 128 + o] = W_enc[o * 96 + c];
  } else if (idx < 159744) {
    int k = idx - 110592;             // W_ihT [128][384]
    int o = k % 384, c = k / 384;
    ws[WIHT_OFF + c * 384 + o] = W_ih[o * 128 + c];
  } else if (idx < 208896) {
    int k = idx - 159744;             // W_hhT [128][384]
    int o = k % 384, c = k / 384;
    ws[WHHT_OFF + c * 384 + o] = W_hh[o * 128 + c];
  } else if (idx < 225280) {
    int k = idx - 208896;             // W_othT [128][128]
    int o = k & 127, c = k >> 7;
    ws[WOTHT_OFF + c * 128 + o] = W_oth[o * 128 + c];
  } else if (idx < 258048) {
    int k = idx - 225280;             // W_q1T [256][128]
    int o = k & 127, c = k >> 7;
    ws[WQ1T_OFF + c * 128 + o] = W_q1[o * 256 + c];
  } else if (idx < 260608) {
    int k = idx - 258048;             // W_q2T [128][20]
    int o = k % 20, c = k / 20;
    ws[WQ2T_OFF + c * 20 + o] = W_q2[o * 128 + c];
  }
}

// ---------------- per-head projection folds, stored float4-permuted ----------------
__global__ __launch_bounds__(256) void kMP(
    const float* __restrict__ Wq, const float* __restrict__ Wk,
    const float* __restrict__ Wv, const float* __restrict__ Wo,
    float* __restrict__ Mhq, float* __restrict__ Pq) {
  const int bid = blockIdx.x;  // 24 = r*8 + hh*2 + which
  const int which = bid & 1, hh = (bid >> 1) & 3, r = bid >> 3;
  const int t = threadIdx.x;
  __shared__ float A[4096];
  __shared__ float B[4224];
  if (which == 0) {
    for (int k = t; k < 4096; k += 256) {
      int e = k >> 7, c = k & 127;
      A[k] = Wq[(r * 128 + hh * 32 + e) * 128 + c];
      B[k] = Wk[(r * 128 + hh * 32 + e) * 128 + c];
    }
    __syncthreads();
    for (int k = 0; k < 64; ++k) {
      int o = k * 256 + t, c = o >> 7, d = o & 127;
      float a = 0.f;
      #pragma unroll 8
      for (int e = 0; e < 32; ++e) a += A[e * 128 + c] * B[e * 128 + d];
      Mhq[(size_t)(r * 4 + hh) * 16384 + ((c >> 2) * 128 + d) * 4 + (c & 3)] = a;
    }
  } else {
    for (int k = t; k < 4096; k += 256) A[k] = Wv[(r * 128 + hh * 32 + (k >> 7)) * 128 + (k & 127)];
    for (int k = t; k < 4096; k += 256) {
      int dp = k >> 5, e = k & 31;
      B[dp * 33 + e] = Wo[(r * 128 + dp) * 128 + hh * 32 + e];
    }
    __syncthreads();
    for (int k = 0; k < 64; ++k) {
      int o = k * 256 + t, d = o >> 7, dp = o & 127;
      float a = 0.f;
      #pragma unroll 8
      for (int e = 0; e < 32; ++e) a += A[e * 128 + d] * B[dp * 33 + e];
      int kk = hh * 128 + d;
      Pq[(size_t)r * 65536 + ((kk >> 2) * 128 + dp) * 4 + (kk & 3)] = a;
    }
  }
}

// ---------------- encoder + GRU + others ----------------
__global__ __launch_bounds__(128) void k_enc(
    const float* __restrict__ obs, const float* __restrict__ hidden,
    const float* __restrict__ WencT, const float* __restrict__ b_enc,
    const float* __restrict__ WihT, const float* __restrict__ WhhT,
    const float* __restrict__ b_ih, const float* __restrict__ b_hh,
    const float* __restrict__ WothT, const float* __restrict__ b_oth,
    float* __restrict__ h_f32, float* __restrict__ oth_f32,
    float* __restrict__ out_h, int b0) {
  const int row_l = blockIdx.x, t = threadIdx.x;
  const int row_g = b0 * 64 + row_l;
  __shared__ float obs_s[96], hid_s[128], x_s[128], h_s[128];
  if (t < 96) obs_s[t] = obs[row_g * 96 + t];
  hid_s[t] = hidden[row_g * 128 + t];
  __syncthreads();
  float x = b_enc[t];
  #pragma unroll 8
  for (int c = 0; c < 96; ++c) x += obs_s[c] * WencT[c * 128 + t];
  x_s[t] = x;
  __syncthreads();
  float gxr = b_ih[t], gxz = b_ih[t + 128], gxn = b_ih[t + 256];
  float ghr = b_hh[t], ghz = b_hh[t + 128], ghn = b_hh[t + 256];
  #pragma unroll 4
  for (int c = 0; c < 128; ++c) {
    float xv = x_s[c], hv = hid_s[c];
    const float* wi = WihT + c * 384 + t;
    const float* wh = WhhT + c * 384 + t;
    gxr += xv * wi[0]; gxz += xv * wi[128]; gxn += xv * wi[256];
    ghr += hv * wh[0]; ghz += hv * wh[128]; ghn += hv * wh[256];
  }
  float rg = 1.f / (1.f + expf(-(gxr + ghr)));
  float zg = 1.f / (1.f + expf(-(gxz + ghz)));
  float ng = tanhf(gxn + rg * ghn);
  float hv = (1.f - zg) * ng + zg * hid_s[t];
  h_s[t] = hv;
  h_f32[row_l * 128 + t] = hv;
  out_h[(size_t)row_g * 128 + t] = hv;
  __syncthreads();
  float o = b_oth[t];
  #pragma unroll 4
  for (int c = 0; c < 128; ++c) o += h_s[c] * WothT[c * 128 + t];
  oth_f32[row_l * 128 + t] = o;
}

// ---------------- message MLP + scheduler MLP (EXACT round-9 code: 775us known-good) ----
__global__ __launch_bounds__(256) void k_msg(
    const float* __restrict__ h_f32, const float* __restrict__ oth_f32,
    const float* __restrict__ Wm1q, const float* __restrict__ Wm1sT,
    const float* __restrict__ b_m1, const float* __restrict__ Wm2q,
    const float* __restrict__ b_m2, const float* __restrict__ Ws1q,
    const float* __restrict__ Ws1sT, const float* __restrict__ b_s1,
    const float* __restrict__ W_s2, const float* __restrict__ b_s2,
    bf16* __restrict__ msg_g, float* __restrict__ S_g, int nblk) {
  const int blk = blockIdx.x;        // local: b_l*64 + i
  const int b = blk >> 6;
  const int t = threadIdx.x;
  __shared__ float oth_s[64 * 128];  // 32KB: others; becomes msg after layer 2
  __shared__ float tact[64 * 128];   // 32KB
  const int dq = t & 31;             // dm quad: dm = dq + 32*k, k=0..3
  const int jb = (t >> 5) * 8;       // 8 j-groups of 8
  const int l = t & 63, wv = t >> 6; // scheduler mapping (l = du = lane)

  // cooperative load of others rows for this batch element
  {
    const float* ob = oth_f32 + (size_t)b * 8192;
    for (int k = t; k < 8192; k += 256) oth_s[k] = ob[k];
  }
  // per-thread self-half partial sums (seed + ascending c, as before)
  float sp0 = b_m1[dq], sp1v = b_m1[dq + 32], sp2 = b_m1[dq + 64], sp3 = b_m1[dq + 96];
  float spS0 = b_s1[l], spS1 = b_s1[64 + l], spS2 = b_s1[128 + l];
  {
    const float* hrow = h_f32 + (size_t)blk * 128;
    #pragma unroll 4
    for (int c = 0; c < 128; ++c) {
      float hv = hrow[c];
      const float* wt = Wm1sT + c * 128;
      sp0  += hv * wt[dq];
      sp1v += hv * wt[dq + 32];
      sp2  += hv * wt[dq + 64];
      sp3  += hv * wt[dq + 96];
      spS0 += hv * Ws1sT[c * 64 + l];
      spS1 += hv * Ws1sT[8192 + c * 64 + l];
      spS2 += hv * Ws1sT[16384 + c * 64 + l];
    }
  }
  __syncthreads();
  // ---- message layer 1: c4-outer, 8 j inner, 4 dm per thread ----
  {
    float a0[8], a1[8], a2[8], a3[8];
    #pragma unroll
    for (int j = 0; j < 8; ++j) { a0[j] = sp0; a1[j] = sp1v; a2[j] = sp2; a3[j] = sp3; }
    const float4* wq = (const float4*)Wm1q;
    for (int c4 = 0; c4 < 32; ++c4) {
      float4 w0 = wq[c4 * 128 + dq];
      float4 w1 = wq[c4 * 128 + dq + 32];
      float4 w2 = wq[c4 * 128 + dq + 64];
      float4 w3 = wq[c4 * 128 + dq + 96];
      #pragma unroll
      for (int j = 0; j < 8; ++j) {
        float4 v = *(const float4*)&oth_s[(jb + j) * 128 + c4 * 4];
        a0[j] += v.x * w0.x; a0[j] += v.y * w0.y; a0[j] += v.z * w0.z; a0[j] += v.w * w0.w;
        a1[j] += v.x * w1.x; a1[j] += v.y * w1.y; a1[j] += v.z * w1.z; a1[j] += v.w * w1.w;
        a2[j] += v.x * w2.x; a2[j] += v.y * w2.y; a2[j] += v.z * w2.z; a2[j] += v.w * w2.w;
        a3[j] += v.x * w3.x; a3[j] += v.y * w3.y; a3[j] += v.z * w3.z; a3[j] += v.w * w3.w;
      }
    }
    #pragma unroll
    for (int j = 0; j < 8; ++j) {
      tact[(jb + j) * 128 + dq]      = fmaxf(a0[j], 0.f);
      tact[(jb + j) * 128 + dq + 32] = fmaxf(a1[j], 0.f);
      tact[(jb + j) * 128 + dq + 64] = fmaxf(a2[j], 0.f);
      tact[(jb + j) * 128 + dq + 96] = fmaxf(a3[j], 0.f);
    }
  }
  __syncthreads();
  // ---- message layer 2: reads tact, overwrites oth_s with msg ----
  {
    float a0[8], a1[8], a2[8], a3[8];
    const float s0 = b_m2[dq], s1 = b_m2[dq + 32], s2 = b_m2[dq + 64], s3 = b_m2[dq + 96];
    #pragma unroll
    for (int j = 0; j < 8; ++j) { a0[j] = s0; a1[j] = s1; a2[j] = s2; a3[j] = s3; }
    const float4* wq = (const float4*)Wm2q;
    for (int c4 = 0; c4 < 32; ++c4) {
      float4 w0 = wq[c4 * 128 + dq];
      float4 w1 = wq[c4 * 128 + dq + 32];
      float4 w2 = wq[c4 * 128 + dq + 64];
      float4 w3 = wq[c4 * 128 + dq + 96];
      #pragma unroll
      for (int j = 0; j < 8; ++j) {
        float4 v = *(const float4*)&tact[(jb + j) * 128 + c4 * 4];
        a0[j] += v.x * w0.x; a0[j] += v.y * w0.y; a0[j] += v.z * w0.z; a0[j] += v.w * w0.w;
        a1[j] += v.x * w1.x; a1[j] += v.y * w1.y; a1[j] += v.z * w1.z; a1[j] += v.w * w1.w;
        a2[j] += v.x * w2.x; a2[j] += v.y * w2.y; a2[j] += v.z * w2.z; a2[j] += v.w * w2.w;
        a3[j] += v.x * w3.x; a3[j] += v.y * w3.y; a3[j] += v.z * w3.z; a3[j] += v.w * w3.w;
      }
    }
    #pragma unroll
    for (int j = 0; j < 8; ++j) {
      float m0 = fmaxf(a0[j], 0.f), m1 = fmaxf(a1[j], 0.f);
      float m2 = fmaxf(a2[j], 0.f), m3 = fmaxf(a3[j], 0.f);
      oth_s[(jb + j) * 128 + dq]      = m0;
      oth_s[(jb + j) * 128 + dq + 32] = m1;
      oth_s[(jb + j) * 128 + dq + 64] = m2;
      oth_s[(jb + j) * 128 + dq + 96] = m3;
      bf16* mg = msg_g + ((size_t)blk * 64 + (jb + j)) * 128 + dq;
      mg[0]  = __float2bfloat16(m0);
      mg[32] = __float2bfloat16(m1);
      mg[64] = __float2bfloat16(m2);
      mg[96] = __float2bfloat16(m3);
    }
  }
  __syncthreads();
  // ---- scheduler MLP: c4-outer accumulation (same per-output order),
  //      butterfly reduction kept identical (l = du lane mapping) ----
  const float spSr[3] = {spS0, spS1, spS2};
  for (int r = 0; r < 3; ++r) {
    const float4* wq = (const float4*)(Ws1q + r * 8192);
    const float w2a = W_s2[(r * 2 + 0) * 64 + l];
    const float w2b = W_s2[(r * 2 + 1) * 64 + l];
    const float bs2a = b_s2[r * 2 + 0], bs2b = b_s2[r * 2 + 1];
    float ua[16];
    #pragma unroll
    for (int j = 0; j < 16; ++j) ua[j] = spSr[r];
    for (int c4 = 0; c4 < 32; ++c4) {
      float4 w = wq[c4 * 64 + l];
      #pragma unroll
      for (int j = 0; j < 16; ++j) {
        float4 v = *(const float4*)&oth_s[(wv * 16 + j) * 128 + c4 * 4];
        ua[j] += v.x * w.x + v.y * w.y + v.z * w.z + v.w * w.w;
      }
    }
    for (int j = 0; j < 16; ++j) {
      float u = fmaxf(ua[j], 0.f);
      float v0 = u * w2a, v1 = u * w2b;
      #pragma unroll
      for (int s = 1; s < 64; s <<= 1) {
        v0 += __shfl_xor(v0, s, 64);
        v1 += __shfl_xor(v1, s, 64);
      }
      if (l == 0) {
        float* sp = S_g + (((size_t)r * nblk + blk) * 64 + (wv * 16 + j)) * 2;
        sp[0] = v0 + bs2a;
        sp[1] = v1 + bs2b;
      }
    }
  }
}

// ---------------- batched qW = h @ Mh (Mh read once per 64 agents) ----------------
__global__ __launch_bounds__(256) void k_qw(
    const float* __restrict__ h_f32, const float* __restrict__ Mhq,
    float* __restrict__ qW_g, int nblk) {
  const int b = blockIdx.x, r = blockIdx.y, t = threadIdx.x;
  __shared__ float h_s[8192];
  for (int k = t; k < 8192; k += 256) h_s[k] = h_f32[(size_t)b * 8192 + k];
  __syncthreads();
  const int dq = t & 31, ib = (t >> 5) * 8;
  for (int hh = 0; hh < 4; ++hh) {
    float a0[8], a1[8], a2[8], a3[8];
    #pragma unroll
    for (int i = 0; i < 8; ++i) { a0[i] = 0.f; a1[i] = 0.f; a2[i] = 0.f; a3[i] = 0.f; }
    const float4* mq = (const float4*)(Mhq + (size_t)(r * 4 + hh) * 16384);
    for (int c4 = 0; c4 < 32; ++c4) {
      float4 w0 = mq[c4 * 128 + dq];
      float4 w1 = mq[c4 * 128 + dq + 32];
      float4 w2 = mq[c4 * 128 + dq + 64];
      float4 w3 = mq[c4 * 128 + dq + 96];
      #pragma unroll
      for (int i = 0; i < 8; ++i) {
        float4 v = *(const float4*)&h_s[(ib + i) * 128 + c4 * 4];
        a0[i] += v.x * w0.x; a0[i] += v.y * w0.y; a0[i] += v.z * w0.z; a0[i] += v.w * w0.w;
        a1[i] += v.x * w1.x; a1[i] += v.y * w1.y; a1[i] += v.z * w1.z; a1[i] += v.w * w1.w;
        a2[i] += v.x * w2.x; a2[i] += v.y * w2.y; a2[i] += v.z * w2.z; a2[i] += v.w * w2.w;
        a3[i] += v.x * w3.x; a3[i] += v.y * w3.y; a3[i] += v.z * w3.z; a3[i] += v.w * w3.w;
      }
    }
    #pragma unroll
    for (int i = 0; i < 8; ++i) {
      float* qp = qW_g + ((size_t)r * nblk + b * 64 + ib + i) * 512 + hh * 128 + dq;
      qp[0]  = a0[i];
      qp[32] = a1[i];
      qp[64] = a2[i];
      qp[96] = a3[i];
    }
  }
}

// ---------------- adjacency + scores + masked softmax + mw (core) ----------------
__global__ __launch_bounds__(256) void k_attn(
    const bf16* __restrict__ msg_g, const float* __restrict__ S_g,
    const float* __restrict__ gumbel, const float* __restrict__ qW_g,
    float* __restrict__ mw_g, int b0, int nblk) {
  const int blk = blockIdx.x, r = blockIdx.y;
  const int b = blk >> 6, i = blk & 63, t = threadIdx.x;
  __shared__ float msg_s[64][132];
  __shared__ float qW_s[4][132];
  __shared__ float sc_s[320];
  __shared__ float adj_s[64];
  __shared__ float w_s[320];

  {
    const unsigned int* mb = (const unsigned int*)(msg_g + (size_t)blk * 8192);
    for (int k = t; k < 4096; k += 256) {
      unsigned int v = mb[k];
      int j = k >> 6, d2 = (k & 63) * 2;
      msg_s[j][d2]     = __uint_as_float(v << 16);
      msg_s[j][d2 + 1] = __uint_as_float(v & 0xffff0000u);
    }
  }
  for (int o = t; o < 512; o += 256)
    qW_s[o >> 7][o & 127] = qW_g[((size_t)r * nblk + blk) * 512 + o];
  if (t < 64) {
    const int j = t;
    const float* Sij = S_g + (((size_t)r * nblk + blk) * 64 + j) * 2;
    const float* Sji = S_g + (((size_t)r * nblk + b * 64 + j) * 64 + i) * 2;
    const float* g = gumbel + ((((size_t)r * 64 + (b0 + b)) * 64 + i) * 64 + j) * 2;
    float y0 = 0.5f * Sij[0] + 0.5f * Sji[0] + g[0];
    float y1 = 0.5f * Sij[1] + 0.5f * Sji[1] + g[1];
    adj_s[j] = (y1 > y0) ? 1.f : 0.f;
  }
  __syncthreads();
  // scores[j][hh]
  {
    const int j = t >> 2, hh = t & 3;
    float a = 0.f;
    #pragma unroll
    for (int d4 = 0; d4 < 32; ++d4) {
      float4 mv = *(const float4*)&msg_s[j][d4 * 4];
      float4 qv = *(const float4*)&qW_s[hh][d4 * 4];
      a += mv.x * qv.x + mv.y * qv.y + mv.z * qv.z + mv.w * qv.w;
    }
    sc_s[j * 5 + hh] = a * 0.17677669529663687f;  // 1/sqrt(32)
  }
  __syncthreads();
  // masked softmax per head (one wave per head)
  {
    const int hh = t >> 6, jj = t & 63;
    float v = sc_s[jj * 5 + hh];
    float mx = v;
    #pragma unroll
    for (int s = 32; s > 0; s >>= 1) mx = fmaxf(mx, __shfl_xor(mx, s, 64));
    float e = expf(v - mx);
    float ad = adj_s[jj];
    float E = e, Em = ad * e;
    #pragma unroll
    for (int s = 32; s > 0; s >>= 1) {
      E += __shfl_xor(E, s, 64);
      Em += __shfl_xor(Em, s, 64);
    }
    w_s[jj * 5 + hh] = ad * e / (Em + 1e-10f * E);
  }
  __syncthreads();
  // mw[hh][d] = sum_j w[j,hh] * msg[j,d]  -> mw_g
  {
    const int hh0 = t >> 7, d = t & 127;
    float a0 = 0.f, a1 = 0.f;
    for (int j = 0; j < 64; ++j) {
      float m = msg_s[j][d];
      a0 += w_s[j * 5 + hh0] * m;
      a1 += w_s[j * 5 + hh0 + 2] * m;
    }
    float* mp = mw_g + ((size_t)r * nblk + blk) * 512;
    mp[hh0 * 128 + d] = a0;
    mp[(hh0 + 2) * 128 + d] = a1;
  }
}

// ---------------- batched att = elu(mw @ P) (P read once per 64 agents) ----------------
__global__ __launch_bounds__(256) void k_pv(
    const float* __restrict__ mw_g, const float* __restrict__ Pq,
    float* __restrict__ att_r, int nblk) {
  const int b = blockIdx.x, r = blockIdx.y, t = threadIdx.x;
  const int dq = t & 31, ib = (t >> 5) * 8;
  float a0[8], a1[8], a2[8], a3[8];
  #pragma unroll
  for (int i = 0; i < 8; ++i) { a0[i] = 0.f; a1[i] = 0.f; a2[i] = 0.f; a3[i] = 0.f; }
  const float4* pq = (const float4*)(Pq + (size_t)r * 65536);
  const float* mwb = mw_g + ((size_t)r * nblk + b * 64) * 512;
  for (int c4 = 0; c4 < 128; ++c4) {
    float4 w0 = pq[c4 * 128 + dq];
    float4 w1 = pq[c4 * 128 + dq + 32];
    float4 w2 = pq[c4 * 128 + dq + 64];
    float4 w3 = pq[c4 * 128 + dq + 96];
    #pragma unroll
    for (int i = 0; i < 8; ++i) {
      float4 v = *(const float4*)&mwb[(size_t)(ib + i) * 512 + c4 * 4];
      a0[i] += v.x * w0.x; a0[i] += v.y * w0.y; a0[i] += v.z * w0.z; a0[i] += v.w * w0.w;
      a1[i] += v.x * w1.x; a1[i] += v.y * w1.y; a1[i] += v.z * w1.z; a1[i] += v.w * w1.w;
      a2[i] += v.x * w2.x; a2[i] += v.y * w2.y; a2[i] += v.z * w2.z; a2[i] += v.w * w2.w;
      a3[i] += v.x * w3.x; a3[i] += v.y * w3.y; a3[i] += v.z * w3.z; a3[i] += v.w * w3.w;
    }
  }
  #pragma unroll
  for (int i = 0; i < 8; ++i) {
    float* ap = att_r + ((size_t)r * nblk + b * 64 + ib + i) * 128 + dq;
    ap[0]  = (a0[i] > 0.f) ? a0[i] : expm1f(a0[i]);
    ap[32] = (a1[i] > 0.f) ? a1[i] : expm1f(a1[i]);
    ap[64] = (a2[i] > 0.f) ? a2[i] : expm1f(a2[i]);
    ap[96] = (a3[i] > 0.f) ? a3[i] : expm1f(a3[i]);
  }
}

// ---------------- mean over rounds + output head ----------------
__global__ __launch_bounds__(128) void k_head(
    const float* __restrict__ h_f32, const float* __restrict__ att_r,
    const float* __restrict__ Wq1T, const float* __restrict__ b_q1,
    const float* __restrict__ Wq2T, const float* __restrict__ b_q2,
    float* __restrict__ out_q, int b0, int nblk) {
  const int blk = blockIdx.x, t = threadIdx.x;
  __shared__ float hi[128], agg[128], u[128];
  hi[t] = h_f32[(size_t)blk * 128 + t];
  agg[t] = (att_r[(size_t)blk * 128 + t] +
            att_r[((size_t)nblk + blk) * 128 + t] +
            att_r[((size_t)2 * nblk + blk) * 128 + t]) * (1.f / 3.f);
  __syncthreads();
  float a = b_q1[t];
  #pragma unroll 4
  for (int c = 0; c < 128; ++c) a += hi[c] * Wq1T[c * 128 + t];
  #pragma unroll 4
  for (int c = 0; c < 128; ++c) a += agg[c] * Wq1T[(128 + c) * 128 + t];
  u[t] = fmaxf(a, 0.f);
  __syncthreads();
  if (t < 20) {
    float a2 = b_q2[t];
    #pragma unroll 4
    for (int c = 0; c < 128; ++c) a2 += u[c] * Wq2T[c * 20 + t];
    out_q[((size_t)b0 * 64 + blk) * 20 + t] = a2;
  }
}

extern "C" void kernel_launch(void* const* d_in, const int* in_sizes, int n_in,
                              void* d_out, int out_size, void* d_ws, size_t ws_size,
                              hipStream_t stream) {
  (void)in_sizes; (void)n_in; (void)out_size;
  const float* obs    = (const float*)d_in[0];
  const float* hidden = (const float*)d_in[1];
  const float* gumb   = (const float*)d_in[2];
  const float* W_enc  = (const float*)d_in[3];
  const float* b_enc  = (const float*)d_in[4];
  const float* W_ih   = (const float*)d_in[5];
  const float* W_hh   = (const float*)d_in[6];
  const float* b_ih   = (const float*)d_in[7];
  const float* b_hh   = (const float*)d_in[8];
  const float* W_oth  = (const float*)d_in[9];
  const float* b_oth  = (const float*)d_in[10];
  const float* W_m1   = (const float*)d_in[11];
  const float* b_m1   = (const float*)d_in[12];
  const float* W_m2   = (const float*)d_in[13];
  const float* b_m2   = (const float*)d_in[14];
  const float* W_s1   = (const float*)d_in[15];
  const float* b_s1   = (const float*)d_in[16];
  const float* W_s2   = (const float*)d_in[17];
  const float* b_s2   = (const float*)d_in[18];
  const float* Wq     = (const float*)d_in[19];
  const float* Wk     = (const float*)d_in[20];
  const float* Wv     = (const float*)d_in[21];
  const float* Wo     = (const float*)d_in[22];
  const float* W_q1   = (const float*)d_in[23];
  const float* b_q1   = (const float*)d_in[24];
  const float* W_q2   = (const float*)d_in[25];
  const float* b_q2   = (const float*)d_in[26];

  float* ws    = (float*)d_ws;
  float* Wm1q  = ws + WM1_OFF;
  float* Wm2q  = ws + WM2_OFF;
  float* Ws1q  = ws + WS1_OFF;
  float* Wm1sT = ws + WM1ST_OFF;
  float* Ws1sT = ws + WS1ST_OFF;
  float* WencT = ws + WENCT_OFF;
  float* WihT  = ws + WIHT_OFF;
  float* WhhT  = ws + WHHT_OFF;
  float* WothT = ws + WOTHT_OFF;
  float* Wq1T  = ws + WQ1T_OFF;
  float* Wq2T  = ws + WQ2T_OFF;
  float* Mhq   = ws + MH_OFF;
  float* Pq    = ws + P_OFF;

  float* out_q = (float*)d_out;  // f32 output: qout then h
  float* out_h = out_q + BZc * NAc * NACTc;

  // per-b chunk: h 32KB + oth 32KB + S 96KB + att 96KB + qW 384KB + mw 384KB + msg 1MB = 2MB
  int BC = 64;
  while (BC > 1) {
    size_t need = 4ull * CHUNK_BASE + (size_t)BC * 2097152ull;
    if (need <= ws_size) break;
    BC >>= 1;
  }
  const int nblk = BC * 64;
  float* h_f32   = ws + CHUNK_BASE;
  float* oth_f32 = h_f32 + (size_t)BC * 8192;
  float* S_g     = oth_f32 + (size_t)BC * 8192;
  float* att_rb  = S_g + (size_t)BC * 24576;
  float* qW_g    = att_rb + (size_t)BC * 24576;
  float* mw_g    = qW_g + (size_t)BC * 98304;
  bf16*  msg_g   = (bf16*)(mw_g + (size_t)BC * 98304);

  kW<<<dim3(1018), dim3(256), 0, stream>>>(W_m1, W_m2, W_s1, W_enc, W_ih, W_hh,
                                           W_oth, W_q1, W_q2, ws);
  kMP<<<dim3(24), dim3(256), 0, stream>>>(Wq, Wk, Wv, Wo, Mhq, Pq);
  for (int b0 = 0; b0 < BZc; b0 += BC) {
    k_enc<<<dim3(nblk), dim3(128), 0, stream>>>(obs, hidden, WencT, b_enc, WihT, WhhT,
                                                b_ih, b_hh, WothT, b_oth,
                                                h_f32, oth_f32, out_h, b0);
    k_msg<<<dim3(nblk), dim3(256), 0, stream>>>(h_f32, oth_f32, Wm1q, Wm1sT, b_m1,
                                                Wm2q, b_m2, Ws1q, Ws1sT, b_s1,
                                                W_s2, b_s2, msg_g, S_g, nblk);
    k_qw<<<dim3(BC, 3), dim3(256), 0, stream>>>(h_f32, Mhq, qW_g, nblk);
    k_attn<<<dim3(nblk, 3), dim3(256), 0, stream>>>(msg_g, S_g, gumb, qW_g,
                                                    mw_g, b0, nblk);
    k_pv<<<dim3(BC, 3), dim3(256), 0, stream>>>(mw_g, Pq, att_rb, nblk);
    k_head<<<dim3(nblk), dim3(128), 0, stream>>>(h_f32, att_rb, Wq1T, b_q1,
                                                 Wq2T, b_q2, out_q, b0, nblk);
  }
}

// Round 12
// 943.384 us; speedup vs baseline: 12.7816x; 1.0726x over previous
//
#include <hip/hip_runtime.h>
#include <hip/hip_bf16.h>

typedef __hip_bfloat16 bf16;

#define BZc 64
#define NAc 64
#define Dc 128
#define Rc 3
#define Hc 4
#define INc 96
#define NACTc 20

// fixed workspace layout (float element offsets)
#define WM1_OFF    0        // 16384 : W_m1 others-half, float4-permuted by dm
#define WM2_OFF    16384    // 16384 : W_m2 float4-permuted
#define WS1_OFF    32768    // 24576 : W_s1 msg-half, float4-permuted by du
#define WM1ST_OFF  57344    // 16384 : W_m1 self-half, transposed [c][dm]
#define WS1ST_OFF  73728    // 24576 : W_s1 self-half, transposed [r][c][du]
#define WENCT_OFF  98304    // 12288 : W_enc^T [c][128]
#define WIHT_OFF   110592   // 49152 : W_ih^T  [c][384]
#define WHHT_OFF   159744   // 49152 : W_hh^T  [c][384]
#define WOTHT_OFF  208896   // 16384 : W_oth^T [c][128]
#define WQ1T_OFF   225280   // 32768 : W_q1^T  [c][128]
#define WQ2T_OFF   258048   // 2560  : W_q2^T  [c][20]
#define MH_OFF     260608   // 196608: Mhq[r][hh] float4-permuted (Wq_h^T Wk_h)
#define P_OFF      457216   // 196608: Pq[r] float4-permuted (k=hh*128+d major)
#define CHUNK_BASE 655360   // floats; per-chunk region starts here

// ---------------- weight permute / transpose kernel ----------------
__global__ void kW(const float* __restrict__ W_m1, const float* __restrict__ W_m2,
                   const float* __restrict__ W_s1, const float* __restrict__ W_enc,
                   const float* __restrict__ W_ih, const float* __restrict__ W_hh,
                   const float* __restrict__ W_oth, const float* __restrict__ W_q1,
                   const float* __restrict__ W_q2, float* __restrict__ ws) {
  int idx = blockIdx.x * blockDim.x + threadIdx.x;
  if (idx < 16384) {
    int dm = idx & 127, c = idx >> 7;
    ws[WM1_OFF + ((c >> 2) * 128 + dm) * 4 + (c & 3)] = W_m1[dm * 256 + c];
  } else if (idx < 32768) {
    int k = idx - 16384;
    int dm = k & 127, c = k >> 7;
    ws[WM2_OFF + ((c >> 2) * 128 + dm) * 4 + (c & 3)] = W_m2[dm * 128 + c];
  } else if (idx < 57344) {
    int k = idx - 32768;
    int r = k >> 13, rem = k & 8191;
    int du = rem & 63, c = rem >> 6;
    ws[WS1_OFF + r * 8192 + ((c >> 2) * 64 + du) * 4 + (c & 3)] =
        W_s1[(r * 64 + du) * 256 + 128 + c];
  } else if (idx < 73728) {
    int k = idx - 57344;
    int dm = k & 127, c = k >> 7;
    ws[WM1ST_OFF + c * 128 + dm] = W_m1[dm * 256 + 128 + c];
  } else if (idx < 98304) {
    int k = idx - 73728;
    int r = k >> 13, rem = k & 8191;
    int du = rem & 63, c = rem >> 6;
    ws[WS1ST_OFF + r * 8192 + c * 64 + du] = W_s1[(r * 64 + du) * 256 + c];
  } else if (idx < 110592) {
    int k = idx - 98304;              // W_encT [96][128]
    int o = k & 127, c = k >> 7;
    ws[WENCT_OFF + c * 128 + o] = W_enc[o * 96 + c];
  } else if (idx < 159744) {
    int k = idx - 110592;             // W_ihT [128][384]
    int o = k % 384, c = k / 384;
    ws[WIHT_OFF + c * 384 + o] = W_ih[o * 128 + c];
  } else if (idx < 208896) {
    int k = idx - 159744;             // W_hhT [128][384]
    int o = k % 384, c = k / 384;
    ws[WHHT_OFF + c * 384 + o] = W_hh[o * 128 + c];
  } else if (idx < 225280) {
    int k = idx - 208896;             // W_othT [128][128]
    int o = k & 127, c = k >> 7;
    ws[WOTHT_OFF + c * 128 + o] = W_oth[o * 128 + c];
  } else if (idx < 258048) {
    int k = idx - 225280;             // W_q1T [256][128]
    int o = k & 127, c = k >> 7;
    ws[WQ1T_OFF + c * 128 + o] = W_q1[o * 256 + c];
  } else if (idx < 260608) {
    int k = idx - 258048;             // W_q2T [128][20]
    int o = k % 20, c = k / 20;
    ws[WQ2T_OFF + c * 20 + o] = W_q2[o * 128 + c];
  }
}

// ---------------- per-head projection folds, stored float4-permuted ----------------
__global__ __launch_bounds__(256) void kMP(
    const float* __restrict__ Wq, const float* __restrict__ Wk,
    const float* __restrict__ Wv, const float* __restrict__ Wo,
    float* __restrict__ Mhq, float* __restrict__ Pq) {
  const int bid = blockIdx.x;  // 24 = r*8 + hh*2 + which
  const int which = bid & 1, hh = (bid >> 1) & 3, r = bid >> 3;
  const int t = threadIdx.x;
  __shared__ float A[4096];
  __shared__ float B[4224];
  if (which == 0) {
    for (int k = t; k < 4096; k += 256) {
      int e = k >> 7, c = k & 127;
      A[k] = Wq[(r * 128 + hh * 32 + e) * 128 + c];
      B[k] = Wk[(r * 128 + hh * 32 + e) * 128 + c];
    }
    __syncthreads();
    for (int k = 0; k < 64; ++k) {
      int o = k * 256 + t, c = o >> 7, d = o & 127;
      float a = 0.f;
      #pragma unroll 8
      for (int e = 0; e < 32; ++e) a += A[e * 128 + c] * B[e * 128 + d];
      Mhq[(size_t)(r * 4 + hh) * 16384 + ((c >> 2) * 128 + d) * 4 + (c & 3)] = a;
    }
  } else {
    for (int k = t; k < 4096; k += 256) A[k] = Wv[(r * 128 + hh * 32 + (k >> 7)) * 128 + (k & 127)];
    for (int k = t; k < 4096; k += 256) {
      int dp = k >> 5, e = k & 31;
      B[dp * 33 + e] = Wo[(r * 128 + dp) * 128 + hh * 32 + e];
    }
    __syncthreads();
    for (int k = 0; k < 64; ++k) {
      int o = k * 256 + t, d = o >> 7, dp = o & 127;
      float a = 0.f;
      #pragma unroll 8
      for (int e = 0; e < 32; ++e) a += A[e * 128 + d] * B[dp * 33 + e];
      int kk = hh * 128 + d;
      Pq[(size_t)r * 65536 + ((kk >> 2) * 128 + dp) * 4 + (kk & 3)] = a;
    }
  }
}

// ---------------- encoder + GRU + others ----------------
__global__ __launch_bounds__(128) void k_enc(
    const float* __restrict__ obs, const float* __restrict__ hidden,
    const float* __restrict__ WencT, const float* __restrict__ b_enc,
    const float* __restrict__ WihT, const float* __restrict__ WhhT,
    const float* __restrict__ b_ih, const float* __restrict__ b_hh,
    const float* __restrict__ WothT, const float* __restrict__ b_oth,
    float* __restrict__ h_f32, float* __restrict__ oth_f32,
    float* __restrict__ out_h, int b0) {
  const int row_l = blockIdx.x, t = threadIdx.x;
  const int row_g = b0 * 64 + row_l;
  __shared__ float obs_s[96], hid_s[128], x_s[128], h_s[128];
  if (t < 96) obs_s[t] = obs[row_g * 96 + t];
  hid_s[t] = hidden[row_g * 128 + t];
  __syncthreads();
  float x = b_enc[t];
  #pragma unroll 8
  for (int c = 0; c < 96; ++c) x += obs_s[c] * WencT[c * 128 + t];
  x_s[t] = x;
  __syncthreads();
  float gxr = b_ih[t], gxz = b_ih[t + 128], gxn = b_ih[t + 256];
  float ghr = b_hh[t], ghz = b_hh[t + 128], ghn = b_hh[t + 256];
  #pragma unroll 4
  for (int c = 0; c < 128; ++c) {
    float xv = x_s[c], hv = hid_s[c];
    const float* wi = WihT + c * 384 + t;
    const float* wh = WhhT + c * 384 + t;
    gxr += xv * wi[0]; gxz += xv * wi[128]; gxn += xv * wi[256];
    ghr += hv * wh[0]; ghz += hv * wh[128]; ghn += hv * wh[256];
  }
  float rg = 1.f / (1.f + expf(-(gxr + ghr)));
  float zg = 1.f / (1.f + expf(-(gxz + ghz)));
  float ng = tanhf(gxn + rg * ghn);
  float hv = (1.f - zg) * ng + zg * hid_s[t];
  h_s[t] = hv;
  h_f32[row_l * 128 + t] = hv;
  out_h[(size_t)row_g * 128 + t] = hv;
  __syncthreads();
  float o = b_oth[t];
  #pragma unroll 4
  for (int c = 0; c < 128; ++c) o += h_s[c] * WothT[c * 128 + t];
  oth_f32[row_l * 128 + t] = o;
}

// ---------------- message MLP + scheduler MLP ----------------
// Round 12: scheduler's 3 rounds fused into ONE c4 pass (LDS reads 1536->512
// per thread). Per-output chains preserved (seed spS_r, ascending c4, same
// 4-term statement) -> S bit-exact. L1/L2 untouched from round 9.
__global__ __launch_bounds__(256) void k_msg(
    const float* __restrict__ h_f32, const float* __restrict__ oth_f32,
    const float* __restrict__ Wm1q, const float* __restrict__ Wm1sT,
    const float* __restrict__ b_m1, const float* __restrict__ Wm2q,
    const float* __restrict__ b_m2, const float* __restrict__ Ws1q,
    const float* __restrict__ Ws1sT, const float* __restrict__ b_s1,
    const float* __restrict__ W_s2, const float* __restrict__ b_s2,
    bf16* __restrict__ msg_g, float* __restrict__ S_g, int nblk) {
  const int blk = blockIdx.x;        // local: b_l*64 + i
  const int b = blk >> 6;
  const int t = threadIdx.x;
  __shared__ float oth_s[64 * 128];  // 32KB: others; becomes msg after layer 2
  __shared__ float tact[64 * 128];   // 32KB
  const int dq = t & 31;             // dm quad: dm = dq + 32*k, k=0..3
  const int jb = (t >> 5) * 8;       // 8 j-groups of 8
  const int l = t & 63, wv = t >> 6; // scheduler mapping (l = du = lane)

  // cooperative load of others rows for this batch element
  {
    const float* ob = oth_f32 + (size_t)b * 8192;
    for (int k = t; k < 8192; k += 256) oth_s[k] = ob[k];
  }
  // per-thread self-half partial sums (seed + ascending c, as before)
  float sp0 = b_m1[dq], sp1v = b_m1[dq + 32], sp2 = b_m1[dq + 64], sp3 = b_m1[dq + 96];
  float spS0 = b_s1[l], spS1 = b_s1[64 + l], spS2 = b_s1[128 + l];
  {
    const float* hrow = h_f32 + (size_t)blk * 128;
    #pragma unroll 4
    for (int c = 0; c < 128; ++c) {
      float hv = hrow[c];
      const float* wt = Wm1sT + c * 128;
      sp0  += hv * wt[dq];
      sp1v += hv * wt[dq + 32];
      sp2  += hv * wt[dq + 64];
      sp3  += hv * wt[dq + 96];
      spS0 += hv * Ws1sT[c * 64 + l];
      spS1 += hv * Ws1sT[8192 + c * 64 + l];
      spS2 += hv * Ws1sT[16384 + c * 64 + l];
    }
  }
  __syncthreads();
  // ---- message layer 1: c4-outer, 8 j inner, 4 dm per thread ----
  {
    float a0[8], a1[8], a2[8], a3[8];
    #pragma unroll
    for (int j = 0; j < 8; ++j) { a0[j] = sp0; a1[j] = sp1v; a2[j] = sp2; a3[j] = sp3; }
    const float4* wq = (const float4*)Wm1q;
    for (int c4 = 0; c4 < 32; ++c4) {
      float4 w0 = wq[c4 * 128 + dq];
      float4 w1 = wq[c4 * 128 + dq + 32];
      float4 w2 = wq[c4 * 128 + dq + 64];
      float4 w3 = wq[c4 * 128 + dq + 96];
      #pragma unroll
      for (int j = 0; j < 8; ++j) {
        float4 v = *(const float4*)&oth_s[(jb + j) * 128 + c4 * 4];
        a0[j] += v.x * w0.x; a0[j] += v.y * w0.y; a0[j] += v.z * w0.z; a0[j] += v.w * w0.w;
        a1[j] += v.x * w1.x; a1[j] += v.y * w1.y; a1[j] += v.z * w1.z; a1[j] += v.w * w1.w;
        a2[j] += v.x * w2.x; a2[j] += v.y * w2.y; a2[j] += v.z * w2.z; a2[j] += v.w * w2.w;
        a3[j] += v.x * w3.x; a3[j] += v.y * w3.y; a3[j] += v.z * w3.z; a3[j] += v.w * w3.w;
      }
    }
    #pragma unroll
    for (int j = 0; j < 8; ++j) {
      tact[(jb + j) * 128 + dq]      = fmaxf(a0[j], 0.f);
      tact[(jb + j) * 128 + dq + 32] = fmaxf(a1[j], 0.f);
      tact[(jb + j) * 128 + dq + 64] = fmaxf(a2[j], 0.f);
      tact[(jb + j) * 128 + dq + 96] = fmaxf(a3[j], 0.f);
    }
  }
  __syncthreads();
  // ---- message layer 2: reads tact, overwrites oth_s with msg ----
  {
    float a0[8], a1[8], a2[8], a3[8];
    const float s0 = b_m2[dq], s1 = b_m2[dq + 32], s2 = b_m2[dq + 64], s3 = b_m2[dq + 96];
    #pragma unroll
    for (int j = 0; j < 8; ++j) { a0[j] = s0; a1[j] = s1; a2[j] = s2; a3[j] = s3; }
    const float4* wq = (const float4*)Wm2q;
    for (int c4 = 0; c4 < 32; ++c4) {
      float4 w0 = wq[c4 * 128 + dq];
      float4 w1 = wq[c4 * 128 + dq + 32];
      float4 w2 = wq[c4 * 128 + dq + 64];
      float4 w3 = wq[c4 * 128 + dq + 96];
      #pragma unroll
      for (int j = 0; j < 8; ++j) {
        float4 v = *(const float4*)&tact[(jb + j) * 128 + c4 * 4];
        a0[j] += v.x * w0.x; a0[j] += v.y * w0.y; a0[j] += v.z * w0.z; a0[j] += v.w * w0.w;
        a1[j] += v.x * w1.x; a1[j] += v.y * w1.y; a1[j] += v.z * w1.z; a1[j] += v.w * w1.w;
        a2[j] += v.x * w2.x; a2[j] += v.y * w2.y; a2[j] += v.z * w2.z; a2[j] += v.w * w2.w;
        a3[j] += v.x * w3.x; a3[j] += v.y * w3.y; a3[j] += v.z * w3.z; a3[j] += v.w * w3.w;
      }
    }
    #pragma unroll
    for (int j = 0; j < 8; ++j) {
      float m0 = fmaxf(a0[j], 0.f), m1 = fmaxf(a1[j], 0.f);
      float m2 = fmaxf(a2[j], 0.f), m3 = fmaxf(a3[j], 0.f);
      oth_s[(jb + j) * 128 + dq]      = m0;
      oth_s[(jb + j) * 128 + dq + 32] = m1;
      oth_s[(jb + j) * 128 + dq + 64] = m2;
      oth_s[(jb + j) * 128 + dq + 96] = m3;
      bf16* mg = msg_g + ((size_t)blk * 64 + (jb + j)) * 128 + dq;
      mg[0]  = __float2bfloat16(m0);
      mg[32] = __float2bfloat16(m1);
      mg[64] = __float2bfloat16(m2);
      mg[96] = __float2bfloat16(m3);
    }
  }
  __syncthreads();
  // ---- scheduler MLP: ONE c4 pass accumulating all 3 rounds ----
  float ua0[16], ua1[16], ua2[16];
  #pragma unroll
  for (int j = 0; j < 16; ++j) { ua0[j] = spS0; ua1[j] = spS1; ua2[j] = spS2; }
  {
    const float4* wq0 = (const float4*)(Ws1q);
    const float4* wq1 = (const float4*)(Ws1q + 8192);
    const float4* wq2 = (const float4*)(Ws1q + 16384);
    for (int c4 = 0; c4 < 32; ++c4) {
      float4 w0 = wq0[c4 * 64 + l];
      float4 w1 = wq1[c4 * 64 + l];
      float4 w2 = wq2[c4 * 64 + l];
      #pragma unroll
      for (int j = 0; j < 16; ++j) {
        float4 v = *(const float4*)&oth_s[(wv * 16 + j) * 128 + c4 * 4];
        ua0[j] += v.x * w0.x + v.y * w0.y + v.z * w0.z + v.w * w0.w;
        ua1[j] += v.x * w1.x + v.y * w1.y + v.z * w1.z + v.w * w1.w;
        ua2[j] += v.x * w2.x + v.y * w2.y + v.z * w2.z + v.w * w2.w;
      }
    }
  }
  // butterfly + store per round (identical to round 9's form)
  {
    const float w2a = W_s2[0 * 64 + l], w2b = W_s2[1 * 64 + l];
    const float bs2a = b_s2[0], bs2b = b_s2[1];
    for (int j = 0; j < 16; ++j) {
      float u = fmaxf(ua0[j], 0.f);
      float v0 = u * w2a, v1 = u * w2b;
      #pragma unroll
      for (int s = 1; s < 64; s <<= 1) {
        v0 += __shfl_xor(v0, s, 64);
        v1 += __shfl_xor(v1, s, 64);
      }
      if (l == 0) {
        float* sp = S_g + (((size_t)0 * nblk + blk) * 64 + (wv * 16 + j)) * 2;
        sp[0] = v0 + bs2a;
        sp[1] = v1 + bs2b;
      }
    }
  }
  {
    const float w2a = W_s2[2 * 64 + l], w2b = W_s2[3 * 64 + l];
    const float bs2a = b_s2[2], bs2b = b_s2[3];
    for (int j = 0; j < 16; ++j) {
      float u = fmaxf(ua1[j], 0.f);
      float v0 = u * w2a, v1 = u * w2b;
      #pragma unroll
      for (int s = 1; s < 64; s <<= 1) {
        v0 += __shfl_xor(v0, s, 64);
        v1 += __shfl_xor(v1, s, 64);
      }
      if (l == 0) {
        float* sp = S_g + (((size_t)1 * nblk + blk) * 64 + (wv * 16 + j)) * 2;
        sp[0] = v0 + bs2a;
        sp[1] = v1 + bs2b;
      }
    }
  }
  {
    const float w2a = W_s2[4 * 64 + l], w2b = W_s2[5 * 64 + l];
    const float bs2a = b_s2[4], bs2b = b_s2[5];
    for (int j = 0; j < 16; ++j) {
      float u = fmaxf(ua2[j], 0.f);
      float v0 = u * w2a, v1 = u * w2b;
      #pragma unroll
      for (int s = 1; s < 64; s <<= 1) {
        v0 += __shfl_xor(v0, s, 64);
        v1 += __shfl_xor(v1, s, 64);
      }
      if (l == 0) {
        float* sp = S_g + (((size_t)2 * nblk + blk) * 64 + (wv * 16 + j)) * 2;
        sp[0] = v0 + bs2a;
        sp[1] = v1 + bs2b;
      }
    }
  }
}

// ---------------- batched qW = h @ Mh (Mh read once per 64 agents) ----------------
__global__ __launch_bounds__(256) void k_qw(
    const float* __restrict__ h_f32, const float* __restrict__ Mhq,
    float* __restrict__ qW_g, int nblk) {
  const int b = blockIdx.x, r = blockIdx.y, t = threadIdx.x;
  __shared__ float h_s[8192];
  for (int k = t; k < 8192; k += 256) h_s[k] = h_f32[(size_t)b * 8192 + k];
  __syncthreads();
  const int dq = t & 31, ib = (t >> 5) * 8;
  for (int hh = 0; hh < 4; ++hh) {
    float a0[8], a1[8], a2[8], a3[8];
    #pragma unroll
    for (int i = 0; i < 8; ++i) { a0[i] = 0.f; a1[i] = 0.f; a2[i] = 0.f; a3[i] = 0.f; }
    const float4* mq = (const float4*)(Mhq + (size_t)(r * 4 + hh) * 16384);
    for (int c4 = 0; c4 < 32; ++c4) {
      float4 w0 = mq[c4 * 128 + dq];
      float4 w1 = mq[c4 * 128 + dq + 32];
      float4 w2 = mq[c4 * 128 + dq + 64];
      float4 w3 = mq[c4 * 128 + dq + 96];
      #pragma unroll
      for (int i = 0; i < 8; ++i) {
        float4 v = *(const float4*)&h_s[(ib + i) * 128 + c4 * 4];
        a0[i] += v.x * w0.x; a0[i] += v.y * w0.y; a0[i] += v.z * w0.z; a0[i] += v.w * w0.w;
        a1[i] += v.x * w1.x; a1[i] += v.y * w1.y; a1[i] += v.z * w1.z; a1[i] += v.w * w1.w;
        a2[i] += v.x * w2.x; a2[i] += v.y * w2.y; a2[i] += v.z * w2.z; a2[i] += v.w * w2.w;
        a3[i] += v.x * w3.x; a3[i] += v.y * w3.y; a3[i] += v.z * w3.z; a3[i] += v.w * w3.w;
      }
    }
    #pragma unroll
    for (int i = 0; i < 8; ++i) {
      float* qp = qW_g + ((size_t)r * nblk + b * 64 + ib + i) * 512 + hh * 128 + dq;
      qp[0]  = a0[i];
      qp[32] = a1[i];
      qp[64] = a2[i];
      qp[96] = a3[i];
    }
  }
}

// ---------------- adjacency + scores + masked softmax + mw (core) ----------------
__global__ __launch_bounds__(256) void k_attn(
    const bf16* __restrict__ msg_g, const float* __restrict__ S_g,
    const float* __restrict__ gumbel, const float* __restrict__ qW_g,
    float* __restrict__ mw_g, int b0, int nblk) {
  const int blk = blockIdx.x, r = blockIdx.y;
  const int b = blk >> 6, i = blk & 63, t = threadIdx.x;
  __shared__ float msg_s[64][132];
  __shared__ float qW_s[4][132];
  __shared__ float sc_s[320];
  __shared__ float adj_s[64];
  __shared__ float w_s[320];

  {
    const unsigned int* mb = (const unsigned int*)(msg_g + (size_t)blk * 8192);
    for (int k = t; k < 4096; k += 256) {
      unsigned int v = mb[k];
      int j = k >> 6, d2 = (k & 63) * 2;
      msg_s[j][d2]     = __uint_as_float(v << 16);
      msg_s[j][d2 + 1] = __uint_as_float(v & 0xffff0000u);
    }
  }
  for (int o = t; o < 512; o += 256)
    qW_s[o >> 7][o & 127] = qW_g[((size_t)r * nblk + blk) * 512 + o];
  if (t < 64) {
    const int j = t;
    const float* Sij = S_g + (((size_t)r * nblk + blk) * 64 + j) * 2;
    const float* Sji = S_g + (((size_t)r * nblk + b * 64 + j) * 64 + i) * 2;
    const float* g = gumbel + ((((size_t)r * 64 + (b0 + b)) * 64 + i) * 64 + j) * 2;
    float y0 = 0.5f * Sij[0] + 0.5f * Sji[0] + g[0];
    float y1 = 0.5f * Sij[1] + 0.5f * Sji[1] + g[1];
    adj_s[j] = (y1 > y0) ? 1.f : 0.f;
  }
  __syncthreads();
  // scores[j][hh]
  {
    const int j = t >> 2, hh = t & 3;
    float a = 0.f;
    #pragma unroll
    for (int d4 = 0; d4 < 32; ++d4) {
      float4 mv = *(const float4*)&msg_s[j][d4 * 4];
      float4 qv = *(const float4*)&qW_s[hh][d4 * 4];
      a += mv.x * qv.x + mv.y * qv.y + mv.z * qv.z + mv.w * qv.w;
    }
    sc_s[j * 5 + hh] = a * 0.17677669529663687f;  // 1/sqrt(32)
  }
  __syncthreads();
  // masked softmax per head (one wave per head)
  {
    const int hh = t >> 6, jj = t & 63;
    float v = sc_s[jj * 5 + hh];
    float mx = v;
    #pragma unroll
    for (int s = 32; s > 0; s >>= 1) mx = fmaxf(mx, __shfl_xor(mx, s, 64));
    float e = expf(v - mx);
    float ad = adj_s[jj];
    float E = e, Em = ad * e;
    #pragma unroll
    for (int s = 32; s > 0; s >>= 1) {
      E += __shfl_xor(E, s, 64);
      Em += __shfl_xor(Em, s, 64);
    }
    w_s[jj * 5 + hh] = ad * e / (Em + 1e-10f * E);
  }
  __syncthreads();
  // mw[hh][d] = sum_j w[j,hh] * msg[j,d]  -> mw_g
  {
    const int hh0 = t >> 7, d = t & 127;
    float a0 = 0.f, a1 = 0.f;
    for (int j = 0; j < 64; ++j) {
      float m = msg_s[j][d];
      a0 += w_s[j * 5 + hh0] * m;
      a1 += w_s[j * 5 + hh0 + 2] * m;
    }
    float* mp = mw_g + ((size_t)r * nblk + blk) * 512;
    mp[hh0 * 128 + d] = a0;
    mp[(hh0 + 2) * 128 + d] = a1;
  }
}

// ---------------- batched att = elu(mw @ P) (P read once per 64 agents) ----------------
__global__ __launch_bounds__(256) void k_pv(
    const float* __restrict__ mw_g, const float* __restrict__ Pq,
    float* __restrict__ att_r, int nblk) {
  const int b = blockIdx.x, r = blockIdx.y, t = threadIdx.x;
  const int dq = t & 31, ib = (t >> 5) * 8;
  float a0[8], a1[8], a2[8], a3[8];
  #pragma unroll
  for (int i = 0; i < 8; ++i) { a0[i] = 0.f; a1[i] = 0.f; a2[i] = 0.f; a3[i] = 0.f; }
  const float4* pq = (const float4*)(Pq + (size_t)r * 65536);
  const float* mwb = mw_g + ((size_t)r * nblk + b * 64) * 512;
  for (int c4 = 0; c4 < 128; ++c4) {
    float4 w0 = pq[c4 * 128 + dq];
    float4 w1 = pq[c4 * 128 + dq + 32];
    float4 w2 = pq[c4 * 128 + dq + 64];
    float4 w3 = pq[c4 * 128 + dq + 96];
    #pragma unroll
    for (int i = 0; i < 8; ++i) {
      float4 v = *(const float4*)&mwb[(size_t)(ib + i) * 512 + c4 * 4];
      a0[i] += v.x * w0.x; a0[i] += v.y * w0.y; a0[i] += v.z * w0.z; a0[i] += v.w * w0.w;
      a1[i] += v.x * w1.x; a1[i] += v.y * w1.y; a1[i] += v.z * w1.z; a1[i] += v.w * w1.w;
      a2[i] += v.x * w2.x; a2[i] += v.y * w2.y; a2[i] += v.z * w2.z; a2[i] += v.w * w2.w;
      a3[i] += v.x * w3.x; a3[i] += v.y * w3.y; a3[i] += v.z * w3.z; a3[i] += v.w * w3.w;
    }
  }
  #pragma unroll
  for (int i = 0; i < 8; ++i) {
    float* ap = att_r + ((size_t)r * nblk + b * 64 + ib + i) * 128 + dq;
    ap[0]  = (a0[i] > 0.f) ? a0[i] : expm1f(a0[i]);
    ap[32] = (a1[i] > 0.f) ? a1[i] : expm1f(a1[i]);
    ap[64] = (a2[i] > 0.f) ? a2[i] : expm1f(a2[i]);
    ap[96] = (a3[i] > 0.f) ? a3[i] : expm1f(a3[i]);
  }
}

// ---------------- mean over rounds + output head ----------------
__global__ __launch_bounds__(128) void k_head(
    const float* __restrict__ h_f32, const float* __restrict__ att_r,
    const float* __restrict__ Wq1T, const float* __restrict__ b_q1,
    const float* __restrict__ Wq2T, const float* __restrict__ b_q2,
    float* __restrict__ out_q, int b0, int nblk) {
  const int blk = blockIdx.x, t = threadIdx.x;
  __shared__ float hi[128], agg[128], u[128];
  hi[t] = h_f32[(size_t)blk * 128 + t];
  agg[t] = (att_r[(size_t)blk * 128 + t] +
            att_r[((size_t)nblk + blk) * 128 + t] +
            att_r[((size_t)2 * nblk + blk) * 128 + t]) * (1.f / 3.f);
  __syncthreads();
  float a = b_q1[t];
  #pragma unroll 4
  for (int c = 0; c < 128; ++c) a += hi[c] * Wq1T[c * 128 + t];
  #pragma unroll 4
  for (int c = 0; c < 128; ++c) a += agg[c] * Wq1T[(128 + c) * 128 + t];
  u[t] = fmaxf(a, 0.f);
  __syncthreads();
  if (t < 20) {
    float a2 = b_q2[t];
    #pragma unroll 4
    for (int c = 0; c < 128; ++c) a2 += u[c] * Wq2T[c * 20 + t];
    out_q[((size_t)b0 * 64 + blk) * 20 + t] = a2;
  }
}

extern "C" void kernel_launch(void* const* d_in, const int* in_sizes, int n_in,
                              void* d_out, int out_size, void* d_ws, size_t ws_size,
                              hipStream_t stream) {
  (void)in_sizes; (void)n_in; (void)out_size;
  const float* obs    = (const float*)d_in[0];
  const float* hidden = (const float*)d_in[1];
  const float* gumb   = (const float*)d_in[2];
  const float* W_enc  = (const float*)d_in[3];
  const float* b_enc  = (const float*)d_in[4];
  const float* W_ih   = (const float*)d_in[5];
  const float* W_hh   = (const float*)d_in[6];
  const float* b_ih   = (const float*)d_in[7];
  const float* b_hh   = (const float*)d_in[8];
  const float* W_oth  = (const float*)d_in[9];
  const float* b_oth  = (const float*)d_in[10];
  const float* W_m1   = (const float*)d_in[11];
  const float* b_m1   = (const float*)d_in[12];
  const float* W_m2   = (const float*)d_in[13];
  const float* b_m2   = (const float*)d_in[14];
  const float* W_s1   = (const float*)d_in[15];
  const float* b_s1   = (const float*)d_in[16];
  const float* W_s2   = (const float*)d_in[17];
  const float* b_s2   = (const float*)d_in[18];
  const float* Wq     = (const float*)d_in[19];
  const float* Wk     = (const float*)d_in[20];
  const float* Wv     = (const float*)d_in[21];
  const float* Wo     = (const float*)d_in[22];
  const float* W_q1   = (const float*)d_in[23];
  const float* b_q1   = (const float*)d_in[24];
  const float* W_q2   = (const float*)d_in[25];
  const float* b_q2   = (const float*)d_in[26];

  float* ws    = (float*)d_ws;
  float* Wm1q  = ws + WM1_OFF;
  float* Wm2q  = ws + WM2_OFF;
  float* Ws1q  = ws + WS1_OFF;
  float* Wm1sT = ws + WM1ST_OFF;
  float* Ws1sT = ws + WS1ST_OFF;
  float* WencT = ws + WENCT_OFF;
  float* WihT  = ws + WIHT_OFF;
  float* WhhT  = ws + WHHT_OFF;
  float* WothT = ws + WOTHT_OFF;
  float* Wq1T  = ws + WQ1T_OFF;
  float* Wq2T  = ws + WQ2T_OFF;
  float* Mhq   = ws + MH_OFF;
  float* Pq    = ws + P_OFF;

  float* out_q = (float*)d_out;  // f32 output: qout then h
  float* out_h = out_q + BZc * NAc * NACTc;

  // per-b chunk: h 32KB + oth 32KB + S 96KB + att 96KB + qW 384KB + mw 384KB + msg 1MB = 2MB
  int BC = 64;
  while (BC > 1) {
    size_t need = 4ull * CHUNK_BASE + (size_t)BC * 2097152ull;
    if (need <= ws_size) break;
    BC >>= 1;
  }
  const int nblk = BC * 64;
  float* h_f32   = ws + CHUNK_BASE;
  float* oth_f32 = h_f32 + (size_t)BC * 8192;
  float* S_g     = oth_f32 + (size_t)BC * 8192;
  float* att_rb  = S_g + (size_t)BC * 24576;
  float* qW_g    = att_rb + (size_t)BC * 24576;
  float* mw_g    = qW_g + (size_t)BC * 98304;
  bf16*  msg_g   = (bf16*)(mw_g + (size_t)BC * 98304);

  kW<<<dim3(1018), dim3(256), 0, stream>>>(W_m1, W_m2, W_s1, W_enc, W_ih, W_hh,
                                           W_oth, W_q1, W_q2, ws);
  kMP<<<dim3(24), dim3(256), 0, stream>>>(Wq, Wk, Wv, Wo, Mhq, Pq);
  for (int b0 = 0; b0 < BZc; b0 += BC) {
    k_enc<<<dim3(nblk), dim3(128), 0, stream>>>(obs, hidden, WencT, b_enc, WihT, WhhT,
                                                b_ih, b_hh, WothT, b_oth,
                                                h_f32, oth_f32, out_h, b0);
    k_msg<<<dim3(nblk), dim3(256), 0, stream>>>(h_f32, oth_f32, Wm1q, Wm1sT, b_m1,
                                                Wm2q, b_m2, Ws1q, Ws1sT, b_s1,
                                                W_s2, b_s2, msg_g, S_g, nblk);
    k_qw<<<dim3(BC, 3), dim3(256), 0, stream>>>(h_f32, Mhq, qW_g, nblk);
    k_attn<<<dim3(nblk, 3), dim3(256), 0, stream>>>(msg_g, S_g, gumb, qW_g,
                                                    mw_g, b0, nblk);
    k_pv<<<dim3(BC, 3), dim3(256), 0, stream>>>(mw_g, Pq, att_rb, nblk);
    k_head<<<dim3(nblk), dim3(128), 0, stream>>>(h_f32, att_rb, Wq1T, b_q1,
                                                 Wq2T, b_q2, out_q, b0, nblk);
  }
}

// Round 14
// 895.685 us; speedup vs baseline: 13.4623x; 1.0533x over previous
//
#include <hip/hip_runtime.h>
#include <hip/hip_bf16.h>

typedef __hip_bfloat16 bf16;

#define BZc 64
#define NAc 64
#define Dc 128
#define Rc 3
#define Hc 4
#define INc 96
#define NACTc 20

// fixed workspace layout (float element offsets)
#define WM1_OFF    0        // 16384 : W_m1 others-half, float4-permuted by dm
#define WM2_OFF    16384    // 16384 : W_m2 float4-permuted
#define WS1_OFF    32768    // 24576 : W_s1 msg-half, float4-permuted by du
#define WM1ST_OFF  57344    // 16384 : W_m1 self-half, transposed [c][dm]
#define WS1ST_OFF  73728    // 24576 : W_s1 self-half, transposed [r][c][du]
#define WENCT_OFF  98304    // 12288 : W_enc^T [c][128]
#define WIHT_OFF   110592   // 49152 : W_ih^T  [c][384]
#define WHHT_OFF   159744   // 49152 : W_hh^T  [c][384]
#define WOTHT_OFF  208896   // 16384 : W_oth^T [c][128]
#define WQ1T_OFF   225280   // 32768 : W_q1^T  [c][128]
#define WQ2T_OFF   258048   // 2560  : W_q2^T  [c][20]
#define MH_OFF     260608   // 196608: Mhq[r][hh] float4-permuted (Wq_h^T Wk_h)
#define P_OFF      457216   // 196608: Pq[r] float4-permuted (k=hh*128+d major)
#define CHUNK_BASE 655360   // floats; per-chunk region starts here

// ---------------- weight permute / transpose kernel ----------------
__global__ void kW(const float* __restrict__ W_m1, const float* __restrict__ W_m2,
                   const float* __restrict__ W_s1, const float* __restrict__ W_enc,
                   const float* __restrict__ W_ih, const float* __restrict__ W_hh,
                   const float* __restrict__ W_oth, const float* __restrict__ W_q1,
                   const float* __restrict__ W_q2, float* __restrict__ ws) {
  int idx = blockIdx.x * blockDim.x + threadIdx.x;
  if (idx < 16384) {
    int dm = idx & 127, c = idx >> 7;
    ws[WM1_OFF + ((c >> 2) * 128 + dm) * 4 + (c & 3)] = W_m1[dm * 256 + c];
  } else if (idx < 32768) {
    int k = idx - 16384;
    int dm = k & 127, c = k >> 7;
    ws[WM2_OFF + ((c >> 2) * 128 + dm) * 4 + (c & 3)] = W_m2[dm * 128 + c];
  } else if (idx < 57344) {
    int k = idx - 32768;
    int r = k >> 13, rem = k & 8191;
    int du = rem & 63, c = rem >> 6;
    ws[WS1_OFF + r * 8192 + ((c >> 2) * 64 + du) * 4 + (c & 3)] =
        W_s1[(r * 64 + du) * 256 + 128 + c];
  } else if (idx < 73728) {
    int k = idx - 57344;
    int dm = k & 127, c = k >> 7;
    ws[WM1ST_OFF + c * 128 + dm] = W_m1[dm * 256 + 128 + c];
  } else if (idx < 98304) {
    int k = idx - 73728;
    int r = k >> 13, rem = k & 8191;
    int du = rem & 63, c = rem >> 6;
    ws[WS1ST_OFF + r * 8192 + c * 64 + du] = W_s1[(r * 64 + du) * 256 + c];
  } else if (idx < 110592) {
    int k = idx - 98304;              // W_encT [96][128]
    int o = k & 127, c = k >> 7;
    ws[WENCT_OFF + c * 128 + o] = W_enc[o * 96 + c];
  } else if (idx < 159744) {
    int k = idx - 110592;             // W_ihT [128][384]
    int o = k % 384, c = k / 384;
    ws[WIHT_OFF + c * 384 + o] = W_ih[o * 128 + c];
  } else if (idx < 208896) {
    int k = idx - 159744;             // W_hhT [128][384]
    int o = k % 384, c = k / 384;
    ws[WHHT_OFF + c * 384 + o] = W_hh[o * 128 + c];
  } else if (idx < 225280) {
    int k = idx - 208896;             // W_othT [128][128]
    int o = k & 127, c = k >> 7;
    ws[WOTHT_OFF + c * 128 + o] = W_oth[o * 128 + c];
  } else if (idx < 258048) {
    int k = idx - 225280;             // W_q1T [256][128]
    int o = k & 127, c = k >> 7;
    ws[WQ1T_OFF + c * 128 + o] = W_q1[o * 256 + c];
  } else if (idx < 260608) {
    int k = idx - 258048;             // W_q2T [128][20]
    int o = k % 20, c = k / 20;
    ws[WQ2T_OFF + c * 20 + o] = W_q2[o * 128 + c];
  }
}

// ---------------- per-head projection folds, stored float4-permuted ----------------
__global__ __launch_bounds__(256) void kMP(
    const float* __restrict__ Wq, const float* __restrict__ Wk,
    const float* __restrict__ Wv, const float* __restrict__ Wo,
    float* __restrict__ Mhq, float* __restrict__ Pq) {
  const int bid = blockIdx.x;  // 24 = r*8 + hh*2 + which
  const int which = bid & 1, hh = (bid >> 1) & 3, r = bid >> 3;
  const int t = threadIdx.x;
  __shared__ float A[4096];
  __shared__ float B[4224];
  if (which == 0) {
    for (int k = t; k < 4096; k += 256) {
      int e = k >> 7, c = k & 127;
      A[k] = Wq[(r * 128 + hh * 32 + e) * 128 + c];
      B[k] = Wk[(r * 128 + hh * 32 + e) * 128 + c];
    }
    __syncthreads();
    for (int k = 0; k < 64; ++k) {
      int o = k * 256 + t, c = o >> 7, d = o & 127;
      float a = 0.f;
      #pragma unroll 8
      for (int e = 0; e < 32; ++e) a += A[e * 128 + c] * B[e * 128 + d];
      Mhq[(size_t)(r * 4 + hh) * 16384 + ((c >> 2) * 128 + d) * 4 + (c & 3)] = a;
    }
  } else {
    for (int k = t; k < 4096; k += 256) A[k] = Wv[(r * 128 + hh * 32 + (k >> 7)) * 128 + (k & 127)];
    for (int k = t; k < 4096; k += 256) {
      int dp = k >> 5, e = k & 31;
      B[dp * 33 + e] = Wo[(r * 128 + dp) * 128 + hh * 32 + e];
    }
    __syncthreads();
    for (int k = 0; k < 64; ++k) {
      int o = k * 256 + t, d = o >> 7, dp = o & 127;
      float a = 0.f;
      #pragma unroll 8
      for (int e = 0; e < 32; ++e) a += A[e * 128 + d] * B[dp * 33 + e];
      int kk = hh * 128 + d;
      Pq[(size_t)r * 65536 + ((kk >> 2) * 128 + dp) * 4 + (kk & 3)] = a;
    }
  }
}

// ---------------- encoder + GRU + others ----------------
__global__ __launch_bounds__(128) void k_enc(
    const float* __restrict__ obs, const float* __restrict__ hidden,
    const float* __restrict__ WencT, const float* __restrict__ b_enc,
    const float* __restrict__ WihT, const float* __restrict__ WhhT,
    const float* __restrict__ b_ih, const float* __restrict__ b_hh,
    const float* __restrict__ WothT, const float* __restrict__ b_oth,
    float* __restrict__ h_f32, float* __restrict__ oth_f32,
    float* __restrict__ out_h, int b0) {
  const int row_l = blockIdx.x, t = threadIdx.x;
  const int row_g = b0 * 64 + row_l;
  __shared__ float obs_s[96], hid_s[128], x_s[128], h_s[128];
  if (t < 96) obs_s[t] = obs[row_g * 96 + t];
  hid_s[t] = hidden[row_g * 128 + t];
  __syncthreads();
  float x = b_enc[t];
  #pragma unroll 8
  for (int c = 0; c < 96; ++c) x += obs_s[c] * WencT[c * 128 + t];
  x_s[t] = x;
  __syncthreads();
  float gxr = b_ih[t], gxz = b_ih[t + 128], gxn = b_ih[t + 256];
  float ghr = b_hh[t], ghz = b_hh[t + 128], ghn = b_hh[t + 256];
  #pragma unroll 4
  for (int c = 0; c < 128; ++c) {
    float xv = x_s[c], hv = hid_s[c];
    const float* wi = WihT + c * 384 + t;
    const float* wh = WhhT + c * 384 + t;
    gxr += xv * wi[0]; gxz += xv * wi[128]; gxn += xv * wi[256];
    ghr += hv * wh[0]; ghz += hv * wh[128]; ghn += hv * wh[256];
  }
  float rg = 1.f / (1.f + expf(-(gxr + ghr)));
  float zg = 1.f / (1.f + expf(-(gxz + ghz)));
  float ng = tanhf(gxn + rg * ghn);
  float hv = (1.f - zg) * ng + zg * hid_s[t];
  h_s[t] = hv;
  h_f32[row_l * 128 + t] = hv;
  out_h[(size_t)row_g * 128 + t] = hv;
  __syncthreads();
  float o = b_oth[t];
  #pragma unroll 4
  for (int c = 0; c < 128; ++c) o += h_s[c] * WothT[c * 128 + t];
  oth_f32[row_l * 128 + t] = o;
}

// ---------------- self-half partial sums, hoisted (bit-exact chains) ----------------
// Thread t<128 computes sp1[dm=t]; t in [128,320) computes spS[r][du].
// Chain per output is IDENTICAL to round-12 k_msg's in-loop version:
// seed = bias, ascending c, one fma per step.
__global__ __launch_bounds__(320) void k_sp(
    const float* __restrict__ h_f32, const float* __restrict__ Wm1sT,
    const float* __restrict__ b_m1, const float* __restrict__ Ws1sT,
    const float* __restrict__ b_s1,
    float* __restrict__ sp1_g, float* __restrict__ spS_g) {
  const int blk = blockIdx.x, t = threadIdx.x;
  __shared__ float h_s[128];
  if (t < 128) h_s[t] = h_f32[(size_t)blk * 128 + t];
  __syncthreads();
  if (t < 128) {
    float a = b_m1[t];
    #pragma unroll 4
    for (int c = 0; c < 128; ++c) a += h_s[c] * Wm1sT[c * 128 + t];
    sp1_g[(size_t)blk * 128 + t] = a;
  } else {
    const int r = (t - 128) >> 6, du = (t - 128) & 63;
    float a = b_s1[r * 64 + du];
    #pragma unroll 4
    for (int c = 0; c < 128; ++c) a += h_s[c] * Ws1sT[r * 8192 + c * 64 + du];
    spS_g[(size_t)blk * 192 + r * 64 + du] = a;
  }
}

// ---------------- message MLP + scheduler MLP (round-12 body; sp values loaded) ----
__global__ __launch_bounds__(256) void k_msg(
    const float* __restrict__ oth_f32, const float* __restrict__ sp1_g,
    const float* __restrict__ spS_g, const float* __restrict__ Wm1q,
    const float* __restrict__ Wm2q, const float* __restrict__ b_m2,
    const float* __restrict__ Ws1q, const float* __restrict__ W_s2,
    const float* __restrict__ b_s2,
    bf16* __restrict__ msg_g, float* __restrict__ S_g, int nblk) {
  const int blk = blockIdx.x;        // local: b_l*64 + i
  const int b = blk >> 6;
  const int t = threadIdx.x;
  __shared__ float oth_s[64 * 128];  // 32KB: others; becomes msg after layer 2
  __shared__ float tact[64 * 128];   // 32KB
  const int dq = t & 31;             // dm quad: dm = dq + 32*k, k=0..3
  const int jb = (t >> 5) * 8;       // 8 j-groups of 8
  const int l = t & 63, wv = t >> 6; // scheduler mapping (l = du = lane)

  // cooperative load of others rows for this batch element
  {
    const float* ob = oth_f32 + (size_t)b * 8192;
    for (int k = t; k < 8192; k += 256) oth_s[k] = ob[k];
  }
  // self-half partial sums: precomputed by k_sp (bit-identical values)
  const float* spp = sp1_g + (size_t)blk * 128;
  const float sp0 = spp[dq], sp1v = spp[dq + 32], sp2 = spp[dq + 64], sp3 = spp[dq + 96];
  const float* sps = spS_g + (size_t)blk * 192;
  const float spS0 = sps[l], spS1 = sps[64 + l], spS2 = sps[128 + l];
  __syncthreads();
  // ---- message layer 1: c4-outer, 8 j inner, 4 dm per thread ----
  {
    float a0[8], a1[8], a2[8], a3[8];
    #pragma unroll
    for (int j = 0; j < 8; ++j) { a0[j] = sp0; a1[j] = sp1v; a2[j] = sp2; a3[j] = sp3; }
    const float4* wq = (const float4*)Wm1q;
    for (int c4 = 0; c4 < 32; ++c4) {
      float4 w0 = wq[c4 * 128 + dq];
      float4 w1 = wq[c4 * 128 + dq + 32];
      float4 w2 = wq[c4 * 128 + dq + 64];
      float4 w3 = wq[c4 * 128 + dq + 96];
      #pragma unroll
      for (int j = 0; j < 8; ++j) {
        float4 v = *(const float4*)&oth_s[(jb + j) * 128 + c4 * 4];
        a0[j] += v.x * w0.x; a0[j] += v.y * w0.y; a0[j] += v.z * w0.z; a0[j] += v.w * w0.w;
        a1[j] += v.x * w1.x; a1[j] += v.y * w1.y; a1[j] += v.z * w1.z; a1[j] += v.w * w1.w;
        a2[j] += v.x * w2.x; a2[j] += v.y * w2.y; a2[j] += v.z * w2.z; a2[j] += v.w * w2.w;
        a3[j] += v.x * w3.x; a3[j] += v.y * w3.y; a3[j] += v.z * w3.z; a3[j] += v.w * w3.w;
      }
    }
    #pragma unroll
    for (int j = 0; j < 8; ++j) {
      tact[(jb + j) * 128 + dq]      = fmaxf(a0[j], 0.f);
      tact[(jb + j) * 128 + dq + 32] = fmaxf(a1[j], 0.f);
      tact[(jb + j) * 128 + dq + 64] = fmaxf(a2[j], 0.f);
      tact[(jb + j) * 128 + dq + 96] = fmaxf(a3[j], 0.f);
    }
  }
  __syncthreads();
  // ---- message layer 2: reads tact, overwrites oth_s with msg ----
  {
    float a0[8], a1[8], a2[8], a3[8];
    const float s0 = b_m2[dq], s1 = b_m2[dq + 32], s2 = b_m2[dq + 64], s3 = b_m2[dq + 96];
    #pragma unroll
    for (int j = 0; j < 8; ++j) { a0[j] = s0; a1[j] = s1; a2[j] = s2; a3[j] = s3; }
    const float4* wq = (const float4*)Wm2q;
    for (int c4 = 0; c4 < 32; ++c4) {
      float4 w0 = wq[c4 * 128 + dq];
      float4 w1 = wq[c4 * 128 + dq + 32];
      float4 w2 = wq[c4 * 128 + dq + 64];
      float4 w3 = wq[c4 * 128 + dq + 96];
      #pragma unroll
      for (int j = 0; j < 8; ++j) {
        float4 v = *(const float4*)&tact[(jb + j) * 128 + c4 * 4];
        a0[j] += v.x * w0.x; a0[j] += v.y * w0.y; a0[j] += v.z * w0.z; a0[j] += v.w * w0.w;
        a1[j] += v.x * w1.x; a1[j] += v.y * w1.y; a1[j] += v.z * w1.z; a1[j] += v.w * w1.w;
        a2[j] += v.x * w2.x; a2[j] += v.y * w2.y; a2[j] += v.z * w2.z; a2[j] += v.w * w2.w;
        a3[j] += v.x * w3.x; a3[j] += v.y * w3.y; a3[j] += v.z * w3.z; a3[j] += v.w * w3.w;
      }
    }
    #pragma unroll
    for (int j = 0; j < 8; ++j) {
      float m0 = fmaxf(a0[j], 0.f), m1 = fmaxf(a1[j], 0.f);
      float m2 = fmaxf(a2[j], 0.f), m3 = fmaxf(a3[j], 0.f);
      oth_s[(jb + j) * 128 + dq]      = m0;
      oth_s[(jb + j) * 128 + dq + 32] = m1;
      oth_s[(jb + j) * 128 + dq + 64] = m2;
      oth_s[(jb + j) * 128 + dq + 96] = m3;
      bf16* mg = msg_g + ((size_t)blk * 64 + (jb + j)) * 128 + dq;
      mg[0]  = __float2bfloat16(m0);
      mg[32] = __float2bfloat16(m1);
      mg[64] = __float2bfloat16(m2);
      mg[96] = __float2bfloat16(m3);
    }
  }
  __syncthreads();
  // ---- scheduler MLP: ONE c4 pass accumulating all 3 rounds ----
  float ua0[16], ua1[16], ua2[16];
  #pragma unroll
  for (int j = 0; j < 16; ++j) { ua0[j] = spS0; ua1[j] = spS1; ua2[j] = spS2; }
  {
    const float4* wq0 = (const float4*)(Ws1q);
    const float4* wq1 = (const float4*)(Ws1q + 8192);
    const float4* wq2 = (const float4*)(Ws1q + 16384);
    for (int c4 = 0; c4 < 32; ++c4) {
      float4 w0 = wq0[c4 * 64 + l];
      float4 w1 = wq1[c4 * 64 + l];
      float4 w2 = wq2[c4 * 64 + l];
      #pragma unroll
      for (int j = 0; j < 16; ++j) {
        float4 v = *(const float4*)&oth_s[(wv * 16 + j) * 128 + c4 * 4];
        ua0[j] += v.x * w0.x + v.y * w0.y + v.z * w0.z + v.w * w0.w;
        ua1[j] += v.x * w1.x + v.y * w1.y + v.z * w1.z + v.w * w1.w;
        ua2[j] += v.x * w2.x + v.y * w2.y + v.z * w2.z + v.w * w2.w;
      }
    }
  }
  // butterfly + store per round (identical form to round 12)
  {
    const float w2a = W_s2[0 * 64 + l], w2b = W_s2[1 * 64 + l];
    const float bs2a = b_s2[0], bs2b = b_s2[1];
    for (int j = 0; j < 16; ++j) {
      float u = fmaxf(ua0[j], 0.f);
      float v0 = u * w2a, v1 = u * w2b;
      #pragma unroll
      for (int s = 1; s < 64; s <<= 1) {
        v0 += __shfl_xor(v0, s, 64);
        v1 += __shfl_xor(v1, s, 64);
      }
      if (l == 0) {
        float* sp = S_g + (((size_t)0 * nblk + blk) * 64 + (wv * 16 + j)) * 2;
        sp[0] = v0 + bs2a;
        sp[1] = v1 + bs2b;
      }
    }
  }
  {
    const float w2a = W_s2[2 * 64 + l], w2b = W_s2[3 * 64 + l];
    const float bs2a = b_s2[2], bs2b = b_s2[3];
    for (int j = 0; j < 16; ++j) {
      float u = fmaxf(ua1[j], 0.f);
      float v0 = u * w2a, v1 = u * w2b;
      #pragma unroll
      for (int s = 1; s < 64; s <<= 1) {
        v0 += __shfl_xor(v0, s, 64);
        v1 += __shfl_xor(v1, s, 64);
      }
      if (l == 0) {
        float* sp = S_g + (((size_t)1 * nblk + blk) * 64 + (wv * 16 + j)) * 2;
        sp[0] = v0 + bs2a;
        sp[1] = v1 + bs2b;
      }
    }
  }
  {
    const float w2a = W_s2[4 * 64 + l], w2b = W_s2[5 * 64 + l];
    const float bs2a = b_s2[4], bs2b = b_s2[5];
    for (int j = 0; j < 16; ++j) {
      float u = fmaxf(ua2[j], 0.f);
      float v0 = u * w2a, v1 = u * w2b;
      #pragma unroll
      for (int s = 1; s < 64; s <<= 1) {
        v0 += __shfl_xor(v0, s, 64);
        v1 += __shfl_xor(v1, s, 64);
      }
      if (l == 0) {
        float* sp = S_g + (((size_t)2 * nblk + blk) * 64 + (wv * 16 + j)) * 2;
        sp[0] = v0 + bs2a;
        sp[1] = v1 + bs2b;
      }
    }
  }
}

// ---------------- batched qW = h @ Mh (Mh read once per 64 agents) ----------------
__global__ __launch_bounds__(256) void k_qw(
    const float* __restrict__ h_f32, const float* __restrict__ Mhq,
    float* __restrict__ qW_g, int nblk) {
  const int b = blockIdx.x, r = blockIdx.y, t = threadIdx.x;
  __shared__ float h_s[8192];
  for (int k = t; k < 8192; k += 256) h_s[k] = h_f32[(size_t)b * 8192 + k];
  __syncthreads();
  const int dq = t & 31, ib = (t >> 5) * 8;
  for (int hh = 0; hh < 4; ++hh) {
    float a0[8], a1[8], a2[8], a3[8];
    #pragma unroll
    for (int i = 0; i < 8; ++i) { a0[i] = 0.f; a1[i] = 0.f; a2[i] = 0.f; a3[i] = 0.f; }
    const float4* mq = (const float4*)(Mhq + (size_t)(r * 4 + hh) * 16384);
    for (int c4 = 0; c4 < 32; ++c4) {
      float4 w0 = mq[c4 * 128 + dq];
      float4 w1 = mq[c4 * 128 + dq + 32];
      float4 w2 = mq[c4 * 128 + dq + 64];
      float4 w3 = mq[c4 * 128 + dq + 96];
      #pragma unroll
      for (int i = 0; i < 8; ++i) {
        float4 v = *(const float4*)&h_s[(ib + i) * 128 + c4 * 4];
        a0[i] += v.x * w0.x; a0[i] += v.y * w0.y; a0[i] += v.z * w0.z; a0[i] += v.w * w0.w;
        a1[i] += v.x * w1.x; a1[i] += v.y * w1.y; a1[i] += v.z * w1.z; a1[i] += v.w * w1.w;
        a2[i] += v.x * w2.x; a2[i] += v.y * w2.y; a2[i] += v.z * w2.z; a2[i] += v.w * w2.w;
        a3[i] += v.x * w3.x; a3[i] += v.y * w3.y; a3[i] += v.z * w3.z; a3[i] += v.w * w3.w;
      }
    }
    #pragma unroll
    for (int i = 0; i < 8; ++i) {
      float* qp = qW_g + ((size_t)r * nblk + b * 64 + ib + i) * 512 + hh * 128 + dq;
      qp[0]  = a0[i];
      qp[32] = a1[i];
      qp[64] = a2[i];
      qp[96] = a3[i];
    }
  }
}

// ---------------- adjacency + scores + masked softmax + mw (core) ----------------
__global__ __launch_bounds__(256) void k_attn(
    const bf16* __restrict__ msg_g, const float* __restrict__ S_g,
    const float* __restrict__ gumbel, const float* __restrict__ qW_g,
    float* __restrict__ mw_g, int b0, int nblk) {
  const int blk = blockIdx.x, r = blockIdx.y;
  const int b = blk >> 6, i = blk & 63, t = threadIdx.x;
  __shared__ float msg_s[64][132];
  __shared__ float qW_s[4][132];
  __shared__ float sc_s[320];
  __shared__ float adj_s[64];
  __shared__ float w_s[320];

  {
    const unsigned int* mb = (const unsigned int*)(msg_g + (size_t)blk * 8192);
    for (int k = t; k < 4096; k += 256) {
      unsigned int v = mb[k];
      int j = k >> 6, d2 = (k & 63) * 2;
      msg_s[j][d2]     = __uint_as_float(v << 16);
      msg_s[j][d2 + 1] = __uint_as_float(v & 0xffff0000u);
    }
  }
  for (int o = t; o < 512; o += 256)
    qW_s[o >> 7][o & 127] = qW_g[((size_t)r * nblk + blk) * 512 + o];
  if (t < 64) {
    const int j = t;
    const float* Sij = S_g + (((size_t)r * nblk + blk) * 64 + j) * 2;
    const float* Sji = S_g + (((size_t)r * nblk + b * 64 + j) * 64 + i) * 2;
    const float* g = gumbel + ((((size_t)r * 64 + (b0 + b)) * 64 + i) * 64 + j) * 2;
    float y0 = 0.5f * Sij[0] + 0.5f * Sji[0] + g[0];
    float y1 = 0.5f * Sij[1] + 0.5f * Sji[1] + g[1];
    adj_s[j] = (y1 > y0) ? 1.f : 0.f;
  }
  __syncthreads();
  // scores[j][hh]
  {
    const int j = t >> 2, hh = t & 3;
    float a = 0.f;
    #pragma unroll
    for (int d4 = 0; d4 < 32; ++d4) {
      float4 mv = *(const float4*)&msg_s[j][d4 * 4];
      float4 qv = *(const float4*)&qW_s[hh][d4 * 4];
      a += mv.x * qv.x + mv.y * qv.y + mv.z * qv.z + mv.w * qv.w;
    }
    sc_s[j * 5 + hh] = a * 0.17677669529663687f;  // 1/sqrt(32)
  }
  __syncthreads();
  // masked softmax per head (one wave per head)
  {
    const int hh = t >> 6, jj = t & 63;
    float v = sc_s[jj * 5 + hh];
    float mx = v;
    #pragma unroll
    for (int s = 32; s > 0; s >>= 1) mx = fmaxf(mx, __shfl_xor(mx, s, 64));
    float e = expf(v - mx);
    float ad = adj_s[jj];
    float E = e, Em = ad * e;
    #pragma unroll
    for (int s = 32; s > 0; s >>= 1) {
      E += __shfl_xor(E, s, 64);
      Em += __shfl_xor(Em, s, 64);
    }
    w_s[jj * 5 + hh] = ad * e / (Em + 1e-10f * E);
  }
  __syncthreads();
  // mw[hh][d] = sum_j w[j,hh] * msg[j,d]  -> mw_g
  {
    const int hh0 = t >> 7, d = t & 127;
    float a0 = 0.f, a1 = 0.f;
    for (int j = 0; j < 64; ++j) {
      float m = msg_s[j][d];
      a0 += w_s[j * 5 + hh0] * m;
      a1 += w_s[j * 5 + hh0 + 2] * m;
    }
    float* mp = mw_g + ((size_t)r * nblk + blk) * 512;
    mp[hh0 * 128 + d] = a0;
    mp[(hh0 + 2) * 128 + d] = a1;
  }
}

// ---------------- batched att = elu(mw @ P) (P read once per 64 agents) ----------------
__global__ __launch_bounds__(256) void k_pv(
    const float* __restrict__ mw_g, const float* __restrict__ Pq,
    float* __restrict__ att_r, int nblk) {
  const int b = blockIdx.x, r = blockIdx.y, t = threadIdx.x;
  const int dq = t & 31, ib = (t >> 5) * 8;
  float a0[8], a1[8], a2[8], a3[8];
  #pragma unroll
  for (int i = 0; i < 8; ++i) { a0[i] = 0.f; a1[i] = 0.f; a2[i] = 0.f; a3[i] = 0.f; }
  const float4* pq = (const float4*)(Pq + (size_t)r * 65536);
  const float* mwb = mw_g + ((size_t)r * nblk + b * 64) * 512;
  for (int c4 = 0; c4 < 128; ++c4) {
    float4 w0 = pq[c4 * 128 + dq];
    float4 w1 = pq[c4 * 128 + dq + 32];
    float4 w2 = pq[c4 * 128 + dq + 64];
    float4 w3 = pq[c4 * 128 + dq + 96];
    #pragma unroll
    for (int i = 0; i < 8; ++i) {
      float4 v = *(const float4*)&mwb[(size_t)(ib + i) * 512 + c4 * 4];
      a0[i] += v.x * w0.x; a0[i] += v.y * w0.y; a0[i] += v.z * w0.z; a0[i] += v.w * w0.w;
      a1[i] += v.x * w1.x; a1[i] += v.y * w1.y; a1[i] += v.z * w1.z; a1[i] += v.w * w1.w;
      a2[i] += v.x * w2.x; a2[i] += v.y * w2.y; a2[i] += v.z * w2.z; a2[i] += v.w * w2.w;
      a3[i] += v.x * w3.x; a3[i] += v.y * w3.y; a3[i] += v.z * w3.z; a3[i] += v.w * w3.w;
    }
  }
  #pragma unroll
  for (int i = 0; i < 8; ++i) {
    float* ap = att_r + ((size_t)r * nblk + b * 64 + ib + i) * 128 + dq;
    ap[0]  = (a0[i] > 0.f) ? a0[i] : expm1f(a0[i]);
    ap[32] = (a1[i] > 0.f) ? a1[i] : expm1f(a1[i]);
    ap[64] = (a2[i] > 0.f) ? a2[i] : expm1f(a2[i]);
    ap[96] = (a3[i] > 0.f) ? a3[i] : expm1f(a3[i]);
  }
}

// ---------------- mean over rounds + output head ----------------
__global__ __launch_bounds__(128) void k_head(
    const float* __restrict__ h_f32, const float* __restrict__ att_r,
    const float* __restrict__ Wq1T, const float* __restrict__ b_q1,
    const float* __restrict__ Wq2T, const float* __restrict__ b_q2,
    float* __restrict__ out_q, int b0, int nblk) {
  const int blk = blockIdx.x, t = threadIdx.x;
  __shared__ float hi[128], agg[128], u[128];
  hi[t] = h_f32[(size_t)blk * 128 + t];
  agg[t] = (att_r[(size_t)blk * 128 + t] +
            att_r[((size_t)nblk + blk) * 128 + t] +
            att_r[((size_t)2 * nblk + blk) * 128 + t]) * (1.f / 3.f);
  __syncthreads();
  float a = b_q1[t];
  #pragma unroll 4
  for (int c = 0; c < 128; ++c) a += hi[c] * Wq1T[c * 128 + t];
  #pragma unroll 4
  for (int c = 0; c < 128; ++c) a += agg[c] * Wq1T[(128 + c) * 128 + t];
  u[t] = fmaxf(a, 0.f);
  __syncthreads();
  if (t < 20) {
    float a2 = b_q2[t];
    #pragma unroll 4
    for (int c = 0; c < 128; ++c) a2 += u[c] * Wq2T[c * 20 + t];
    out_q[((size_t)b0 * 64 + blk) * 20 + t] = a2;
  }
}

extern "C" void kernel_launch(void* const* d_in, const int* in_sizes, int n_in,
                              void* d_out, int out_size, void* d_ws, size_t ws_size,
                              hipStream_t stream) {
  (void)in_sizes; (void)n_in; (void)out_size;
  const float* obs    = (const float*)d_in[0];
  const float* hidden = (const float*)d_in[1];
  const float* gumb   = (const float*)d_in[2];
  const float* W_enc  = (const float*)d_in[3];
  const float* b_enc  = (const float*)d_in[4];
  const float* W_ih   = (const float*)d_in[5];
  const float* W_hh   = (const float*)d_in[6];
  const float* b_ih   = (const float*)d_in[7];
  const float* b_hh   = (const float*)d_in[8];
  const float* W_oth  = (const float*)d_in[9];
  const float* b_oth  = (const float*)d_in[10];
  const float* W_m1   = (const float*)d_in[11];
  const float* b_m1   = (const float*)d_in[12];
  const float* W_m2   = (const float*)d_in[13];
  const float* b_m2   = (const float*)d_in[14];
  const float* W_s1   = (const float*)d_in[15];
  const float* b_s1   = (const float*)d_in[16];
  const float* W_s2   = (const float*)d_in[17];
  const float* b_s2   = (const float*)d_in[18];
  const float* Wq     = (const float*)d_in[19];
  const float* Wk     = (const float*)d_in[20];
  const float* Wv     = (const float*)d_in[21];
  const float* Wo     = (const float*)d_in[22];
  const float* W_q1   = (const float*)d_in[23];
  const float* b_q1   = (const float*)d_in[24];
  const float* W_q2   = (const float*)d_in[25];
  const float* b_q2   = (const float*)d_in[26];

  float* ws    = (float*)d_ws;
  float* Wm1q  = ws + WM1_OFF;
  float* Wm2q  = ws + WM2_OFF;
  float* Ws1q  = ws + WS1_OFF;
  float* Wm1sT = ws + WM1ST_OFF;
  float* Ws1sT = ws + WS1ST_OFF;
  float* WencT = ws + WENCT_OFF;
  float* WihT  = ws + WIHT_OFF;
  float* WhhT  = ws + WHHT_OFF;
  float* WothT = ws + WOTHT_OFF;
  float* Wq1T  = ws + WQ1T_OFF;
  float* Wq2T  = ws + WQ2T_OFF;
  float* Mhq   = ws + MH_OFF;
  float* Pq    = ws + P_OFF;

  float* out_q = (float*)d_out;  // f32 output: qout then h
  float* out_h = out_q + BZc * NAc * NACTc;

  // per-b chunk bytes: h 32K + oth 32K + sp1 32K + spS 48K + S 96K + att 96K
  //                    + qW 384K + mw 384K + msg(bf16) 1M = 2179072
  int BC = 64;
  while (BC > 1) {
    size_t need = 4ull * CHUNK_BASE + (size_t)BC * 2179072ull;
    if (need <= ws_size) break;
    BC >>= 1;
  }
  const int nblk = BC * 64;
  float* h_f32   = ws + CHUNK_BASE;
  float* oth_f32 = h_f32 + (size_t)BC * 8192;
  float* sp1_g   = oth_f32 + (size_t)BC * 8192;
  float* spS_g   = sp1_g + (size_t)BC * 8192;
  float* S_g     = spS_g + (size_t)BC * 12288;
  float* att_rb  = S_g + (size_t)BC * 24576;
  float* qW_g    = att_rb + (size_t)BC * 24576;
  float* mw_g    = qW_g + (size_t)BC * 98304;
  bf16*  msg_g   = (bf16*)(mw_g + (size_t)BC * 98304);

  kW<<<dim3(1018), dim3(256), 0, stream>>>(W_m1, W_m2, W_s1, W_enc, W_ih, W_hh,
                                           W_oth, W_q1, W_q2, ws);
  kMP<<<dim3(24), dim3(256), 0, stream>>>(Wq, Wk, Wv, Wo, Mhq, Pq);
  for (int b0 = 0; b0 < BZc; b0 += BC) {
    k_enc<<<dim3(nblk), dim3(128), 0, stream>>>(obs, hidden, WencT, b_enc, WihT, WhhT,
                                                b_ih, b_hh, WothT, b_oth,
                                                h_f32, oth_f32, out_h, b0);
    k_sp<<<dim3(nblk), dim3(320), 0, stream>>>(h_f32, Wm1sT, b_m1, Ws1sT, b_s1,
                                               sp1_g, spS_g);
    k_msg<<<dim3(nblk), dim3(256), 0, stream>>>(oth_f32, sp1_g, spS_g, Wm1q,
                                                Wm2q, b_m2, Ws1q,
                                                W_s2, b_s2, msg_g, S_g, nblk);
    k_qw<<<dim3(BC, 3), dim3(256), 0, stream>>>(h_f32, Mhq, qW_g, nblk);
    k_attn<<<dim3(nblk, 3), dim3(256), 0, stream>>>(msg_g, S_g, gumb, qW_g,
                                                    mw_g, b0, nblk);
    k_pv<<<dim3(BC, 3), dim3(256), 0, stream>>>(mw_g, Pq, att_rb, nblk);
    k_head<<<dim3(nblk), dim3(128), 0, stream>>>(h_f32, att_rb, Wq1T, b_q1,
                                                 Wq2T, b_q2, out_q, b0, nblk);
  }
}

// Round 15
// 799.975 us; speedup vs baseline: 15.0729x; 1.1196x over previous
//
#include <hip/hip_runtime.h>
#include <hip/hip_bf16.h>

typedef __hip_bfloat16 bf16;

#define BZc 64
#define NAc 64
#define Dc 128
#define Rc 3
#define Hc 4
#define INc 96
#define NACTc 20

// fixed workspace layout (float element offsets)
#define WM1_OFF    0        // 16384 : W_m1 others-half, float4-permuted by dm
#define WM2_OFF    16384    // 16384 : W_m2 float4-permuted
#define WS1_OFF    32768    // 24576 : W_s1 msg-half, float4-permuted by du
#define WM1ST_OFF  57344    // 16384 : W_m1 self-half, transposed [c][dm]
#define WS1ST_OFF  73728    // 24576 : W_s1 self-half, transposed [r][c][du]
#define WENCT_OFF  98304    // 12288 : W_enc^T [c][128]
#define WIHT_OFF   110592   // 49152 : W_ih^T  [c][384]
#define WHHT_OFF   159744   // 49152 : W_hh^T  [c][384]
#define WOTHT_OFF  208896   // 16384 : W_oth^T [c][128]
#define WQ1T_OFF   225280   // 32768 : W_q1^T  [c][128]
#define WQ2T_OFF   258048   // 2560  : W_q2^T  [c][20]
#define MH_OFF     260608   // 196608: Mhq[r][hh] float4-permuted (Wq_h^T Wk_h)
#define P_OFF      457216   // 196608: Pq[r] float4-permuted (k=hh*128+d major)
#define CHUNK_BASE 655360   // floats; per-chunk region starts here

// ---------------- weight permute / transpose kernel ----------------
__global__ void kW(const float* __restrict__ W_m1, const float* __restrict__ W_m2,
                   const float* __restrict__ W_s1, const float* __restrict__ W_enc,
                   const float* __restrict__ W_ih, const float* __restrict__ W_hh,
                   const float* __restrict__ W_oth, const float* __restrict__ W_q1,
                   const float* __restrict__ W_q2, float* __restrict__ ws) {
  int idx = blockIdx.x * blockDim.x + threadIdx.x;
  if (idx < 16384) {
    int dm = idx & 127, c = idx >> 7;
    ws[WM1_OFF + ((c >> 2) * 128 + dm) * 4 + (c & 3)] = W_m1[dm * 256 + c];
  } else if (idx < 32768) {
    int k = idx - 16384;
    int dm = k & 127, c = k >> 7;
    ws[WM2_OFF + ((c >> 2) * 128 + dm) * 4 + (c & 3)] = W_m2[dm * 128 + c];
  } else if (idx < 57344) {
    int k = idx - 32768;
    int r = k >> 13, rem = k & 8191;
    int du = rem & 63, c = rem >> 6;
    ws[WS1_OFF + r * 8192 + ((c >> 2) * 64 + du) * 4 + (c & 3)] =
        W_s1[(r * 64 + du) * 256 + 128 + c];
  } else if (idx < 73728) {
    int k = idx - 57344;
    int dm = k & 127, c = k >> 7;
    ws[WM1ST_OFF + c * 128 + dm] = W_m1[dm * 256 + 128 + c];
  } else if (idx < 98304) {
    int k = idx - 73728;
    int r = k >> 13, rem = k & 8191;
    int du = rem & 63, c = rem >> 6;
    ws[WS1ST_OFF + r * 8192 + c * 64 + du] = W_s1[(r * 64 + du) * 256 + c];
  } else if (idx < 110592) {
    int k = idx - 98304;              // W_encT [96][128]
    int o = k & 127, c = k >> 7;
    ws[WENCT_OFF + c * 128 + o] = W_enc[o * 96 + c];
  } else if (idx < 159744) {
    int k = idx - 110592;             // W_ihT [128][384]
    int o = k % 384, c = k / 384;
    ws[WIHT_OFF + c * 384 + o] = W_ih[o * 128 + c];
  } else if (idx < 208896) {
    int k = idx - 159744;             // W_hhT [128][384]
    int o = k % 384, c = k / 384;
    ws[WHHT_OFF + c * 384 + o] = W_hh[o * 128 + c];
  } else if (idx < 225280) {
    int k = idx - 208896;             // W_othT [128][128]
    int o = k & 127, c = k >> 7;
    ws[WOTHT_OFF + c * 128 + o] = W_oth[o * 128 + c];
  } else if (idx < 258048) {
    int k = idx - 225280;             // W_q1T [256][128]
    int o = k & 127, c = k >> 7;
    ws[WQ1T_OFF + c * 128 + o] = W_q1[o * 256 + c];
  } else if (idx < 260608) {
    int k = idx - 258048;             // W_q2T [128][20]
    int o = k % 20, c = k / 20;
    ws[WQ2T_OFF + c * 20 + o] = W_q2[o * 128 + c];
  }
}

// ---------------- per-head projection folds, stored float4-permuted ----------------
__global__ __launch_bounds__(256) void kMP(
    const float* __restrict__ Wq, const float* __restrict__ Wk,
    const float* __restrict__ Wv, const float* __restrict__ Wo,
    float* __restrict__ Mhq, float* __restrict__ Pq) {
  const int bid = blockIdx.x;  // 24 = r*8 + hh*2 + which
  const int which = bid & 1, hh = (bid >> 1) & 3, r = bid >> 3;
  const int t = threadIdx.x;
  __shared__ float A[4096];
  __shared__ float B[4224];
  if (which == 0) {
    for (int k = t; k < 4096; k += 256) {
      int e = k >> 7, c = k & 127;
      A[k] = Wq[(r * 128 + hh * 32 + e) * 128 + c];
      B[k] = Wk[(r * 128 + hh * 32 + e) * 128 + c];
    }
    __syncthreads();
    for (int k = 0; k < 64; ++k) {
      int o = k * 256 + t, c = o >> 7, d = o & 127;
      float a = 0.f;
      #pragma unroll 8
      for (int e = 0; e < 32; ++e) a += A[e * 128 + c] * B[e * 128 + d];
      Mhq[(size_t)(r * 4 + hh) * 16384 + ((c >> 2) * 128 + d) * 4 + (c & 3)] = a;
    }
  } else {
    for (int k = t; k < 4096; k += 256) A[k] = Wv[(r * 128 + hh * 32 + (k >> 7)) * 128 + (k & 127)];
    for (int k = t; k < 4096; k += 256) {
      int dp = k >> 5, e = k & 31;
      B[dp * 33 + e] = Wo[(r * 128 + dp) * 128 + hh * 32 + e];
    }
    __syncthreads();
    for (int k = 0; k < 64; ++k) {
      int o = k * 256 + t, d = o >> 7, dp = o & 127;
      float a = 0.f;
      #pragma unroll 8
      for (int e = 0; e < 32; ++e) a += A[e * 128 + d] * B[dp * 33 + e];
      int kk = hh * 128 + d;
      Pq[(size_t)r * 65536 + ((kk >> 2) * 128 + dp) * 4 + (kk & 3)] = a;
    }
  }
}

// ---------------- encoder + GRU + others ----------------
__global__ __launch_bounds__(128) void k_enc(
    const float* __restrict__ obs, const float* __restrict__ hidden,
    const float* __restrict__ WencT, const float* __restrict__ b_enc,
    const float* __restrict__ WihT, const float* __restrict__ WhhT,
    const float* __restrict__ b_ih, const float* __restrict__ b_hh,
    const float* __restrict__ WothT, const float* __restrict__ b_oth,
    float* __restrict__ h_f32, float* __restrict__ oth_f32,
    float* __restrict__ out_h, int b0) {
  const int row_l = blockIdx.x, t = threadIdx.x;
  const int row_g = b0 * 64 + row_l;
  __shared__ float obs_s[96], hid_s[128], x_s[128], h_s[128];
  if (t < 96) obs_s[t] = obs[row_g * 96 + t];
  hid_s[t] = hidden[row_g * 128 + t];
  __syncthreads();
  float x = b_enc[t];
  #pragma unroll 8
  for (int c = 0; c < 96; ++c) x += obs_s[c] * WencT[c * 128 + t];
  x_s[t] = x;
  __syncthreads();
  float gxr = b_ih[t], gxz = b_ih[t + 128], gxn = b_ih[t + 256];
  float ghr = b_hh[t], ghz = b_hh[t + 128], ghn = b_hh[t + 256];
  #pragma unroll 4
  for (int c = 0; c < 128; ++c) {
    float xv = x_s[c], hv = hid_s[c];
    const float* wi = WihT + c * 384 + t;
    const float* wh = WhhT + c * 384 + t;
    gxr += xv * wi[0]; gxz += xv * wi[128]; gxn += xv * wi[256];
    ghr += hv * wh[0]; ghz += hv * wh[128]; ghn += hv * wh[256];
  }
  float rg = 1.f / (1.f + expf(-(gxr + ghr)));
  float zg = 1.f / (1.f + expf(-(gxz + ghz)));
  float ng = tanhf(gxn + rg * ghn);
  float hv = (1.f - zg) * ng + zg * hid_s[t];
  h_s[t] = hv;
  h_f32[row_l * 128 + t] = hv;
  out_h[(size_t)row_g * 128 + t] = hv;
  __syncthreads();
  float o = b_oth[t];
  #pragma unroll 4
  for (int c = 0; c < 128; ++c) o += h_s[c] * WothT[c * 128 + t];
  oth_f32[row_l * 128 + t] = o;
}

// ---------------- self-half partial sums, hoisted (bit-exact chains) ----------------
__global__ __launch_bounds__(320) void k_sp(
    const float* __restrict__ h_f32, const float* __restrict__ Wm1sT,
    const float* __restrict__ b_m1, const float* __restrict__ Ws1sT,
    const float* __restrict__ b_s1,
    float* __restrict__ sp1_g, float* __restrict__ spS_g) {
  const int blk = blockIdx.x, t = threadIdx.x;
  __shared__ float h_s[128];
  if (t < 128) h_s[t] = h_f32[(size_t)blk * 128 + t];
  __syncthreads();
  if (t < 128) {
    float a = b_m1[t];
    #pragma unroll 4
    for (int c = 0; c < 128; ++c) a += h_s[c] * Wm1sT[c * 128 + t];
    sp1_g[(size_t)blk * 128 + t] = a;
  } else {
    const int r = (t - 128) >> 6, du = (t - 128) & 63;
    float a = b_s1[r * 64 + du];
    #pragma unroll 4
    for (int c = 0; c < 128; ++c) a += h_s[c] * Ws1sT[r * 8192 + c * 64 + du];
    spS_g[(size_t)blk * 192 + r * 64 + du] = a;
  }
}

// ---------------- i-invariant hoist: othp[b][j][dm] = others[b][j] @ W1_others^T ----
// 0-seeded, ascending c4, x/y/z/w order (round-13-validated chain).
__global__ __launch_bounds__(256) void k_othp(
    const float* __restrict__ oth_f32, const float* __restrict__ Wm1q,
    float* __restrict__ othp) {
  const int b = blockIdx.x, t = threadIdx.x;
  const int dq = t & 31, jb = (t >> 5) * 8;
  __shared__ float oth_s[8192];
  for (int k = t; k < 8192; k += 256) oth_s[k] = oth_f32[(size_t)b * 8192 + k];
  __syncthreads();
  float a0[8], a1[8], a2[8], a3[8];
  #pragma unroll
  for (int j = 0; j < 8; ++j) { a0[j] = 0.f; a1[j] = 0.f; a2[j] = 0.f; a3[j] = 0.f; }
  const float4* wq = (const float4*)Wm1q;
  for (int c4 = 0; c4 < 32; ++c4) {
    float4 w0 = wq[c4 * 128 + dq];
    float4 w1 = wq[c4 * 128 + dq + 32];
    float4 w2 = wq[c4 * 128 + dq + 64];
    float4 w3 = wq[c4 * 128 + dq + 96];
    #pragma unroll
    for (int j = 0; j < 8; ++j) {
      float4 v = *(const float4*)&oth_s[(jb + j) * 128 + c4 * 4];
      a0[j] += v.x * w0.x; a0[j] += v.y * w0.y; a0[j] += v.z * w0.z; a0[j] += v.w * w0.w;
      a1[j] += v.x * w1.x; a1[j] += v.y * w1.y; a1[j] += v.z * w1.z; a1[j] += v.w * w1.w;
      a2[j] += v.x * w2.x; a2[j] += v.y * w2.y; a2[j] += v.z * w2.z; a2[j] += v.w * w2.w;
      a3[j] += v.x * w3.x; a3[j] += v.y * w3.y; a3[j] += v.z * w3.z; a3[j] += v.w * w3.w;
    }
  }
  #pragma unroll
  for (int j = 0; j < 8; ++j) {
    float* op = othp + (size_t)b * 8192 + (jb + j) * 128 + dq;
    op[0]  = a0[j];
    op[32] = a1[j];
    op[64] = a2[j];
    op[96] = a3[j];
  }
}

// ---------------- message layer2 + scheduler MLP ----------------
// Round 15: L1 replaced by fused staging tact = relu(othp + sp1). Each thread's
// staging elements all share dm = t&127 -> one scalar spl from sp1_g (global,
// no LDS publication). L2 + scheduler + butterfly byte-identical to round 14.
__global__ __launch_bounds__(256) void k_msg(
    const float* __restrict__ othp, const float* __restrict__ sp1_g,
    const float* __restrict__ spS_g,
    const float* __restrict__ Wm2q, const float* __restrict__ b_m2,
    const float* __restrict__ Ws1q, const float* __restrict__ W_s2,
    const float* __restrict__ b_s2,
    bf16* __restrict__ msg_g, float* __restrict__ S_g, int nblk) {
  const int blk = blockIdx.x;        // local: b_l*64 + i
  const int b = blk >> 6;
  const int t = threadIdx.x;
  __shared__ float tact_s[64 * 128]; // 32KB: relu(othp + sp1)
  __shared__ float msg_s[64 * 128];  // 32KB: msg (written by L2, read by sched)
  const int dq = t & 31;             // dm quad: dm = dq + 32*k, k=0..3
  const int jb = (t >> 5) * 8;       // 8 j-groups of 8
  const int l = t & 63, wv = t >> 6; // scheduler mapping (l = du = lane)

  // fused staging: k = u*256 + t -> dm = k&127 = t&127 (fixed per thread)
  {
    const float spl = sp1_g[(size_t)blk * 128 + (t & 127)];
    const float* op = othp + (size_t)b * 8192;
    for (int k = t; k < 8192; k += 256)
      tact_s[k] = fmaxf(op[k] + spl, 0.f);
  }
  const float* sps = spS_g + (size_t)blk * 192;
  const float spS0 = sps[l], spS1 = sps[64 + l], spS2 = sps[128 + l];
  __syncthreads();
  // ---- message layer 2: reads tact_s, writes msg_s + msg_g (round-14 chains) ----
  {
    float a0[8], a1[8], a2[8], a3[8];
    const float s0 = b_m2[dq], s1 = b_m2[dq + 32], s2 = b_m2[dq + 64], s3 = b_m2[dq + 96];
    #pragma unroll
    for (int j = 0; j < 8; ++j) { a0[j] = s0; a1[j] = s1; a2[j] = s2; a3[j] = s3; }
    const float4* wq = (const float4*)Wm2q;
    for (int c4 = 0; c4 < 32; ++c4) {
      float4 w0 = wq[c4 * 128 + dq];
      float4 w1 = wq[c4 * 128 + dq + 32];
      float4 w2 = wq[c4 * 128 + dq + 64];
      float4 w3 = wq[c4 * 128 + dq + 96];
      #pragma unroll
      for (int j = 0; j < 8; ++j) {
        float4 v = *(const float4*)&tact_s[(jb + j) * 128 + c4 * 4];
        a0[j] += v.x * w0.x; a0[j] += v.y * w0.y; a0[j] += v.z * w0.z; a0[j] += v.w * w0.w;
        a1[j] += v.x * w1.x; a1[j] += v.y * w1.y; a1[j] += v.z * w1.z; a1[j] += v.w * w1.w;
        a2[j] += v.x * w2.x; a2[j] += v.y * w2.y; a2[j] += v.z * w2.z; a2[j] += v.w * w2.w;
        a3[j] += v.x * w3.x; a3[j] += v.y * w3.y; a3[j] += v.z * w3.z; a3[j] += v.w * w3.w;
      }
    }
    #pragma unroll
    for (int j = 0; j < 8; ++j) {
      float m0 = fmaxf(a0[j], 0.f), m1 = fmaxf(a1[j], 0.f);
      float m2 = fmaxf(a2[j], 0.f), m3 = fmaxf(a3[j], 0.f);
      msg_s[(jb + j) * 128 + dq]      = m0;
      msg_s[(jb + j) * 128 + dq + 32] = m1;
      msg_s[(jb + j) * 128 + dq + 64] = m2;
      msg_s[(jb + j) * 128 + dq + 96] = m3;
      bf16* mg = msg_g + ((size_t)blk * 64 + (jb + j)) * 128 + dq;
      mg[0]  = __float2bfloat16(m0);
      mg[32] = __float2bfloat16(m1);
      mg[64] = __float2bfloat16(m2);
      mg[96] = __float2bfloat16(m3);
    }
  }
  __syncthreads();
  // ---- scheduler MLP: ONE c4 pass accumulating all 3 rounds (round-14 form) ----
  float ua0[16], ua1[16], ua2[16];
  #pragma unroll
  for (int j = 0; j < 16; ++j) { ua0[j] = spS0; ua1[j] = spS1; ua2[j] = spS2; }
  {
    const float4* wq0 = (const float4*)(Ws1q);
    const float4* wq1 = (const float4*)(Ws1q + 8192);
    const float4* wq2 = (const float4*)(Ws1q + 16384);
    for (int c4 = 0; c4 < 32; ++c4) {
      float4 w0 = wq0[c4 * 64 + l];
      float4 w1 = wq1[c4 * 64 + l];
      float4 w2 = wq2[c4 * 64 + l];
      #pragma unroll
      for (int j = 0; j < 16; ++j) {
        float4 v = *(const float4*)&msg_s[(wv * 16 + j) * 128 + c4 * 4];
        ua0[j] += v.x * w0.x + v.y * w0.y + v.z * w0.z + v.w * w0.w;
        ua1[j] += v.x * w1.x + v.y * w1.y + v.z * w1.z + v.w * w1.w;
        ua2[j] += v.x * w2.x + v.y * w2.y + v.z * w2.z + v.w * w2.w;
      }
    }
  }
  // butterfly + store per round (identical form to round 14)
  {
    const float w2a = W_s2[0 * 64 + l], w2b = W_s2[1 * 64 + l];
    const float bs2a = b_s2[0], bs2b = b_s2[1];
    for (int j = 0; j < 16; ++j) {
      float u = fmaxf(ua0[j], 0.f);
      float v0 = u * w2a, v1 = u * w2b;
      #pragma unroll
      for (int s = 1; s < 64; s <<= 1) {
        v0 += __shfl_xor(v0, s, 64);
        v1 += __shfl_xor(v1, s, 64);
      }
      if (l == 0) {
        float* sp = S_g + (((size_t)0 * nblk + blk) * 64 + (wv * 16 + j)) * 2;
        sp[0] = v0 + bs2a;
        sp[1] = v1 + bs2b;
      }
    }
  }
  {
    const float w2a = W_s2[2 * 64 + l], w2b = W_s2[3 * 64 + l];
    const float bs2a = b_s2[2], bs2b = b_s2[3];
    for (int j = 0; j < 16; ++j) {
      float u = fmaxf(ua1[j], 0.f);
      float v0 = u * w2a, v1 = u * w2b;
      #pragma unroll
      for (int s = 1; s < 64; s <<= 1) {
        v0 += __shfl_xor(v0, s, 64);
        v1 += __shfl_xor(v1, s, 64);
      }
      if (l == 0) {
        float* sp = S_g + (((size_t)1 * nblk + blk) * 64 + (wv * 16 + j)) * 2;
        sp[0] = v0 + bs2a;
        sp[1] = v1 + bs2b;
      }
    }
  }
  {
    const float w2a = W_s2[4 * 64 + l], w2b = W_s2[5 * 64 + l];
    const float bs2a = b_s2[4], bs2b = b_s2[5];
    for (int j = 0; j < 16; ++j) {
      float u = fmaxf(ua2[j], 0.f);
      float v0 = u * w2a, v1 = u * w2b;
      #pragma unroll
      for (int s = 1; s < 64; s <<= 1) {
        v0 += __shfl_xor(v0, s, 64);
        v1 += __shfl_xor(v1, s, 64);
      }
      if (l == 0) {
        float* sp = S_g + (((size_t)2 * nblk + blk) * 64 + (wv * 16 + j)) * 2;
        sp[0] = v0 + bs2a;
        sp[1] = v1 + bs2b;
      }
    }
  }
}

// ---------------- batched qW = h @ Mh (Mh read once per 64 agents) ----------------
__global__ __launch_bounds__(256) void k_qw(
    const float* __restrict__ h_f32, const float* __restrict__ Mhq,
    float* __restrict__ qW_g, int nblk) {
  const int b = blockIdx.x, r = blockIdx.y, t = threadIdx.x;
  __shared__ float h_s[8192];
  for (int k = t; k < 8192; k += 256) h_s[k] = h_f32[(size_t)b * 8192 + k];
  __syncthreads();
  const int dq = t & 31, ib = (t >> 5) * 8;
  for (int hh = 0; hh < 4; ++hh) {
    float a0[8], a1[8], a2[8], a3[8];
    #pragma unroll
    for (int i = 0; i < 8; ++i) { a0[i] = 0.f; a1[i] = 0.f; a2[i] = 0.f; a3[i] = 0.f; }
    const float4* mq = (const float4*)(Mhq + (size_t)(r * 4 + hh) * 16384);
    for (int c4 = 0; c4 < 32; ++c4) {
      float4 w0 = mq[c4 * 128 + dq];
      float4 w1 = mq[c4 * 128 + dq + 32];
      float4 w2 = mq[c4 * 128 + dq + 64];
      float4 w3 = mq[c4 * 128 + dq + 96];
      #pragma unroll
      for (int i = 0; i < 8; ++i) {
        float4 v = *(const float4*)&h_s[(ib + i) * 128 + c4 * 4];
        a0[i] += v.x * w0.x; a0[i] += v.y * w0.y; a0[i] += v.z * w0.z; a0[i] += v.w * w0.w;
        a1[i] += v.x * w1.x; a1[i] += v.y * w1.y; a1[i] += v.z * w1.z; a1[i] += v.w * w1.w;
        a2[i] += v.x * w2.x; a2[i] += v.y * w2.y; a2[i] += v.z * w2.z; a2[i] += v.w * w2.w;
        a3[i] += v.x * w3.x; a3[i] += v.y * w3.y; a3[i] += v.z * w3.z; a3[i] += v.w * w3.w;
      }
    }
    #pragma unroll
    for (int i = 0; i < 8; ++i) {
      float* qp = qW_g + ((size_t)r * nblk + b * 64 + ib + i) * 512 + hh * 128 + dq;
      qp[0]  = a0[i];
      qp[32] = a1[i];
      qp[64] = a2[i];
      qp[96] = a3[i];
    }
  }
}

// ---------------- adjacency + scores + masked softmax + mw (core) ----------------
__global__ __launch_bounds__(256) void k_attn(
    const bf16* __restrict__ msg_g, const float* __restrict__ S_g,
    const float* __restrict__ gumbel, const float* __restrict__ qW_g,
    float* __restrict__ mw_g, int b0, int nblk) {
  const int blk = blockIdx.x, r = blockIdx.y;
  const int b = blk >> 6, i = blk & 63, t = threadIdx.x;
  __shared__ float msg_s[64][132];
  __shared__ float qW_s[4][132];
  __shared__ float sc_s[320];
  __shared__ float adj_s[64];
  __shared__ float w_s[320];

  {
    const unsigned int* mb = (const unsigned int*)(msg_g + (size_t)blk * 8192);
    for (int k = t; k < 4096; k += 256) {
      unsigned int v = mb[k];
      int j = k >> 6, d2 = (k & 63) * 2;
      msg_s[j][d2]     = __uint_as_float(v << 16);
      msg_s[j][d2 + 1] = __uint_as_float(v & 0xffff0000u);
    }
  }
  for (int o = t; o < 512; o += 256)
    qW_s[o >> 7][o & 127] = qW_g[((size_t)r * nblk + blk) * 512 + o];
  if (t < 64) {
    const int j = t;
    const float* Sij = S_g + (((size_t)r * nblk + blk) * 64 + j) * 2;
    const float* Sji = S_g + (((size_t)r * nblk + b * 64 + j) * 64 + i) * 2;
    const float* g = gumbel + ((((size_t)r * 64 + (b0 + b)) * 64 + i) * 64 + j) * 2;
    float y0 = 0.5f * Sij[0] + 0.5f * Sji[0] + g[0];
    float y1 = 0.5f * Sij[1] + 0.5f * Sji[1] + g[1];
    adj_s[j] = (y1 > y0) ? 1.f : 0.f;
  }
  __syncthreads();
  // scores[j][hh]
  {
    const int j = t >> 2, hh = t & 3;
    float a = 0.f;
    #pragma unroll
    for (int d4 = 0; d4 < 32; ++d4) {
      float4 mv = *(const float4*)&msg_s[j][d4 * 4];
      float4 qv = *(const float4*)&qW_s[hh][d4 * 4];
      a += mv.x * qv.x + mv.y * qv.y + mv.z * qv.z + mv.w * qv.w;
    }
    sc_s[j * 5 + hh] = a * 0.17677669529663687f;  // 1/sqrt(32)
  }
  __syncthreads();
  // masked softmax per head (one wave per head)
  {
    const int hh = t >> 6, jj = t & 63;
    float v = sc_s[jj * 5 + hh];
    float mx = v;
    #pragma unroll
    for (int s = 32; s > 0; s >>= 1) mx = fmaxf(mx, __shfl_xor(mx, s, 64));
    float e = expf(v - mx);
    float ad = adj_s[jj];
    float E = e, Em = ad * e;
    #pragma unroll
    for (int s = 32; s > 0; s >>= 1) {
      E += __shfl_xor(E, s, 64);
      Em += __shfl_xor(Em, s, 64);
    }
    w_s[jj * 5 + hh] = ad * e / (Em + 1e-10f * E);
  }
  __syncthreads();
  // mw[hh][d] = sum_j w[j,hh] * msg[j,d]  -> mw_g
  {
    const int hh0 = t >> 7, d = t & 127;
    float a0 = 0.f, a1 = 0.f;
    for (int j = 0; j < 64; ++j) {
      float m = msg_s[j][d];
      a0 += w_s[j * 5 + hh0] * m;
      a1 += w_s[j * 5 + hh0 + 2] * m;
    }
    float* mp = mw_g + ((size_t)r * nblk + blk) * 512;
    mp[hh0 * 128 + d] = a0;
    mp[(hh0 + 2) * 128 + d] = a1;
  }
}

// ---------------- batched att = elu(mw @ P) (P read once per 64 agents) ----------------
__global__ __launch_bounds__(256) void k_pv(
    const float* __restrict__ mw_g, const float* __restrict__ Pq,
    float* __restrict__ att_r, int nblk) {
  const int b = blockIdx.x, r = blockIdx.y, t = threadIdx.x;
  const int dq = t & 31, ib = (t >> 5) * 8;
  float a0[8], a1[8], a2[8], a3[8];
  #pragma unroll
  for (int i = 0; i < 8; ++i) { a0[i] = 0.f; a1[i] = 0.f; a2[i] = 0.f; a3[i] = 0.f; }
  const float4* pq = (const float4*)(Pq + (size_t)r * 65536);
  const float* mwb = mw_g + ((size_t)r * nblk + b * 64) * 512;
  for (int c4 = 0; c4 < 128; ++c4) {
    float4 w0 = pq[c4 * 128 + dq];
    float4 w1 = pq[c4 * 128 + dq + 32];
    float4 w2 = pq[c4 * 128 + dq + 64];
    float4 w3 = pq[c4 * 128 + dq + 96];
    #pragma unroll
    for (int i = 0; i < 8; ++i) {
      float4 v = *(const float4*)&mwb[(size_t)(ib + i) * 512 + c4 * 4];
      a0[i] += v.x * w0.x; a0[i] += v.y * w0.y; a0[i] += v.z * w0.z; a0[i] += v.w * w0.w;
      a1[i] += v.x * w1.x; a1[i] += v.y * w1.y; a1[i] += v.z * w1.z; a1[i] += v.w * w1.w;
      a2[i] += v.x * w2.x; a2[i] += v.y * w2.y; a2[i] += v.z * w2.z; a2[i] += v.w * w2.w;
      a3[i] += v.x * w3.x; a3[i] += v.y * w3.y; a3[i] += v.z * w3.z; a3[i] += v.w * w3.w;
    }
  }
  #pragma unroll
  for (int i = 0; i < 8; ++i) {
    float* ap = att_r + ((size_t)r * nblk + b * 64 + ib + i) * 128 + dq;
    ap[0]  = (a0[i] > 0.f) ? a0[i] : expm1f(a0[i]);
    ap[32] = (a1[i] > 0.f) ? a1[i] : expm1f(a1[i]);
    ap[64] = (a2[i] > 0.f) ? a2[i] : expm1f(a2[i]);
    ap[96] = (a3[i] > 0.f) ? a3[i] : expm1f(a3[i]);
  }
}

// ---------------- mean over rounds + output head ----------------
__global__ __launch_bounds__(128) void k_head(
    const float* __restrict__ h_f32, const float* __restrict__ att_r,
    const float* __restrict__ Wq1T, const float* __restrict__ b_q1,
    const float* __restrict__ Wq2T, const float* __restrict__ b_q2,
    float* __restrict__ out_q, int b0, int nblk) {
  const int blk = blockIdx.x, t = threadIdx.x;
  __shared__ float hi[128], agg[128], u[128];
  hi[t] = h_f32[(size_t)blk * 128 + t];
  agg[t] = (att_r[(size_t)blk * 128 + t] +
            att_r[((size_t)nblk + blk) * 128 + t] +
            att_r[((size_t)2 * nblk + blk) * 128 + t]) * (1.f / 3.f);
  __syncthreads();
  float a = b_q1[t];
  #pragma unroll 4
  for (int c = 0; c < 128; ++c) a += hi[c] * Wq1T[c * 128 + t];
  #pragma unroll 4
  for (int c = 0; c < 128; ++c) a += agg[c] * Wq1T[(128 + c) * 128 + t];
  u[t] = fmaxf(a, 0.f);
  __syncthreads();
  if (t < 20) {
    float a2 = b_q2[t];
    #pragma unroll 4
    for (int c = 0; c < 128; ++c) a2 += u[c] * Wq2T[c * 20 + t];
    out_q[((size_t)b0 * 64 + blk) * 20 + t] = a2;
  }
}

extern "C" void kernel_launch(void* const* d_in, const int* in_sizes, int n_in,
                              void* d_out, int out_size, void* d_ws, size_t ws_size,
                              hipStream_t stream) {
  (void)in_sizes; (void)n_in; (void)out_size;
  const float* obs    = (const float*)d_in[0];
  const float* hidden = (const float*)d_in[1];
  const float* gumb   = (const float*)d_in[2];
  const float* W_enc  = (const float*)d_in[3];
  const float* b_enc  = (const float*)d_in[4];
  const float* W_ih   = (const float*)d_in[5];
  const float* W_hh   = (const float*)d_in[6];
  const float* b_ih   = (const float*)d_in[7];
  const float* b_hh   = (const float*)d_in[8];
  const float* W_oth  = (const float*)d_in[9];
  const float* b_oth  = (const float*)d_in[10];
  const float* W_m1   = (const float*)d_in[11];
  const float* b_m1   = (const float*)d_in[12];
  const float* W_m2   = (const float*)d_in[13];
  const float* b_m2   = (const float*)d_in[14];
  const float* W_s1   = (const float*)d_in[15];
  const float* b_s1   = (const float*)d_in[16];
  const float* W_s2   = (const float*)d_in[17];
  const float* b_s2   = (const float*)d_in[18];
  const float* Wq     = (const float*)d_in[19];
  const float* Wk     = (const float*)d_in[20];
  const float* Wv     = (const float*)d_in[21];
  const float* Wo     = (const float*)d_in[22];
  const float* W_q1   = (const float*)d_in[23];
  const float* b_q1   = (const float*)d_in[24];
  const float* W_q2   = (const float*)d_in[25];
  const float* b_q2   = (const float*)d_in[26];

  float* ws    = (float*)d_ws;
  float* Wm1q  = ws + WM1_OFF;
  float* Wm2q  = ws + WM2_OFF;
  float* Ws1q  = ws + WS1_OFF;
  float* Wm1sT = ws + WM1ST_OFF;
  float* Ws1sT = ws + WS1ST_OFF;
  float* WencT = ws + WENCT_OFF;
  float* WihT  = ws + WIHT_OFF;
  float* WhhT  = ws + WHHT_OFF;
  float* WothT = ws + WOTHT_OFF;
  float* Wq1T  = ws + WQ1T_OFF;
  float* Wq2T  = ws + WQ2T_OFF;
  float* Mhq   = ws + MH_OFF;
  float* Pq    = ws + P_OFF;

  float* out_q = (float*)d_out;  // f32 output: qout then h
  float* out_h = out_q + BZc * NAc * NACTc;

  // per-b chunk bytes: h 32K + oth 32K + othp 32K + sp1 32K + spS 48K + S 96K
  //                    + att 96K + qW 384K + mw 384K + msg(bf16) 1M = 2211840
  int BC = 64;
  while (BC > 1) {
    size_t need = 4ull * CHUNK_BASE + (size_t)BC * 2211840ull;
    if (need <= ws_size) break;
    BC >>= 1;
  }
  const int nblk = BC * 64;
  float* h_f32   = ws + CHUNK_BASE;
  float* oth_f32 = h_f32 + (size_t)BC * 8192;
  float* othp    = oth_f32 + (size_t)BC * 8192;
  float* sp1_g   = othp + (size_t)BC * 8192;
  float* spS_g   = sp1_g + (size_t)BC * 8192;
  float* S_g     = spS_g + (size_t)BC * 12288;
  float* att_rb  = S_g + (size_t)BC * 24576;
  float* qW_g    = att_rb + (size_t)BC * 24576;
  float* mw_g    = qW_g + (size_t)BC * 98304;
  bf16*  msg_g   = (bf16*)(mw_g + (size_t)BC * 98304);

  kW<<<dim3(1018), dim3(256), 0, stream>>>(W_m1, W_m2, W_s1, W_enc, W_ih, W_hh,
                                           W_oth, W_q1, W_q2, ws);
  kMP<<<dim3(24), dim3(256), 0, stream>>>(Wq, Wk, Wv, Wo, Mhq, Pq);
  for (int b0 = 0; b0 < BZc; b0 += BC) {
    k_enc<<<dim3(nblk), dim3(128), 0, stream>>>(obs, hidden, WencT, b_enc, WihT, WhhT,
                                                b_ih, b_hh, WothT, b_oth,
                                                h_f32, oth_f32, out_h, b0);
    k_sp<<<dim3(nblk), dim3(320), 0, stream>>>(h_f32, Wm1sT, b_m1, Ws1sT, b_s1,
                                               sp1_g, spS_g);
    k_othp<<<dim3(BC), dim3(256), 0, stream>>>(oth_f32, Wm1q, othp);
    k_msg<<<dim3(nblk), dim3(256), 0, stream>>>(othp, sp1_g, spS_g,
                                                Wm2q, b_m2, Ws1q,
                                                W_s2, b_s2, msg_g, S_g, nblk);
    k_qw<<<dim3(BC, 3), dim3(256), 0, stream>>>(h_f32, Mhq, qW_g, nblk);
    k_attn<<<dim3(nblk, 3), dim3(256), 0, stream>>>(msg_g, S_g, gumb, qW_g,
                                                    mw_g, b0, nblk);
    k_pv<<<dim3(BC, 3), dim3(256), 0, stream>>>(mw_g, Pq, att_rb, nblk);
    k_head<<<dim3(nblk), dim3(128), 0, stream>>>(h_f32, att_rb, Wq1T, b_q1,
                                                 Wq2T, b_q2, out_q, b0, nblk);
  }
}

// Round 16
// 781.085 us; speedup vs baseline: 15.4375x; 1.0242x over previous
//
#include <hip/hip_runtime.h>
#include <hip/hip_bf16.h>

typedef __hip_bfloat16 bf16;

#define BZc 64
#define NAc 64
#define Dc 128
#define Rc 3
#define Hc 4
#define INc 96
#define NACTc 20

// fixed workspace layout (float element offsets)
#define WM1_OFF    0        // 16384 : W_m1 others-half, float4-permuted by dm
#define WM2_OFF    16384    // 16384 : W_m2 float4-permuted
#define WS1_OFF    32768    // 24576 : W_s1 msg-half, float4-permuted by du
#define WM1ST_OFF  57344    // 16384 : W_m1 self-half, transposed [c][dm]
#define WS1ST_OFF  73728    // 24576 : W_s1 self-half, transposed [r][c][du]
#define WENCT_OFF  98304    // 12288 : W_enc^T [c][128]
#define WIHT_OFF   110592   // 49152 : W_ih^T  [c][384]
#define WHHT_OFF   159744   // 49152 : W_hh^T  [c][384]
#define WOTHT_OFF  208896   // 16384 : W_oth^T [c][128]
#define WQ1T_OFF   225280   // 32768 : W_q1^T  [c][128]
#define WQ2T_OFF   258048   // 2560  : W_q2^T  [c][20]
#define MH_OFF     260608   // 196608: Mhq[r][hh] float4-permuted (Wq_h^T Wk_h)
#define P_OFF      457216   // 196608: Pq[r] float4-permuted (k=hh*128+d major)
#define CHUNK_BASE 655360   // floats; per-chunk region starts here

// ---------------- weight permute / transpose kernel ----------------
__global__ void kW(const float* __restrict__ W_m1, const float* __restrict__ W_m2,
                   const float* __restrict__ W_s1, const float* __restrict__ W_enc,
                   const float* __restrict__ W_ih, const float* __restrict__ W_hh,
                   const float* __restrict__ W_oth, const float* __restrict__ W_q1,
                   const float* __restrict__ W_q2, float* __restrict__ ws) {
  int idx = blockIdx.x * blockDim.x + threadIdx.x;
  if (idx < 16384) {
    int dm = idx & 127, c = idx >> 7;
    ws[WM1_OFF + ((c >> 2) * 128 + dm) * 4 + (c & 3)] = W_m1[dm * 256 + c];
  } else if (idx < 32768) {
    int k = idx - 16384;
    int dm = k & 127, c = k >> 7;
    ws[WM2_OFF + ((c >> 2) * 128 + dm) * 4 + (c & 3)] = W_m2[dm * 128 + c];
  } else if (idx < 57344) {
    int k = idx - 32768;
    int r = k >> 13, rem = k & 8191;
    int du = rem & 63, c = rem >> 6;
    ws[WS1_OFF + r * 8192 + ((c >> 2) * 64 + du) * 4 + (c & 3)] =
        W_s1[(r * 64 + du) * 256 + 128 + c];
  } else if (idx < 73728) {
    int k = idx - 57344;
    int dm = k & 127, c = k >> 7;
    ws[WM1ST_OFF + c * 128 + dm] = W_m1[dm * 256 + 128 + c];
  } else if (idx < 98304) {
    int k = idx - 73728;
    int r = k >> 13, rem = k & 8191;
    int du = rem & 63, c = rem >> 6;
    ws[WS1ST_OFF + r * 8192 + c * 64 + du] = W_s1[(r * 64 + du) * 256 + c];
  } else if (idx < 110592) {
    int k = idx - 98304;              // W_encT [96][128]
    int o = k & 127, c = k >> 7;
    ws[WENCT_OFF + c * 128 + o] = W_enc[o * 96 + c];
  } else if (idx < 159744) {
    int k = idx - 110592;             // W_ihT [128][384]
    int o = k % 384, c = k / 384;
    ws[WIHT_OFF + c * 384 + o] = W_ih[o * 128 + c];
  } else if (idx < 208896) {
    int k = idx - 159744;             // W_hhT [128][384]
    int o = k % 384, c = k / 384;
    ws[WHHT_OFF + c * 384 + o] = W_hh[o * 128 + c];
  } else if (idx < 225280) {
    int k = idx - 208896;             // W_othT [128][128]
    int o = k & 127, c = k >> 7;
    ws[WOTHT_OFF + c * 128 + o] = W_oth[o * 128 + c];
  } else if (idx < 258048) {
    int k = idx - 225280;             // W_q1T [256][128]
    int o = k & 127, c = k >> 7;
    ws[WQ1T_OFF + c * 128 + o] = W_q1[o * 256 + c];
  } else if (idx < 260608) {
    int k = idx - 258048;             // W_q2T [128][20]
    int o = k % 20, c = k / 20;
    ws[WQ2T_OFF + c * 20 + o] = W_q2[o * 128 + c];
  }
}

// ---------------- per-head projection folds, stored float4-permuted ----------------
__global__ __launch_bounds__(256) void kMP(
    const float* __restrict__ Wq, const float* __restrict__ Wk,
    const float* __restrict__ Wv, const float* __restrict__ Wo,
    float* __restrict__ Mhq, float* __restrict__ Pq) {
  const int bid = blockIdx.x;  // 24 = r*8 + hh*2 + which
  const int which = bid & 1, hh = (bid >> 1) & 3, r = bid >> 3;
  const int t = threadIdx.x;
  __shared__ float A[4096];
  __shared__ float B[4224];
  if (which == 0) {
    for (int k = t; k < 4096; k += 256) {
      int e = k >> 7, c = k & 127;
      A[k] = Wq[(r * 128 + hh * 32 + e) * 128 + c];
      B[k] = Wk[(r * 128 + hh * 32 + e) * 128 + c];
    }
    __syncthreads();
    for (int k = 0; k < 64; ++k) {
      int o = k * 256 + t, c = o >> 7, d = o & 127;
      float a = 0.f;
      #pragma unroll 8
      for (int e = 0; e < 32; ++e) a += A[e * 128 + c] * B[e * 128 + d];
      Mhq[(size_t)(r * 4 + hh) * 16384 + ((c >> 2) * 128 + d) * 4 + (c & 3)] = a;
    }
  } else {
    for (int k = t; k < 4096; k += 256) A[k] = Wv[(r * 128 + hh * 32 + (k >> 7)) * 128 + (k & 127)];
    for (int k = t; k < 4096; k += 256) {
      int dp = k >> 5, e = k & 31;
      B[dp * 33 + e] = Wo[(r * 128 + dp) * 128 + hh * 32 + e];
    }
    __syncthreads();
    for (int k = 0; k < 64; ++k) {
      int o = k * 256 + t, d = o >> 7, dp = o & 127;
      float a = 0.f;
      #pragma unroll 8
      for (int e = 0; e < 32; ++e) a += A[e * 128 + d] * B[dp * 33 + e];
      int kk = hh * 128 + d;
      Pq[(size_t)r * 65536 + ((kk >> 2) * 128 + dp) * 4 + (kk & 3)] = a;
    }
  }
}

// ---------------- encoder + GRU + others ----------------
__global__ __launch_bounds__(128) void k_enc(
    const float* __restrict__ obs, const float* __restrict__ hidden,
    const float* __restrict__ WencT, const float* __restrict__ b_enc,
    const float* __restrict__ WihT, const float* __restrict__ WhhT,
    const float* __restrict__ b_ih, const float* __restrict__ b_hh,
    const float* __restrict__ WothT, const float* __restrict__ b_oth,
    float* __restrict__ h_f32, float* __restrict__ oth_f32,
    float* __restrict__ out_h, int b0) {
  const int row_l = blockIdx.x, t = threadIdx.x;
  const int row_g = b0 * 64 + row_l;
  __shared__ float obs_s[96], hid_s[128], x_s[128], h_s[128];
  if (t < 96) obs_s[t] = obs[row_g * 96 + t];
  hid_s[t] = hidden[row_g * 128 + t];
  __syncthreads();
  float x = b_enc[t];
  #pragma unroll 8
  for (int c = 0; c < 96; ++c) x += obs_s[c] * WencT[c * 128 + t];
  x_s[t] = x;
  __syncthreads();
  float gxr = b_ih[t], gxz = b_ih[t + 128], gxn = b_ih[t + 256];
  float ghr = b_hh[t], ghz = b_hh[t + 128], ghn = b_hh[t + 256];
  #pragma unroll 4
  for (int c = 0; c < 128; ++c) {
    float xv = x_s[c], hv = hid_s[c];
    const float* wi = WihT + c * 384 + t;
    const float* wh = WhhT + c * 384 + t;
    gxr += xv * wi[0]; gxz += xv * wi[128]; gxn += xv * wi[256];
    ghr += hv * wh[0]; ghz += hv * wh[128]; ghn += hv * wh[256];
  }
  float rg = 1.f / (1.f + expf(-(gxr + ghr)));
  float zg = 1.f / (1.f + expf(-(gxz + ghz)));
  float ng = tanhf(gxn + rg * ghn);
  float hv = (1.f - zg) * ng + zg * hid_s[t];
  h_s[t] = hv;
  h_f32[row_l * 128 + t] = hv;
  out_h[(size_t)row_g * 128 + t] = hv;
  __syncthreads();
  float o = b_oth[t];
  #pragma unroll 4
  for (int c = 0; c < 128; ++c) o += h_s[c] * WothT[c * 128 + t];
  oth_f32[row_l * 128 + t] = o;
}

// ---------------- self-half partial sums, hoisted (bit-exact chains) ----------------
__global__ __launch_bounds__(320) void k_sp(
    const float* __restrict__ h_f32, const float* __restrict__ Wm1sT,
    const float* __restrict__ b_m1, const float* __restrict__ Ws1sT,
    const float* __restrict__ b_s1,
    float* __restrict__ sp1_g, float* __restrict__ spS_g) {
  const int blk = blockIdx.x, t = threadIdx.x;
  __shared__ float h_s[128];
  if (t < 128) h_s[t] = h_f32[(size_t)blk * 128 + t];
  __syncthreads();
  if (t < 128) {
    float a = b_m1[t];
    #pragma unroll 4
    for (int c = 0; c < 128; ++c) a += h_s[c] * Wm1sT[c * 128 + t];
    sp1_g[(size_t)blk * 128 + t] = a;
  } else {
    const int r = (t - 128) >> 6, du = (t - 128) & 63;
    float a = b_s1[r * 64 + du];
    #pragma unroll 4
    for (int c = 0; c < 128; ++c) a += h_s[c] * Ws1sT[r * 8192 + c * 64 + du];
    spS_g[(size_t)blk * 192 + r * 64 + du] = a;
  }
}

// ---------------- i-invariant hoist: othp[b][j][dm] = others[b][j] @ W1_others^T ----
__global__ __launch_bounds__(256) void k_othp(
    const float* __restrict__ oth_f32, const float* __restrict__ Wm1q,
    float* __restrict__ othp) {
  const int b = blockIdx.x, t = threadIdx.x;
  const int dq = t & 31, jb = (t >> 5) * 8;
  __shared__ float oth_s[8192];
  for (int k = t; k < 8192; k += 256) oth_s[k] = oth_f32[(size_t)b * 8192 + k];
  __syncthreads();
  float a0[8], a1[8], a2[8], a3[8];
  #pragma unroll
  for (int j = 0; j < 8; ++j) { a0[j] = 0.f; a1[j] = 0.f; a2[j] = 0.f; a3[j] = 0.f; }
  const float4* wq = (const float4*)Wm1q;
  for (int c4 = 0; c4 < 32; ++c4) {
    float4 w0 = wq[c4 * 128 + dq];
    float4 w1 = wq[c4 * 128 + dq + 32];
    float4 w2 = wq[c4 * 128 + dq + 64];
    float4 w3 = wq[c4 * 128 + dq + 96];
    #pragma unroll
    for (int j = 0; j < 8; ++j) {
      float4 v = *(const float4*)&oth_s[(jb + j) * 128 + c4 * 4];
      a0[j] += v.x * w0.x; a0[j] += v.y * w0.y; a0[j] += v.z * w0.z; a0[j] += v.w * w0.w;
      a1[j] += v.x * w1.x; a1[j] += v.y * w1.y; a1[j] += v.z * w1.z; a1[j] += v.w * w1.w;
      a2[j] += v.x * w2.x; a2[j] += v.y * w2.y; a2[j] += v.z * w2.z; a2[j] += v.w * w2.w;
      a3[j] += v.x * w3.x; a3[j] += v.y * w3.y; a3[j] += v.z * w3.z; a3[j] += v.w * w3.w;
    }
  }
  #pragma unroll
  for (int j = 0; j < 8; ++j) {
    float* op = othp + (size_t)b * 8192 + (jb + j) * 128 + dq;
    op[0]  = a0[j];
    op[32] = a1[j];
    op[64] = a2[j];
    op[96] = a3[j];
  }
}

// ---------------- message layer2 + scheduler MLP ----------------
// Round 16: single 32KB LDS buffer (tact overwritten in place by msg).
// Safety: L2's msg[j] depends only on tact[j]; each wave accumulates over ALL
// c4 before any lane stores (wave-lockstep, stores after read loop in program
// order), and waves own disjoint row ranges. Arithmetic byte-identical to r15.
__global__ __launch_bounds__(256) void k_msg(
    const float* __restrict__ othp, const float* __restrict__ sp1_g,
    const float* __restrict__ spS_g,
    const float* __restrict__ Wm2q, const float* __restrict__ b_m2,
    const float* __restrict__ Ws1q, const float* __restrict__ W_s2,
    const float* __restrict__ b_s2,
    bf16* __restrict__ msg_g, float* __restrict__ S_g, int nblk) {
  const int blk = blockIdx.x;        // local: b_l*64 + i
  const int b = blk >> 6;
  const int t = threadIdx.x;
  __shared__ float buf_s[64 * 128];  // 32KB: tact, overwritten in place by msg
  const int dq = t & 31;             // dm quad: dm = dq + 32*k, k=0..3
  const int jb = (t >> 5) * 8;       // 8 j-groups of 8
  const int l = t & 63, wv = t >> 6; // scheduler mapping (l = du = lane)

  // fused staging: k = u*256 + t -> dm = k&127 = t&127 (fixed per thread)
  {
    const float spl = sp1_g[(size_t)blk * 128 + (t & 127)];
    const float* op = othp + (size_t)b * 8192;
    for (int k = t; k < 8192; k += 256)
      buf_s[k] = fmaxf(op[k] + spl, 0.f);
  }
  const float* sps = spS_g + (size_t)blk * 192;
  const float spS0 = sps[l], spS1 = sps[64 + l], spS2 = sps[128 + l];
  __syncthreads();
  // ---- message layer 2: reads buf_s (tact), overwrites with msg ----
  {
    float a0[8], a1[8], a2[8], a3[8];
    const float s0 = b_m2[dq], s1 = b_m2[dq + 32], s2 = b_m2[dq + 64], s3 = b_m2[dq + 96];
    #pragma unroll
    for (int j = 0; j < 8; ++j) { a0[j] = s0; a1[j] = s1; a2[j] = s2; a3[j] = s3; }
    const float4* wq = (const float4*)Wm2q;
    for (int c4 = 0; c4 < 32; ++c4) {
      float4 w0 = wq[c4 * 128 + dq];
      float4 w1 = wq[c4 * 128 + dq + 32];
      float4 w2 = wq[c4 * 128 + dq + 64];
      float4 w3 = wq[c4 * 128 + dq + 96];
      #pragma unroll
      for (int j = 0; j < 8; ++j) {
        float4 v = *(const float4*)&buf_s[(jb + j) * 128 + c4 * 4];
        a0[j] += v.x * w0.x; a0[j] += v.y * w0.y; a0[j] += v.z * w0.z; a0[j] += v.w * w0.w;
        a1[j] += v.x * w1.x; a1[j] += v.y * w1.y; a1[j] += v.z * w1.z; a1[j] += v.w * w1.w;
        a2[j] += v.x * w2.x; a2[j] += v.y * w2.y; a2[j] += v.z * w2.z; a2[j] += v.w * w2.w;
        a3[j] += v.x * w3.x; a3[j] += v.y * w3.y; a3[j] += v.z * w3.z; a3[j] += v.w * w3.w;
      }
    }
    #pragma unroll
    for (int j = 0; j < 8; ++j) {
      float m0 = fmaxf(a0[j], 0.f), m1 = fmaxf(a1[j], 0.f);
      float m2 = fmaxf(a2[j], 0.f), m3 = fmaxf(a3[j], 0.f);
      buf_s[(jb + j) * 128 + dq]      = m0;
      buf_s[(jb + j) * 128 + dq + 32] = m1;
      buf_s[(jb + j) * 128 + dq + 64] = m2;
      buf_s[(jb + j) * 128 + dq + 96] = m3;
      bf16* mg = msg_g + ((size_t)blk * 64 + (jb + j)) * 128 + dq;
      mg[0]  = __float2bfloat16(m0);
      mg[32] = __float2bfloat16(m1);
      mg[64] = __float2bfloat16(m2);
      mg[96] = __float2bfloat16(m3);
    }
  }
  __syncthreads();
  // ---- scheduler MLP: ONE c4 pass accumulating all 3 rounds ----
  float ua0[16], ua1[16], ua2[16];
  #pragma unroll
  for (int j = 0; j < 16; ++j) { ua0[j] = spS0; ua1[j] = spS1; ua2[j] = spS2; }
  {
    const float4* wq0 = (const float4*)(Ws1q);
    const float4* wq1 = (const float4*)(Ws1q + 8192);
    const float4* wq2 = (const float4*)(Ws1q + 16384);
    for (int c4 = 0; c4 < 32; ++c4) {
      float4 w0 = wq0[c4 * 64 + l];
      float4 w1 = wq1[c4 * 64 + l];
      float4 w2 = wq2[c4 * 64 + l];
      #pragma unroll
      for (int j = 0; j < 16; ++j) {
        float4 v = *(const float4*)&buf_s[(wv * 16 + j) * 128 + c4 * 4];
        ua0[j] += v.x * w0.x + v.y * w0.y + v.z * w0.z + v.w * w0.w;
        ua1[j] += v.x * w1.x + v.y * w1.y + v.z * w1.z + v.w * w1.w;
        ua2[j] += v.x * w2.x + v.y * w2.y + v.z * w2.z + v.w * w2.w;
      }
    }
  }
  // butterfly + store per round (identical form to round 15)
  {
    const float w2a = W_s2[0 * 64 + l], w2b = W_s2[1 * 64 + l];
    const float bs2a = b_s2[0], bs2b = b_s2[1];
    for (int j = 0; j < 16; ++j) {
      float u = fmaxf(ua0[j], 0.f);
      float v0 = u * w2a, v1 = u * w2b;
      #pragma unroll
      for (int s = 1; s < 64; s <<= 1) {
        v0 += __shfl_xor(v0, s, 64);
        v1 += __shfl_xor(v1, s, 64);
      }
      if (l == 0) {
        float* sp = S_g + (((size_t)0 * nblk + blk) * 64 + (wv * 16 + j)) * 2;
        sp[0] = v0 + bs2a;
        sp[1] = v1 + bs2b;
      }
    }
  }
  {
    const float w2a = W_s2[2 * 64 + l], w2b = W_s2[3 * 64 + l];
    const float bs2a = b_s2[2], bs2b = b_s2[3];
    for (int j = 0; j < 16; ++j) {
      float u = fmaxf(ua1[j], 0.f);
      float v0 = u * w2a, v1 = u * w2b;
      #pragma unroll
      for (int s = 1; s < 64; s <<= 1) {
        v0 += __shfl_xor(v0, s, 64);
        v1 += __shfl_xor(v1, s, 64);
      }
      if (l == 0) {
        float* sp = S_g + (((size_t)1 * nblk + blk) * 64 + (wv * 16 + j)) * 2;
        sp[0] = v0 + bs2a;
        sp[1] = v1 + bs2b;
      }
    }
  }
  {
    const float w2a = W_s2[4 * 64 + l], w2b = W_s2[5 * 64 + l];
    const float bs2a = b_s2[4], bs2b = b_s2[5];
    for (int j = 0; j < 16; ++j) {
      float u = fmaxf(ua2[j], 0.f);
      float v0 = u * w2a, v1 = u * w2b;
      #pragma unroll
      for (int s = 1; s < 64; s <<= 1) {
        v0 += __shfl_xor(v0, s, 64);
        v1 += __shfl_xor(v1, s, 64);
      }
      if (l == 0) {
        float* sp = S_g + (((size_t)2 * nblk + blk) * 64 + (wv * 16 + j)) * 2;
        sp[0] = v0 + bs2a;
        sp[1] = v1 + bs2b;
      }
    }
  }
}

// ---------------- batched qW = h @ Mh (Mh read once per 64 agents) ----------------
__global__ __launch_bounds__(256) void k_qw(
    const float* __restrict__ h_f32, const float* __restrict__ Mhq,
    float* __restrict__ qW_g, int nblk) {
  const int b = blockIdx.x, r = blockIdx.y, t = threadIdx.x;
  __shared__ float h_s[8192];
  for (int k = t; k < 8192; k += 256) h_s[k] = h_f32[(size_t)b * 8192 + k];
  __syncthreads();
  const int dq = t & 31, ib = (t >> 5) * 8;
  for (int hh = 0; hh < 4; ++hh) {
    float a0[8], a1[8], a2[8], a3[8];
    #pragma unroll
    for (int i = 0; i < 8; ++i) { a0[i] = 0.f; a1[i] = 0.f; a2[i] = 0.f; a3[i] = 0.f; }
    const float4* mq = (const float4*)(Mhq + (size_t)(r * 4 + hh) * 16384);
    for (int c4 = 0; c4 < 32; ++c4) {
      float4 w0 = mq[c4 * 128 + dq];
      float4 w1 = mq[c4 * 128 + dq + 32];
      float4 w2 = mq[c4 * 128 + dq + 64];
      float4 w3 = mq[c4 * 128 + dq + 96];
      #pragma unroll
      for (int i = 0; i < 8; ++i) {
        float4 v = *(const float4*)&h_s[(ib + i) * 128 + c4 * 4];
        a0[i] += v.x * w0.x; a0[i] += v.y * w0.y; a0[i] += v.z * w0.z; a0[i] += v.w * w0.w;
        a1[i] += v.x * w1.x; a1[i] += v.y * w1.y; a1[i] += v.z * w1.z; a1[i] += v.w * w1.w;
        a2[i] += v.x * w2.x; a2[i] += v.y * w2.y; a2[i] += v.z * w2.z; a2[i] += v.w * w2.w;
        a3[i] += v.x * w3.x; a3[i] += v.y * w3.y; a3[i] += v.z * w3.z; a3[i] += v.w * w3.w;
      }
    }
    #pragma unroll
    for (int i = 0; i < 8; ++i) {
      float* qp = qW_g + ((size_t)r * nblk + b * 64 + ib + i) * 512 + hh * 128 + dq;
      qp[0]  = a0[i];
      qp[32] = a1[i];
      qp[64] = a2[i];
      qp[96] = a3[i];
    }
  }
}

// ---------------- adjacency + scores + masked softmax + mw (core) ----------------
__global__ __launch_bounds__(256) void k_attn(
    const bf16* __restrict__ msg_g, const float* __restrict__ S_g,
    const float* __restrict__ gumbel, const float* __restrict__ qW_g,
    float* __restrict__ mw_g, int b0, int nblk) {
  const int blk = blockIdx.x, r = blockIdx.y;
  const int b = blk >> 6, i = blk & 63, t = threadIdx.x;
  __shared__ float msg_s[64][132];
  __shared__ float qW_s[4][132];
  __shared__ float sc_s[320];
  __shared__ float adj_s[64];
  __shared__ float w_s[320];

  {
    const unsigned int* mb = (const unsigned int*)(msg_g + (size_t)blk * 8192);
    for (int k = t; k < 4096; k += 256) {
      unsigned int v = mb[k];
      int j = k >> 6, d2 = (k & 63) * 2;
      msg_s[j][d2]     = __uint_as_float(v << 16);
      msg_s[j][d2 + 1] = __uint_as_float(v & 0xffff0000u);
    }
  }
  for (int o = t; o < 512; o += 256)
    qW_s[o >> 7][o & 127] = qW_g[((size_t)r * nblk + blk) * 512 + o];
  if (t < 64) {
    const int j = t;
    const float* Sij = S_g + (((size_t)r * nblk + blk) * 64 + j) * 2;
    const float* Sji = S_g + (((size_t)r * nblk + b * 64 + j) * 64 + i) * 2;
    const float* g = gumbel + ((((size_t)r * 64 + (b0 + b)) * 64 + i) * 64 + j) * 2;
    float y0 = 0.5f * Sij[0] + 0.5f * Sji[0] + g[0];
    float y1 = 0.5f * Sij[1] + 0.5f * Sji[1] + g[1];
    adj_s[j] = (y1 > y0) ? 1.f : 0.f;
  }
  __syncthreads();
  // scores[j][hh]
  {
    const int j = t >> 2, hh = t & 3;
    float a = 0.f;
    #pragma unroll
    for (int d4 = 0; d4 < 32; ++d4) {
      float4 mv = *(const float4*)&msg_s[j][d4 * 4];
      float4 qv = *(const float4*)&qW_s[hh][d4 * 4];
      a += mv.x * qv.x + mv.y * qv.y + mv.z * qv.z + mv.w * qv.w;
    }
    sc_s[j * 5 + hh] = a * 0.17677669529663687f;  // 1/sqrt(32)
  }
  __syncthreads();
  // masked softmax per head (one wave per head)
  {
    const int hh = t >> 6, jj = t & 63;
    float v = sc_s[jj * 5 + hh];
    float mx = v;
    #pragma unroll
    for (int s = 32; s > 0; s >>= 1) mx = fmaxf(mx, __shfl_xor(mx, s, 64));
    float e = expf(v - mx);
    float ad = adj_s[jj];
    float E = e, Em = ad * e;
    #pragma unroll
    for (int s = 32; s > 0; s >>= 1) {
      E += __shfl_xor(E, s, 64);
      Em += __shfl_xor(Em, s, 64);
    }
    w_s[jj * 5 + hh] = ad * e / (Em + 1e-10f * E);
  }
  __syncthreads();
  // mw[hh][d] = sum_j w[j,hh] * msg[j,d]  -> mw_g
  {
    const int hh0 = t >> 7, d = t & 127;
    float a0 = 0.f, a1 = 0.f;
    for (int j = 0; j < 64; ++j) {
      float m = msg_s[j][d];
      a0 += w_s[j * 5 + hh0] * m;
      a1 += w_s[j * 5 + hh0 + 2] * m;
    }
    float* mp = mw_g + ((size_t)r * nblk + blk) * 512;
    mp[hh0 * 128 + d] = a0;
    mp[(hh0 + 2) * 128 + d] = a1;
  }
}

// ---------------- batched att = elu(mw @ P) (P read once per 64 agents) ----------------
__global__ __launch_bounds__(256) void k_pv(
    const float* __restrict__ mw_g, const float* __restrict__ Pq,
    float* __restrict__ att_r, int nblk) {
  const int b = blockIdx.x, r = blockIdx.y, t = threadIdx.x;
  const int dq = t & 31, ib = (t >> 5) * 8;
  float a0[8], a1[8], a2[8], a3[8];
  #pragma unroll
  for (int i = 0; i < 8; ++i) { a0[i] = 0.f; a1[i] = 0.f; a2[i] = 0.f; a3[i] = 0.f; }
  const float4* pq = (const float4*)(Pq + (size_t)r * 65536);
  const float* mwb = mw_g + ((size_t)r * nblk + b * 64) * 512;
  for (int c4 = 0; c4 < 128; ++c4) {
    float4 w0 = pq[c4 * 128 + dq];
    float4 w1 = pq[c4 * 128 + dq + 32];
    float4 w2 = pq[c4 * 128 + dq + 64];
    float4 w3 = pq[c4 * 128 + dq + 96];
    #pragma unroll
    for (int i = 0; i < 8; ++i) {
      float4 v = *(const float4*)&mwb[(size_t)(ib + i) * 512 + c4 * 4];
      a0[i] += v.x * w0.x; a0[i] += v.y * w0.y; a0[i] += v.z * w0.z; a0[i] += v.w * w0.w;
      a1[i] += v.x * w1.x; a1[i] += v.y * w1.y; a1[i] += v.z * w1.z; a1[i] += v.w * w1.w;
      a2[i] += v.x * w2.x; a2[i] += v.y * w2.y; a2[i] += v.z * w2.z; a2[i] += v.w * w2.w;
      a3[i] += v.x * w3.x; a3[i] += v.y * w3.y; a3[i] += v.z * w3.z; a3[i] += v.w * w3.w;
    }
  }
  #pragma unroll
  for (int i = 0; i < 8; ++i) {
    float* ap = att_r + ((size_t)r * nblk + b * 64 + ib + i) * 128 + dq;
    ap[0]  = (a0[i] > 0.f) ? a0[i] : expm1f(a0[i]);
    ap[32] = (a1[i] > 0.f) ? a1[i] : expm1f(a1[i]);
    ap[64] = (a2[i] > 0.f) ? a2[i] : expm1f(a2[i]);
    ap[96] = (a3[i] > 0.f) ? a3[i] : expm1f(a3[i]);
  }
}

// ---------------- mean over rounds + output head ----------------
__global__ __launch_bounds__(128) void k_head(
    const float* __restrict__ h_f32, const float* __restrict__ att_r,
    const float* __restrict__ Wq1T, const float* __restrict__ b_q1,
    const float* __restrict__ Wq2T, const float* __restrict__ b_q2,
    float* __restrict__ out_q, int b0, int nblk) {
  const int blk = blockIdx.x, t = threadIdx.x;
  __shared__ float hi[128], agg[128], u[128];
  hi[t] = h_f32[(size_t)blk * 128 + t];
  agg[t] = (att_r[(size_t)blk * 128 + t] +
            att_r[((size_t)nblk + blk) * 128 + t] +
            att_r[((size_t)2 * nblk + blk) * 128 + t]) * (1.f / 3.f);
  __syncthreads();
  float a = b_q1[t];
  #pragma unroll 4
  for (int c = 0; c < 128; ++c) a += hi[c] * Wq1T[c * 128 + t];
  #pragma unroll 4
  for (int c = 0; c < 128; ++c) a += agg[c] * Wq1T[(128 + c) * 128 + t];
  u[t] = fmaxf(a, 0.f);
  __syncthreads();
  if (t < 20) {
    float a2 = b_q2[t];
    #pragma unroll 4
    for (int c = 0; c < 128; ++c) a2 += u[c] * Wq2T[c * 20 + t];
    out_q[((size_t)b0 * 64 + blk) * 20 + t] = a2;
  }
}

extern "C" void kernel_launch(void* const* d_in, const int* in_sizes, int n_in,
                              void* d_out, int out_size, void* d_ws, size_t ws_size,
                              hipStream_t stream) {
  (void)in_sizes; (void)n_in; (void)out_size;
  const float* obs    = (const float*)d_in[0];
  const float* hidden = (const float*)d_in[1];
  const float* gumb   = (const float*)d_in[2];
  const float* W_enc  = (const float*)d_in[3];
  const float* b_enc  = (const float*)d_in[4];
  const float* W_ih   = (const float*)d_in[5];
  const float* W_hh   = (const float*)d_in[6];
  const float* b_ih   = (const float*)d_in[7];
  const float* b_hh   = (const float*)d_in[8];
  const float* W_oth  = (const float*)d_in[9];
  const float* b_oth  = (const float*)d_in[10];
  const float* W_m1   = (const float*)d_in[11];
  const float* b_m1   = (const float*)d_in[12];
  const float* W_m2   = (const float*)d_in[13];
  const float* b_m2   = (const float*)d_in[14];
  const float* W_s1   = (const float*)d_in[15];
  const float* b_s1   = (const float*)d_in[16];
  const float* W_s2   = (const float*)d_in[17];
  const float* b_s2   = (const float*)d_in[18];
  const float* Wq     = (const float*)d_in[19];
  const float* Wk     = (const float*)d_in[20];
  const float* Wv     = (const float*)d_in[21];
  const float* Wo     = (const float*)d_in[22];
  const float* W_q1   = (const float*)d_in[23];
  const float* b_q1   = (const float*)d_in[24];
  const float* W_q2   = (const float*)d_in[25];
  const float* b_q2   = (const float*)d_in[26];

  float* ws    = (float*)d_ws;
  float* Wm1q  = ws + WM1_OFF;
  float* Wm2q  = ws + WM2_OFF;
  float* Ws1q  = ws + WS1_OFF;
  float* Wm1sT = ws + WM1ST_OFF;
  float* Ws1sT = ws + WS1ST_OFF;
  float* WencT = ws + WENCT_OFF;
  float* WihT  = ws + WIHT_OFF;
  float* WhhT  = ws + WHHT_OFF;
  float* WothT = ws + WOTHT_OFF;
  float* Wq1T  = ws + WQ1T_OFF;
  float* Wq2T  = ws + WQ2T_OFF;
  float* Mhq   = ws + MH_OFF;
  float* Pq    = ws + P_OFF;

  float* out_q = (float*)d_out;  // f32 output: qout then h
  float* out_h = out_q + BZc * NAc * NACTc;

  // per-b chunk bytes: h 32K + oth 32K + othp 32K + sp1 32K + spS 48K + S 96K
  //                    + att 96K + qW 384K + mw 384K + msg(bf16) 1M = 2211840
  int BC = 64;
  while (BC > 1) {
    size_t need = 4ull * CHUNK_BASE + (size_t)BC * 2211840ull;
    if (need <= ws_size) break;
    BC >>= 1;
  }
  const int nblk = BC * 64;
  float* h_f32   = ws + CHUNK_BASE;
  float* oth_f32 = h_f32 + (size_t)BC * 8192;
  float* othp    = oth_f32 + (size_t)BC * 8192;
  float* sp1_g   = othp + (size_t)BC * 8192;
  float* spS_g   = sp1_g + (size_t)BC * 8192;
  float* S_g     = spS_g + (size_t)BC * 12288;
  float* att_rb  = S_g + (size_t)BC * 24576;
  float* qW_g    = att_rb + (size_t)BC * 24576;
  float* mw_g    = qW_g + (size_t)BC * 98304;
  bf16*  msg_g   = (bf16*)(mw_g + (size_t)BC * 98304);

  kW<<<dim3(1018), dim3(256), 0, stream>>>(W_m1, W_m2, W_s1, W_enc, W_ih, W_hh,
                                           W_oth, W_q1, W_q2, ws);
  kMP<<<dim3(24), dim3(256), 0, stream>>>(Wq, Wk, Wv, Wo, Mhq, Pq);
  for (int b0 = 0; b0 < BZc; b0 += BC) {
    k_enc<<<dim3(nblk), dim3(128), 0, stream>>>(obs, hidden, WencT, b_enc, WihT, WhhT,
                                                b_ih, b_hh, WothT, b_oth,
                                                h_f32, oth_f32, out_h, b0);
    k_sp<<<dim3(nblk), dim3(320), 0, stream>>>(h_f32, Wm1sT, b_m1, Ws1sT, b_s1,
                                               sp1_g, spS_g);
    k_othp<<<dim3(BC), dim3(256), 0, stream>>>(oth_f32, Wm1q, othp);
    k_msg<<<dim3(nblk), dim3(256), 0, stream>>>(othp, sp1_g, spS_g,
                                                Wm2q, b_m2, Ws1q,
                                                W_s2, b_s2, msg_g, S_g, nblk);
    k_qw<<<dim3(BC, 3), dim3(256), 0, stream>>>(h_f32, Mhq, qW_g, nblk);
    k_attn<<<dim3(nblk, 3), dim3(256), 0, stream>>>(msg_g, S_g, gumb, qW_g,
                                                    mw_g, b0, nblk);
    k_pv<<<dim3(BC, 3), dim3(256), 0, stream>>>(mw_g, Pq, att_rb, nblk);
    k_head<<<dim3(nblk), dim3(128), 0, stream>>>(h_f32, att_rb, Wq1T, b_q1,
                                                 Wq2T, b_q2, out_q, b0, nblk);
  }
}

// Round 17
// 778.089 us; speedup vs baseline: 15.4969x; 1.0039x over previous
//
#include <hip/hip_runtime.h>
#include <hip/hip_bf16.h>

typedef __hip_bfloat16 bf16;

#define BZc 64
#define NAc 64
#define Dc 128
#define Rc 3
#define Hc 4
#define INc 96
#define NACTc 20

// fixed workspace layout (float element offsets)
#define WM1_OFF    0        // 16384 : W_m1 others-half, float4-permuted by dm
#define WM2_OFF    16384    // 16384 : W_m2 float4-permuted
#define WS1_OFF    32768    // 24576 : W_s1 msg-half, float4-permuted by du
#define WM1ST_OFF  57344    // 16384 : W_m1 self-half, transposed [c][dm]
#define WS1ST_OFF  73728    // 24576 : W_s1 self-half, transposed [r][c][du]
#define WENCT_OFF  98304    // 12288 : W_enc^T [c][128]
#define WIHT_OFF   110592   // 49152 : W_ih^T  [c][384]
#define WHHT_OFF   159744   // 49152 : W_hh^T  [c][384]
#define WOTHT_OFF  208896   // 16384 : W_oth^T [c][128]
#define WQ1T_OFF   225280   // 32768 : W_q1^T  [c][128]
#define WQ2T_OFF   258048   // 2560  : W_q2^T  [c][20]
#define MH_OFF     260608   // 196608: Mhq[r][hh] float4-permuted (Wq_h^T Wk_h)
#define P_OFF      457216   // 196608: Pq[r] float4-permuted (k=hh*128+d major)
#define CHUNK_BASE 655360   // floats; per-chunk region starts here

// ---------------- weight permute / transpose kernel ----------------
__global__ void kW(const float* __restrict__ W_m1, const float* __restrict__ W_m2,
                   const float* __restrict__ W_s1, const float* __restrict__ W_enc,
                   const float* __restrict__ W_ih, const float* __restrict__ W_hh,
                   const float* __restrict__ W_oth, const float* __restrict__ W_q1,
                   const float* __restrict__ W_q2, float* __restrict__ ws) {
  int idx = blockIdx.x * blockDim.x + threadIdx.x;
  if (idx < 16384) {
    int dm = idx & 127, c = idx >> 7;
    ws[WM1_OFF + ((c >> 2) * 128 + dm) * 4 + (c & 3)] = W_m1[dm * 256 + c];
  } else if (idx < 32768) {
    int k = idx - 16384;
    int dm = k & 127, c = k >> 7;
    ws[WM2_OFF + ((c >> 2) * 128 + dm) * 4 + (c & 3)] = W_m2[dm * 128 + c];
  } else if (idx < 57344) {
    int k = idx - 32768;
    int r = k >> 13, rem = k & 8191;
    int du = rem & 63, c = rem >> 6;
    ws[WS1_OFF + r * 8192 + ((c >> 2) * 64 + du) * 4 + (c & 3)] =
        W_s1[(r * 64 + du) * 256 + 128 + c];
  } else if (idx < 73728) {
    int k = idx - 57344;
    int dm = k & 127, c = k >> 7;
    ws[WM1ST_OFF + c * 128 + dm] = W_m1[dm * 256 + 128 + c];
  } else if (idx < 98304) {
    int k = idx - 73728;
    int r = k >> 13, rem = k & 8191;
    int du = rem & 63, c = rem >> 6;
    ws[WS1ST_OFF + r * 8192 + c * 64 + du] = W_s1[(r * 64 + du) * 256 + c];
  } else if (idx < 110592) {
    int k = idx - 98304;              // W_encT [96][128]
    int o = k & 127, c = k >> 7;
    ws[WENCT_OFF + c * 128 + o] = W_enc[o * 96 + c];
  } else if (idx < 159744) {
    int k = idx - 110592;             // W_ihT [128][384]
    int o = k % 384, c = k / 384;
    ws[WIHT_OFF + c * 384 + o] = W_ih[o * 128 + c];
  } else if (idx < 208896) {
    int k = idx - 159744;             // W_hhT [128][384]
    int o = k % 384, c = k / 384;
    ws[WHHT_OFF + c * 384 + o] = W_hh[o * 128 + c];
  } else if (idx < 225280) {
    int k = idx - 208896;             // W_othT [128][128]
    int o = k & 127, c = k >> 7;
    ws[WOTHT_OFF + c * 128 + o] = W_oth[o * 128 + c];
  } else if (idx < 258048) {
    int k = idx - 225280;             // W_q1T [256][128]
    int o = k & 127, c = k >> 7;
    ws[WQ1T_OFF + c * 128 + o] = W_q1[o * 256 + c];
  } else if (idx < 260608) {
    int k = idx - 258048;             // W_q2T [128][20]
    int o = k % 20, c = k / 20;
    ws[WQ2T_OFF + c * 20 + o] = W_q2[o * 128 + c];
  }
}

// ---------------- per-head projection folds, stored float4-permuted ----------------
__global__ __launch_bounds__(256) void kMP(
    const float* __restrict__ Wq, const float* __restrict__ Wk,
    const float* __restrict__ Wv, const float* __restrict__ Wo,
    float* __restrict__ Mhq, float* __restrict__ Pq) {
  const int bid = blockIdx.x;  // 24 = r*8 + hh*2 + which
  const int which = bid & 1, hh = (bid >> 1) & 3, r = bid >> 3;
  const int t = threadIdx.x;
  __shared__ float A[4096];
  __shared__ float B[4224];
  if (which == 0) {
    for (int k = t; k < 4096; k += 256) {
      int e = k >> 7, c = k & 127;
      A[k] = Wq[(r * 128 + hh * 32 + e) * 128 + c];
      B[k] = Wk[(r * 128 + hh * 32 + e) * 128 + c];
    }
    __syncthreads();
    for (int k = 0; k < 64; ++k) {
      int o = k * 256 + t, c = o >> 7, d = o & 127;
      float a = 0.f;
      #pragma unroll 8
      for (int e = 0; e < 32; ++e) a += A[e * 128 + c] * B[e * 128 + d];
      Mhq[(size_t)(r * 4 + hh) * 16384 + ((c >> 2) * 128 + d) * 4 + (c & 3)] = a;
    }
  } else {
    for (int k = t; k < 4096; k += 256) A[k] = Wv[(r * 128 + hh * 32 + (k >> 7)) * 128 + (k & 127)];
    for (int k = t; k < 4096; k += 256) {
      int dp = k >> 5, e = k & 31;
      B[dp * 33 + e] = Wo[(r * 128 + dp) * 128 + hh * 32 + e];
    }
    __syncthreads();
    for (int k = 0; k < 64; ++k) {
      int o = k * 256 + t, d = o >> 7, dp = o & 127;
      float a = 0.f;
      #pragma unroll 8
      for (int e = 0; e < 32; ++e) a += A[e * 128 + d] * B[dp * 33 + e];
      int kk = hh * 128 + d;
      Pq[(size_t)r * 65536 + ((kk >> 2) * 128 + dp) * 4 + (kk & 3)] = a;
    }
  }
}

// ---------------- encoder + GRU + others + self-half partials (k_sp fused) ----------------
__global__ __launch_bounds__(128) void k_enc(
    const float* __restrict__ obs, const float* __restrict__ hidden,
    const float* __restrict__ WencT, const float* __restrict__ b_enc,
    const float* __restrict__ WihT, const float* __restrict__ WhhT,
    const float* __restrict__ b_ih, const float* __restrict__ b_hh,
    const float* __restrict__ WothT, const float* __restrict__ b_oth,
    const float* __restrict__ Wm1sT, const float* __restrict__ b_m1,
    const float* __restrict__ Ws1sT, const float* __restrict__ b_s1,
    float* __restrict__ h_f32, float* __restrict__ oth_f32,
    float* __restrict__ sp1_g, float* __restrict__ spS_g,
    float* __restrict__ out_h, int b0) {
  const int row_l = blockIdx.x, t = threadIdx.x;
  const int row_g = b0 * 64 + row_l;
  __shared__ float obs_s[96], hid_s[128], x_s[128], h_s[128];
  if (t < 96) obs_s[t] = obs[row_g * 96 + t];
  hid_s[t] = hidden[row_g * 128 + t];
  __syncthreads();
  float x = b_enc[t];
  #pragma unroll 8
  for (int c = 0; c < 96; ++c) x += obs_s[c] * WencT[c * 128 + t];
  x_s[t] = x;
  __syncthreads();
  float gxr = b_ih[t], gxz = b_ih[t + 128], gxn = b_ih[t + 256];
  float ghr = b_hh[t], ghz = b_hh[t + 128], ghn = b_hh[t + 256];
  #pragma unroll 4
  for (int c = 0; c < 128; ++c) {
    float xv = x_s[c], hv = hid_s[c];
    const float* wi = WihT + c * 384 + t;
    const float* wh = WhhT + c * 384 + t;
    gxr += xv * wi[0]; gxz += xv * wi[128]; gxn += xv * wi[256];
    ghr += hv * wh[0]; ghz += hv * wh[128]; ghn += hv * wh[256];
  }
  float rg = 1.f / (1.f + expf(-(gxr + ghr)));
  float zg = 1.f / (1.f + expf(-(gxz + ghz)));
  float ng = tanhf(gxn + rg * ghn);
  float hv = (1.f - zg) * ng + zg * hid_s[t];
  h_s[t] = hv;
  h_f32[row_l * 128 + t] = hv;
  out_h[(size_t)row_g * 128 + t] = hv;
  __syncthreads();
  float o = b_oth[t];
  #pragma unroll 4
  for (int c = 0; c < 128; ++c) o += h_s[c] * WothT[c * 128 + t];
  oth_f32[row_l * 128 + t] = o;
  // ---- fused k_sp: chains identical (seed bias, ascending c, h_s == h_f32) ----
  {
    float a = b_m1[t];
    #pragma unroll 4
    for (int c = 0; c < 128; ++c) a += h_s[c] * Wm1sT[c * 128 + t];
    sp1_g[(size_t)row_l * 128 + t] = a;
  }
  {
    const int r = t >> 6, du = t & 63;   // o = t in [0,128)
    float a = b_s1[r * 64 + du];
    #pragma unroll 4
    for (int c = 0; c < 128; ++c) a += h_s[c] * Ws1sT[r * 8192 + c * 64 + du];
    spS_g[(size_t)row_l * 192 + r * 64 + du] = a;
  }
  if (t < 64) {                          // o = 128 + t (r = 2)
    const int du = t;
    float a = b_s1[128 + du];
    #pragma unroll 4
    for (int c = 0; c < 128; ++c) a += h_s[c] * Ws1sT[16384 + c * 64 + du];
    spS_g[(size_t)row_l * 192 + 128 + du] = a;
  }
}

// ---------------- i-invariant hoist: othp[b][j][dm] = others[b][j] @ W1_others^T ----
__global__ __launch_bounds__(256) void k_othp(
    const float* __restrict__ oth_f32, const float* __restrict__ Wm1q,
    float* __restrict__ othp) {
  const int b = blockIdx.x, t = threadIdx.x;
  const int dq = t & 31, jb = (t >> 5) * 8;
  __shared__ float oth_s[8192];
  {
    const float4* og = (const float4*)(oth_f32 + (size_t)b * 8192);
    float4* os = (float4*)oth_s;
    for (int k = t; k < 2048; k += 256) os[k] = og[k];
  }
  __syncthreads();
  float a0[8], a1[8], a2[8], a3[8];
  #pragma unroll
  for (int j = 0; j < 8; ++j) { a0[j] = 0.f; a1[j] = 0.f; a2[j] = 0.f; a3[j] = 0.f; }
  const float4* wq = (const float4*)Wm1q;
  for (int c4 = 0; c4 < 32; ++c4) {
    float4 w0 = wq[c4 * 128 + dq];
    float4 w1 = wq[c4 * 128 + dq + 32];
    float4 w2 = wq[c4 * 128 + dq + 64];
    float4 w3 = wq[c4 * 128 + dq + 96];
    #pragma unroll
    for (int j = 0; j < 8; ++j) {
      float4 v = *(const float4*)&oth_s[(jb + j) * 128 + c4 * 4];
      a0[j] += v.x * w0.x; a0[j] += v.y * w0.y; a0[j] += v.z * w0.z; a0[j] += v.w * w0.w;
      a1[j] += v.x * w1.x; a1[j] += v.y * w1.y; a1[j] += v.z * w1.z; a1[j] += v.w * w1.w;
      a2[j] += v.x * w2.x; a2[j] += v.y * w2.y; a2[j] += v.z * w2.z; a2[j] += v.w * w2.w;
      a3[j] += v.x * w3.x; a3[j] += v.y * w3.y; a3[j] += v.z * w3.z; a3[j] += v.w * w3.w;
    }
  }
  #pragma unroll
  for (int j = 0; j < 8; ++j) {
    float* op = othp + (size_t)b * 8192 + (jb + j) * 128 + dq;
    op[0]  = a0[j];
    op[32] = a1[j];
    op[64] = a2[j];
    op[96] = a3[j];
  }
}

// ---------------- message layer2 + scheduler MLP ----------------
// Round 17: float4-vectorized staging (same adds, packed). Arithmetic chains
// byte-identical to round 16.
__global__ __launch_bounds__(256) void k_msg(
    const float* __restrict__ othp, const float* __restrict__ sp1_g,
    const float* __restrict__ spS_g,
    const float* __restrict__ Wm2q, const float* __restrict__ b_m2,
    const float* __restrict__ Ws1q, const float* __restrict__ W_s2,
    const float* __restrict__ b_s2,
    bf16* __restrict__ msg_g, float* __restrict__ S_g, int nblk) {
  const int blk = blockIdx.x;        // local: b_l*64 + i
  const int b = blk >> 6;
  const int t = threadIdx.x;
  __shared__ float buf_s[64 * 128];  // 32KB: tact, overwritten in place by msg
  const int dq = t & 31;             // dm quad: dm = dq + 32*k, k=0..3
  const int jb = (t >> 5) * 8;       // 8 j-groups of 8
  const int l = t & 63, wv = t >> 6; // scheduler mapping (l = du = lane)

  // fused staging (float4): float4 index i covers dm = 4*(i&31)+{0..3};
  // i mod 32 == t mod 32 for all iterations -> one sp float4 per thread.
  {
    const float4 sp4 = *(const float4*)(sp1_g + (size_t)blk * 128 + 4 * (t & 31));
    const float4* op = (const float4*)(othp + (size_t)b * 8192);
    float4* bs = (float4*)buf_s;
    #pragma unroll
    for (int u = 0; u < 8; ++u) {
      const int i = u * 256 + t;
      float4 v = op[i];
      float4 o;
      o.x = fmaxf(v.x + sp4.x, 0.f);
      o.y = fmaxf(v.y + sp4.y, 0.f);
      o.z = fmaxf(v.z + sp4.z, 0.f);
      o.w = fmaxf(v.w + sp4.w, 0.f);
      bs[i] = o;
    }
  }
  const float* sps = spS_g + (size_t)blk * 192;
  const float spS0 = sps[l], spS1 = sps[64 + l], spS2 = sps[128 + l];
  __syncthreads();
  // ---- message layer 2: reads buf_s (tact), overwrites with msg ----
  {
    float a0[8], a1[8], a2[8], a3[8];
    const float s0 = b_m2[dq], s1 = b_m2[dq + 32], s2 = b_m2[dq + 64], s3 = b_m2[dq + 96];
    #pragma unroll
    for (int j = 0; j < 8; ++j) { a0[j] = s0; a1[j] = s1; a2[j] = s2; a3[j] = s3; }
    const float4* wq = (const float4*)Wm2q;
    for (int c4 = 0; c4 < 32; ++c4) {
      float4 w0 = wq[c4 * 128 + dq];
      float4 w1 = wq[c4 * 128 + dq + 32];
      float4 w2 = wq[c4 * 128 + dq + 64];
      float4 w3 = wq[c4 * 128 + dq + 96];
      #pragma unroll
      for (int j = 0; j < 8; ++j) {
        float4 v = *(const float4*)&buf_s[(jb + j) * 128 + c4 * 4];
        a0[j] += v.x * w0.x; a0[j] += v.y * w0.y; a0[j] += v.z * w0.z; a0[j] += v.w * w0.w;
        a1[j] += v.x * w1.x; a1[j] += v.y * w1.y; a1[j] += v.z * w1.z; a1[j] += v.w * w1.w;
        a2[j] += v.x * w2.x; a2[j] += v.y * w2.y; a2[j] += v.z * w2.z; a2[j] += v.w * w2.w;
        a3[j] += v.x * w3.x; a3[j] += v.y * w3.y; a3[j] += v.z * w3.z; a3[j] += v.w * w3.w;
      }
    }
    #pragma unroll
    for (int j = 0; j < 8; ++j) {
      float m0 = fmaxf(a0[j], 0.f), m1 = fmaxf(a1[j], 0.f);
      float m2 = fmaxf(a2[j], 0.f), m3 = fmaxf(a3[j], 0.f);
      buf_s[(jb + j) * 128 + dq]      = m0;
      buf_s[(jb + j) * 128 + dq + 32] = m1;
      buf_s[(jb + j) * 128 + dq + 64] = m2;
      buf_s[(jb + j) * 128 + dq + 96] = m3;
      bf16* mg = msg_g + ((size_t)blk * 64 + (jb + j)) * 128 + dq;
      mg[0]  = __float2bfloat16(m0);
      mg[32] = __float2bfloat16(m1);
      mg[64] = __float2bfloat16(m2);
      mg[96] = __float2bfloat16(m3);
    }
  }
  __syncthreads();
  // ---- scheduler MLP: ONE c4 pass accumulating all 3 rounds ----
  float ua0[16], ua1[16], ua2[16];
  #pragma unroll
  for (int j = 0; j < 16; ++j) { ua0[j] = spS0; ua1[j] = spS1; ua2[j] = spS2; }
  {
    const float4* wq0 = (const float4*)(Ws1q);
    const float4* wq1 = (const float4*)(Ws1q + 8192);
    const float4* wq2 = (const float4*)(Ws1q + 16384);
    for (int c4 = 0; c4 < 32; ++c4) {
      float4 w0 = wq0[c4 * 64 + l];
      float4 w1 = wq1[c4 * 64 + l];
      float4 w2 = wq2[c4 * 64 + l];
      #pragma unroll
      for (int j = 0; j < 16; ++j) {
        float4 v = *(const float4*)&buf_s[(wv * 16 + j) * 128 + c4 * 4];
        ua0[j] += v.x * w0.x + v.y * w0.y + v.z * w0.z + v.w * w0.w;
        ua1[j] += v.x * w1.x + v.y * w1.y + v.z * w1.z + v.w * w1.w;
        ua2[j] += v.x * w2.x + v.y * w2.y + v.z * w2.z + v.w * w2.w;
      }
    }
  }
  // butterfly + store per round (identical form to round 16)
  {
    const float w2a = W_s2[0 * 64 + l], w2b = W_s2[1 * 64 + l];
    const float bs2a = b_s2[0], bs2b = b_s2[1];
    for (int j = 0; j < 16; ++j) {
      float u = fmaxf(ua0[j], 0.f);
      float v0 = u * w2a, v1 = u * w2b;
      #pragma unroll
      for (int s = 1; s < 64; s <<= 1) {
        v0 += __shfl_xor(v0, s, 64);
        v1 += __shfl_xor(v1, s, 64);
      }
      if (l == 0) {
        float* sp = S_g + (((size_t)0 * nblk + blk) * 64 + (wv * 16 + j)) * 2;
        sp[0] = v0 + bs2a;
        sp[1] = v1 + bs2b;
      }
    }
  }
  {
    const float w2a = W_s2[2 * 64 + l], w2b = W_s2[3 * 64 + l];
    const float bs2a = b_s2[2], bs2b = b_s2[3];
    for (int j = 0; j < 16; ++j) {
      float u = fmaxf(ua1[j], 0.f);
      float v0 = u * w2a, v1 = u * w2b;
      #pragma unroll
      for (int s = 1; s < 64; s <<= 1) {
        v0 += __shfl_xor(v0, s, 64);
        v1 += __shfl_xor(v1, s, 64);
      }
      if (l == 0) {
        float* sp = S_g + (((size_t)1 * nblk + blk) * 64 + (wv * 16 + j)) * 2;
        sp[0] = v0 + bs2a;
        sp[1] = v1 + bs2b;
      }
    }
  }
  {
    const float w2a = W_s2[4 * 64 + l], w2b = W_s2[5 * 64 + l];
    const float bs2a = b_s2[4], bs2b = b_s2[5];
    for (int j = 0; j < 16; ++j) {
      float u = fmaxf(ua2[j], 0.f);
      float v0 = u * w2a, v1 = u * w2b;
      #pragma unroll
      for (int s = 1; s < 64; s <<= 1) {
        v0 += __shfl_xor(v0, s, 64);
        v1 += __shfl_xor(v1, s, 64);
      }
      if (l == 0) {
        float* sp = S_g + (((size_t)2 * nblk + blk) * 64 + (wv * 16 + j)) * 2;
        sp[0] = v0 + bs2a;
        sp[1] = v1 + bs2b;
      }
    }
  }
}

// ---------------- batched qW = h @ Mh (Mh read once per 64 agents) ----------------
__global__ __launch_bounds__(256) void k_qw(
    const float* __restrict__ h_f32, const float* __restrict__ Mhq,
    float* __restrict__ qW_g, int nblk) {
  const int b = blockIdx.x, r = blockIdx.y, t = threadIdx.x;
  __shared__ float h_s[8192];
  {
    const float4* hg = (const float4*)(h_f32 + (size_t)b * 8192);
    float4* hs = (float4*)h_s;
    for (int k = t; k < 2048; k += 256) hs[k] = hg[k];
  }
  __syncthreads();
  const int dq = t & 31, ib = (t >> 5) * 8;
  for (int hh = 0; hh < 4; ++hh) {
    float a0[8], a1[8], a2[8], a3[8];
    #pragma unroll
    for (int i = 0; i < 8; ++i) { a0[i] = 0.f; a1[i] = 0.f; a2[i] = 0.f; a3[i] = 0.f; }
    const float4* mq = (const float4*)(Mhq + (size_t)(r * 4 + hh) * 16384);
    for (int c4 = 0; c4 < 32; ++c4) {
      float4 w0 = mq[c4 * 128 + dq];
      float4 w1 = mq[c4 * 128 + dq + 32];
      float4 w2 = mq[c4 * 128 + dq + 64];
      float4 w3 = mq[c4 * 128 + dq + 96];
      #pragma unroll
      for (int i = 0; i < 8; ++i) {
        float4 v = *(const float4*)&h_s[(ib + i) * 128 + c4 * 4];
        a0[i] += v.x * w0.x; a0[i] += v.y * w0.y; a0[i] += v.z * w0.z; a0[i] += v.w * w0.w;
        a1[i] += v.x * w1.x; a1[i] += v.y * w1.y; a1[i] += v.z * w1.z; a1[i] += v.w * w1.w;
        a2[i] += v.x * w2.x; a2[i] += v.y * w2.y; a2[i] += v.z * w2.z; a2[i] += v.w * w2.w;
        a3[i] += v.x * w3.x; a3[i] += v.y * w3.y; a3[i] += v.z * w3.z; a3[i] += v.w * w3.w;
      }
    }
    #pragma unroll
    for (int i = 0; i < 8; ++i) {
      float* qp = qW_g + ((size_t)r * nblk + b * 64 + ib + i) * 512 + hh * 128 + dq;
      qp[0]  = a0[i];
      qp[32] = a1[i];
      qp[64] = a2[i];
      qp[96] = a3[i];
    }
  }
}

// ---------------- adjacency + scores + masked softmax + mw (core) ----------------
__global__ __launch_bounds__(256) void k_attn(
    const bf16* __restrict__ msg_g, const float* __restrict__ S_g,
    const float* __restrict__ gumbel, const float* __restrict__ qW_g,
    float* __restrict__ mw_g, int b0, int nblk) {
  const int blk = blockIdx.x, r = blockIdx.y;
  const int b = blk >> 6, i = blk & 63, t = threadIdx.x;
  __shared__ float msg_s[64][132];
  __shared__ float qW_s[4][132];
  __shared__ float sc_s[320];
  __shared__ float adj_s[64];
  __shared__ float w_s[320];

  {
    const uint4* mb = (const uint4*)(msg_g + (size_t)blk * 8192);
    for (int q = t; q < 1024; q += 256) {
      uint4 v4 = mb[q];
      int j = q >> 4, d8 = (q & 15) * 8;
      msg_s[j][d8 + 0] = __uint_as_float(v4.x << 16);
      msg_s[j][d8 + 1] = __uint_as_float(v4.x & 0xffff0000u);
      msg_s[j][d8 + 2] = __uint_as_float(v4.y << 16);
      msg_s[j][d8 + 3] = __uint_as_float(v4.y & 0xffff0000u);
      msg_s[j][d8 + 4] = __uint_as_float(v4.z << 16);
      msg_s[j][d8 + 5] = __uint_as_float(v4.z & 0xffff0000u);
      msg_s[j][d8 + 6] = __uint_as_float(v4.w << 16);
      msg_s[j][d8 + 7] = __uint_as_float(v4.w & 0xffff0000u);
    }
  }
  for (int o = t; o < 512; o += 256)
    qW_s[o >> 7][o & 127] = qW_g[((size_t)r * nblk + blk) * 512 + o];
  if (t < 64) {
    const int j = t;
    const float* Sij = S_g + (((size_t)r * nblk + blk) * 64 + j) * 2;
    const float* Sji = S_g + (((size_t)r * nblk + b * 64 + j) * 64 + i) * 2;
    const float* g = gumbel + ((((size_t)r * 64 + (b0 + b)) * 64 + i) * 64 + j) * 2;
    float y0 = 0.5f * Sij[0] + 0.5f * Sji[0] + g[0];
    float y1 = 0.5f * Sij[1] + 0.5f * Sji[1] + g[1];
    adj_s[j] = (y1 > y0) ? 1.f : 0.f;
  }
  __syncthreads();
  // scores[j][hh]
  {
    const int j = t >> 2, hh = t & 3;
    float a = 0.f;
    #pragma unroll
    for (int d4 = 0; d4 < 32; ++d4) {
      float4 mv = *(const float4*)&msg_s[j][d4 * 4];
      float4 qv = *(const float4*)&qW_s[hh][d4 * 4];
      a += mv.x * qv.x + mv.y * qv.y + mv.z * qv.z + mv.w * qv.w;
    }
    sc_s[j * 5 + hh] = a * 0.17677669529663687f;  // 1/sqrt(32)
  }
  __syncthreads();
  // masked softmax per head (one wave per head)
  {
    const int hh = t >> 6, jj = t & 63;
    float v = sc_s[jj * 5 + hh];
    float mx = v;
    #pragma unroll
    for (int s = 32; s > 0; s >>= 1) mx = fmaxf(mx, __shfl_xor(mx, s, 64));
    float e = expf(v - mx);
    float ad = adj_s[jj];
    float E = e, Em = ad * e;
    #pragma unroll
    for (int s = 32; s > 0; s >>= 1) {
      E += __shfl_xor(E, s, 64);
      Em += __shfl_xor(Em, s, 64);
    }
    w_s[jj * 5 + hh] = ad * e / (Em + 1e-10f * E);
  }
  __syncthreads();
  // mw[hh][d] = sum_j w[j,hh] * msg[j,d]  -> mw_g
  {
    const int hh0 = t >> 7, d = t & 127;
    float a0 = 0.f, a1 = 0.f;
    for (int j = 0; j < 64; ++j) {
      float m = msg_s[j][d];
      a0 += w_s[j * 5 + hh0] * m;
      a1 += w_s[j * 5 + hh0 + 2] * m;
    }
    float* mp = mw_g + ((size_t)r * nblk + blk) * 512;
    mp[hh0 * 128 + d] = a0;
    mp[(hh0 + 2) * 128 + d] = a1;
  }
}

// ---------------- batched att = elu(mw @ P) (P read once per 64 agents) ----------------
__global__ __launch_bounds__(256) void k_pv(
    const float* __restrict__ mw_g, const float* __restrict__ Pq,
    float* __restrict__ att_r, int nblk) {
  const int b = blockIdx.x, r = blockIdx.y, t = threadIdx.x;
  const int dq = t & 31, ib = (t >> 5) * 8;
  float a0[8], a1[8], a2[8], a3[8];
  #pragma unroll
  for (int i = 0; i < 8; ++i) { a0[i] = 0.f; a1[i] = 0.f; a2[i] = 0.f; a3[i] = 0.f; }
  const float4* pq = (const float4*)(Pq + (size_t)r * 65536);
  const float* mwb = mw_g + ((size_t)r * nblk + b * 64) * 512;
  for (int c4 = 0; c4 < 128; ++c4) {
    float4 w0 = pq[c4 * 128 + dq];
    float4 w1 = pq[c4 * 128 + dq + 32];
    float4 w2 = pq[c4 * 128 + dq + 64];
    float4 w3 = pq[c4 * 128 + dq + 96];
    #pragma unroll
    for (int i = 0; i < 8; ++i) {
      float4 v = *(const float4*)&mwb[(size_t)(ib + i) * 512 + c4 * 4];
      a0[i] += v.x * w0.x; a0[i] += v.y * w0.y; a0[i] += v.z * w0.z; a0[i] += v.w * w0.w;
      a1[i] += v.x * w1.x; a1[i] += v.y * w1.y; a1[i] += v.z * w1.z; a1[i] += v.w * w1.w;
      a2[i] += v.x * w2.x; a2[i] += v.y * w2.y; a2[i] += v.z * w2.z; a2[i] += v.w * w2.w;
      a3[i] += v.x * w3.x; a3[i] += v.y * w3.y; a3[i] += v.z * w3.z; a3[i] += v.w * w3.w;
    }
  }
  #pragma unroll
  for (int i = 0; i < 8; ++i) {
    float* ap = att_r + ((size_t)r * nblk + b * 64 + ib + i) * 128 + dq;
    ap[0]  = (a0[i] > 0.f) ? a0[i] : expm1f(a0[i]);
    ap[32] = (a1[i] > 0.f) ? a1[i] : expm1f(a1[i]);
    ap[64] = (a2[i] > 0.f) ? a2[i] : expm1f(a2[i]);
    ap[96] = (a3[i] > 0.f) ? a3[i] : expm1f(a3[i]);
  }
}

// ---------------- mean over rounds + output head ----------------
__global__ __launch_bounds__(128) void k_head(
    const float* __restrict__ h_f32, const float* __restrict__ att_r,
    const float* __restrict__ Wq1T, const float* __restrict__ b_q1,
    const float* __restrict__ Wq2T, const float* __restrict__ b_q2,
    float* __restrict__ out_q, int b0, int nblk) {
  const int blk = blockIdx.x, t = threadIdx.x;
  __shared__ float hi[128], agg[128], u[128];
  hi[t] = h_f32[(size_t)blk * 128 + t];
  agg[t] = (att_r[(size_t)blk * 128 + t] +
            att_r[((size_t)nblk + blk) * 128 + t] +
            att_r[((size_t)2 * nblk + blk) * 128 + t]) * (1.f / 3.f);
  __syncthreads();
  float a = b_q1[t];
  #pragma unroll 4
  for (int c = 0; c < 128; ++c) a += hi[c] * Wq1T[c * 128 + t];
  #pragma unroll 4
  for (int c = 0; c < 128; ++c) a += agg[c] * Wq1T[(128 + c) * 128 + t];
  u[t] = fmaxf(a, 0.f);
  __syncthreads();
  if (t < 20) {
    float a2 = b_q2[t];
    #pragma unroll 4
    for (int c = 0; c < 128; ++c) a2 += u[c] * Wq2T[c * 20 + t];
    out_q[((size_t)b0 * 64 + blk) * 20 + t] = a2;
  }
}

extern "C" void kernel_launch(void* const* d_in, const int* in_sizes, int n_in,
                              void* d_out, int out_size, void* d_ws, size_t ws_size,
                              hipStream_t stream) {
  (void)in_sizes; (void)n_in; (void)out_size;
  const float* obs    = (const float*)d_in[0];
  const float* hidden = (const float*)d_in[1];
  const float* gumb   = (const float*)d_in[2];
  const float* W_enc  = (const float*)d_in[3];
  const float* b_enc  = (const float*)d_in[4];
  const float* W_ih   = (const float*)d_in[5];
  const float* W_hh   = (const float*)d_in[6];
  const float* b_ih   = (const float*)d_in[7];
  const float* b_hh   = (const float*)d_in[8];
  const float* W_oth  = (const float*)d_in[9];
  const float* b_oth  = (const float*)d_in[10];
  const float* W_m1   = (const float*)d_in[11];
  const float* b_m1   = (const float*)d_in[12];
  const float* W_m2   = (const float*)d_in[13];
  const float* b_m2   = (const float*)d_in[14];
  const float* W_s1   = (const float*)d_in[15];
  const float* b_s1   = (const float*)d_in[16];
  const float* W_s2   = (const float*)d_in[17];
  const float* b_s2   = (const float*)d_in[18];
  const float* Wq     = (const float*)d_in[19];
  const float* Wk     = (const float*)d_in[20];
  const float* Wv     = (const float*)d_in[21];
  const float* Wo     = (const float*)d_in[22];
  const float* W_q1   = (const float*)d_in[23];
  const float* b_q1   = (const float*)d_in[24];
  const float* W_q2   = (const float*)d_in[25];
  const float* b_q2   = (const float*)d_in[26];

  float* ws    = (float*)d_ws;
  float* Wm1q  = ws + WM1_OFF;
  float* Wm2q  = ws + WM2_OFF;
  float* Ws1q  = ws + WS1_OFF;
  float* Wm1sT = ws + WM1ST_OFF;
  float* Ws1sT = ws + WS1ST_OFF;
  float* WencT = ws + WENCT_OFF;
  float* WihT  = ws + WIHT_OFF;
  float* WhhT  = ws + WHHT_OFF;
  float* WothT = ws + WOTHT_OFF;
  float* Wq1T  = ws + WQ1T_OFF;
  float* Wq2T  = ws + WQ2T_OFF;
  float* Mhq   = ws + MH_OFF;
  float* Pq    = ws + P_OFF;

  float* out_q = (float*)d_out;  // f32 output: qout then h
  float* out_h = out_q + BZc * NAc * NACTc;

  // per-b chunk bytes: h 32K + oth 32K + othp 32K + sp1 32K + spS 48K + S 96K
  //                    + att 96K + qW 384K + mw 384K + msg(bf16) 1M = 2211840
  int BC = 64;
  while (BC > 1) {
    size_t need = 4ull * CHUNK_BASE + (size_t)BC * 2211840ull;
    if (need <= ws_size) break;
    BC >>= 1;
  }
  const int nblk = BC * 64;
  float* h_f32   = ws + CHUNK_BASE;
  float* oth_f32 = h_f32 + (size_t)BC * 8192;
  float* othp    = oth_f32 + (size_t)BC * 8192;
  float* sp1_g   = othp + (size_t)BC * 8192;
  float* spS_g   = sp1_g + (size_t)BC * 8192;
  float* S_g     = spS_g + (size_t)BC * 12288;
  float* att_rb  = S_g + (size_t)BC * 24576;
  float* qW_g    = att_rb + (size_t)BC * 24576;
  float* mw_g    = qW_g + (size_t)BC * 98304;
  bf16*  msg_g   = (bf16*)(mw_g + (size_t)BC * 98304);

  kW<<<dim3(1018), dim3(256), 0, stream>>>(W_m1, W_m2, W_s1, W_enc, W_ih, W_hh,
                                           W_oth, W_q1, W_q2, ws);
  kMP<<<dim3(24), dim3(256), 0, stream>>>(Wq, Wk, Wv, Wo, Mhq, Pq);
  for (int b0 = 0; b0 < BZc; b0 += BC) {
    k_enc<<<dim3(nblk), dim3(128), 0, stream>>>(obs, hidden, WencT, b_enc, WihT, WhhT,
                                                b_ih, b_hh, WothT, b_oth,
                                                Wm1sT, b_m1, Ws1sT, b_s1,
                                                h_f32, oth_f32, sp1_g, spS_g,
                                                out_h, b0);
    k_othp<<<dim3(BC), dim3(256), 0, stream>>>(oth_f32, Wm1q, othp);
    k_msg<<<dim3(nblk), dim3(256), 0, stream>>>(othp, sp1_g, spS_g,
                                                Wm2q, b_m2, Ws1q,
                                                W_s2, b_s2, msg_g, S_g, nblk);
    k_qw<<<dim3(BC, 3), dim3(256), 0, stream>>>(h_f32, Mhq, qW_g, nblk);
    k_attn<<<dim3(nblk, 3), dim3(256), 0, stream>>>(msg_g, S_g, gumb, qW_g,
                                                    mw_g, b0, nblk);
    k_pv<<<dim3(BC, 3), dim3(256), 0, stream>>>(mw_g, Pq, att_rb, nblk);
    k_head<<<dim3(nblk), dim3(128), 0, stream>>>(h_f32, att_rb, Wq1T, b_q1,
                                                 Wq2T, b_q2, out_q, b0, nblk);
  }
}